// Round 2
// 828.894 us; speedup vs baseline: 1.1734x; 1.1734x over previous
//
#include <hip/hip_runtime.h>
#include <math.h>

// ---------------------------------------------------------------------------
// PromptGenerate: DWT->E->smooth->conv1+BN+GELU->conv2->sigmoid (sal, 512x512)
//  -> bilinear 2x upsample (masks), boxes from mask>0.5, greedy-NMS peak coords
// R6: k_conv moved to bf16 MFMA (16x16x32) with hi/lo split (3-term, ~2^-16
//     rel err). Conv decomposed as 9 shifted 1x1 convs: K = 10 shifts x 16
//     padded ch = 160 -> 5 K-steps. freq stored channel-last bf16 hi/lo
//     ([px][16hi|16lo], 64B/px) so every B fragment is ONE aligned 16B global
//     load (L1/L2 resident); zero pad-channel / pad-shift WEIGHTS make padded
//     B lanes harmless. Weights pre-packed per-lane by k_init (20KB). No LDS,
//     no syncthreads in k_conv. Epilogue gelu via t*sigmoid(2u) (v_exp).
// R7: resubmit of R6 unchanged — round-1 bench was an infra failure (container
//     acquisition), no measurement taken. OOB/layout/numerics re-audited.
// ---------------------------------------------------------------------------

#define CHW 262144          // 512*512
#define FULLHW 1048576      // 1024*1024

typedef __attribute__((ext_vector_type(8))) short bf16x8;
typedef __attribute__((ext_vector_type(4))) float f32x4;

static __device__ __forceinline__ unsigned short f2bf(float x) {
  unsigned u = __float_as_uint(x);
  u += 0x7FFFu + ((u >> 16) & 1u);
  return (unsigned short)(u >> 16);
}
static __device__ __forceinline__ float bf2f(unsigned short h) {
  return __uint_as_float(((unsigned)h) << 16);
}

static constexpr size_t OFF_SAL   = 0;                       // 8*CHW*4
static constexpr size_t OFF_HIST1 = 8388608;                 // 131072
static constexpr size_t OFF_HIST2 = OFF_HIST1 + 131072;      // 131072
static constexpr size_t OFF_THR   = OFF_HIST2 + 131072;      // 256
static constexpr size_t OFF_CNT   = OFF_THR + 256;           // 256
static constexpr size_t OFF_BOX   = OFF_CNT + 256;           // 256 (spacing)
static constexpr size_t OFF_CAND  = OFF_BOX + 256;           // 131072
static constexpr size_t OFF_PART  = OFF_CAND + 131072;       // 32768
static constexpr size_t OFF_APACK = OFF_PART + 32768;        // 20480 (A frags)
static constexpr size_t OFF_EP    = OFF_APACK + 20480;       // 512 (epilogue)
static constexpr size_t OFF_PKM   = OFF_EP + 512;            // 8*CHW u8
static constexpr size_t OFF_DYN   = OFF_PKM + 2097152;       // ebuf + freq2

// shift s = ky*3+kx (0..8), s=9 is K-padding (zero weights)
static constexpr int KDY[10] = {-1,-1,-1, 0,0,0, 1,1,1, 0};
static constexpr int KDX[10] = {-1, 0, 1,-1,0,1,-1,0,1, 0};

// ---------------------------------------------------------------- init + weight pack
// apack layout (ushort): frag = (mt*5+ks)*2+h, element [frag][lane][e] with
//   co = mt*16+(lane&15), k = (lane>>4)*8+e, c = k&15, shift = ks*2+(k>>4)
//   val = (shift<9 && c<12) ? w1[co][c][shift] : 0 ; h=0 -> bf16 hi, h=1 -> lo
// ep layout (float): [0,32) sc | [32,64) sh2 = (b1-mean)*sc+beta | [64,96) w2 | [96] b2
__global__ void k_init(unsigned* __restrict__ h, unsigned* __restrict__ cnt,
                       const float* __restrict__ w1, const float* __restrict__ b1,
                       const float* __restrict__ gam, const float* __restrict__ bet,
                       const float* __restrict__ mean, const float* __restrict__ var,
                       const float* __restrict__ w2, const float* __restrict__ b2,
                       unsigned short* __restrict__ apack, float* __restrict__ ep) {
  int i = blockIdx.x * 256 + threadIdx.x;
  if (i < 65536) h[i] = 0;                       // hist1+hist2 (contiguous)
  if (i < 16) cnt[i] = 0;
  if (i < 10240) {
    int frag = i >> 9, lane = (i >> 3) & 63, e = i & 7;
    int hh = frag & 1, mtks = frag >> 1;
    int mt = mtks / 5, ks = mtks % 5;
    int co = mt * 16 + (lane & 15);
    int k = ((lane >> 4) << 3) + e;
    int c = k & 15, shift = ks * 2 + (k >> 4);
    float val = (shift < 9 && c < 12) ? w1[co * 108 + c * 9 + shift] : 0.0f;
    unsigned short hb = f2bf(val);
    apack[i] = hh ? f2bf(val - bf2f(hb)) : hb;
  }
  int j = i - 10240;
  if (j >= 0 && j < 97) {
    if (j < 32) {
      ep[j] = gam[j] * rsqrtf(var[j] + 1e-5f);
    } else if (j < 64) {
      int c = j - 32;
      float sc = gam[c] * rsqrtf(var[c] + 1e-5f);
      ep[j] = (b1[c] - mean[c]) * sc + bet[c];
    } else if (j < 96) {
      ep[j] = w2[j - 64];
    } else {
      ep[j] = b2[0];
    }
  }
}

// ---------------------------------------------------------------- freq ch 0..9
// writes channel-last bf16 hi/lo: freq2[px][0..15]=hi ch0-15, [16..31]=lo.
// ch10..15 zeroed here (10,11 filled by k_smooth). Er/Ed also to f32 ebuf.
__global__ __launch_bounds__(256) void k_freq(const float* __restrict__ rgb,
                                              const float* __restrict__ dep,
                                              unsigned short* __restrict__ freq2,
                                              float* __restrict__ ebuf, int b0) {
  int t = blockIdx.x * 256 + threadIdx.x;        // [0, 131072)
  int bi = blockIdx.y;
  int b = b0 + bi;
  int xp = t & 255, y = t >> 8;                  // xp: pair idx, outputs x=2xp,2xp+1
  const float* base = rgb + (size_t)b * 3 * FULLHW + (size_t)(2 * y) * 1024 + 4 * xp;
  float4 R0 = *(const float4*)(base);
  float4 R1 = *(const float4*)(base + 1024);
  float4 G0 = *(const float4*)(base + FULLHW);
  float4 G1 = *(const float4*)(base + FULLHW + 1024);
  float4 Bl0 = *(const float4*)(base + 2 * FULLHW);
  float4 Bl1 = *(const float4*)(base + 2 * FULLHW + 1024);
  const float* dbase = dep + (size_t)b * FULLHW + (size_t)(2 * y) * 1024 + 4 * xp;
  float4 D0 = *(const float4*)(dbase);
  float4 D1 = *(const float4*)(dbase + 1024);

  float gt[4], gb[4], dt[4], db_[4];
  gt[0] = (R0.x + G0.x + Bl0.x) / 3.0f; gt[1] = (R0.y + G0.y + Bl0.y) / 3.0f;
  gt[2] = (R0.z + G0.z + Bl0.z) / 3.0f; gt[3] = (R0.w + G0.w + Bl0.w) / 3.0f;
  gb[0] = (R1.x + G1.x + Bl1.x) / 3.0f; gb[1] = (R1.y + G1.y + Bl1.y) / 3.0f;
  gb[2] = (R1.z + G1.z + Bl1.z) / 3.0f; gb[3] = (R1.w + G1.w + Bl1.w) / 3.0f;
  dt[0] = D0.x; dt[1] = D0.y; dt[2] = D0.z; dt[3] = D0.w;
  db_[0] = D1.x; db_[1] = D1.y; db_[2] = D1.z; db_[3] = D1.w;

  unsigned short hs[2][16], ls[2][16];
  float er[2], ed[2];
  #pragma unroll
  for (int j = 0; j < 2; ++j) {
    float a = gt[2 * j] * 0.5f, bb = gb[2 * j] * 0.5f;
    float c = gt[2 * j + 1] * 0.5f, d = gb[2 * j + 1] * 0.5f;
    float v[10];
    v[0] = a + bb; v[1] = a - bb; v[2] = c + d; v[3] = c - d;
    float da = dt[2 * j] * 0.5f, db2 = db_[2 * j] * 0.5f;
    float dc = dt[2 * j + 1] * 0.5f, dd = db_[2 * j + 1] * 0.5f;
    v[4] = da + db2; v[5] = da - db2; v[6] = dc + dd; v[7] = dc - dd;
    v[8] = sqrtf(v[1] * v[1] + v[2] * v[2] + v[3] * v[3] + 1e-8f);
    v[9] = sqrtf(v[5] * v[5] + v[6] * v[6] + v[7] * v[7] + 1e-8f);
    er[j] = v[8]; ed[j] = v[9];
    #pragma unroll
    for (int cc = 0; cc < 10; ++cc) {
      unsigned short hb = f2bf(v[cc]);
      hs[j][cc] = hb;
      ls[j][cc] = f2bf(v[cc] - bf2f(hb));
    }
    #pragma unroll
    for (int cc = 10; cc < 16; ++cc) { hs[j][cc] = 0; ls[j][cc] = 0; }
  }
  unsigned short* dst = freq2 + (size_t)bi * CHW * 32 + (size_t)(y * 512 + 2 * xp) * 32;
  uint4* d4 = (uint4*)dst;
  d4[0] = ((const uint4*)hs[0])[0]; d4[1] = ((const uint4*)hs[0])[1];
  d4[2] = ((const uint4*)ls[0])[0]; d4[3] = ((const uint4*)ls[0])[1];
  d4[4] = ((const uint4*)hs[1])[0]; d4[5] = ((const uint4*)hs[1])[1];
  d4[6] = ((const uint4*)ls[1])[0]; d4[7] = ((const uint4*)ls[1])[1];
  float* eb = ebuf + (size_t)bi * 2 * CHW + (size_t)y * 512 + 2 * xp;
  *(float2*)(eb) = make_float2(er[0], er[1]);
  *(float2*)(eb + CHW) = make_float2(ed[0], ed[1]);
}

// ---------------------------------------------------------------- freq ch 10,11
__constant__ float GW[25] = {
  0.00296901f, 0.01330621f, 0.02193824f, 0.01330621f, 0.00296901f,
  0.01330621f, 0.05963435f, 0.09832035f, 0.05963435f, 0.01330621f,
  0.02193824f, 0.09832035f, 0.16210276f, 0.09832035f, 0.02193824f,
  0.01330621f, 0.05963435f, 0.09832035f, 0.05963435f, 0.01330621f,
  0.00296901f, 0.01330621f, 0.02193824f, 0.01330621f, 0.00296901f};

__global__ __launch_bounds__(256) void k_smooth(const float* __restrict__ ebuf,
                                                unsigned short* __restrict__ freq2) {
  int t = blockIdx.x * 256 + threadIdx.x;
  int bi = blockIdx.y;
  int x = t & 511, y = t >> 9;
  const float* eb = ebuf + (size_t)bi * 2 * CHW;
  float accv[2];
  #pragma unroll
  for (int ch = 0; ch < 2; ++ch) {
    const float* fin = eb + ch * CHW;
    float acc = 0.0f;
    #pragma unroll
    for (int i = 0; i < 5; ++i) {
      int yy = y + i - 2;
      if (yy < 0 || yy > 511) continue;
      #pragma unroll
      for (int j = 0; j < 5; ++j) {
        int xx = x + j - 2;
        if (xx < 0 || xx > 511) continue;
        acc += GW[i * 5 + j] * fin[yy * 512 + xx];
      }
    }
    accv[ch] = acc;
  }
  unsigned short* px = freq2 + (size_t)bi * CHW * 32 + (size_t)t * 32;
  unsigned short h0 = f2bf(accv[0]), h1 = f2bf(accv[1]);
  unsigned short l0 = f2bf(accv[0] - bf2f(h0)), l1 = f2bf(accv[1] - bf2f(h1));
  *(unsigned*)(px + 10) = (unsigned)h0 | ((unsigned)h1 << 16);
  *(unsigned*)(px + 26) = (unsigned)l0 | ((unsigned)l1 << 16);
}

// ---------------------------------------------------------------- conv fused (MFMA)
// Wave = 32 px x-strip (2 N-tiles of 16), all 32 co (2 M-tiles). Block = 4
// independent waves (128 px strip at one row). 5 K-steps of 32 (=2 shifts x
// 16ch), 3 precision terms: AhBh + AlBh + AhBl. acc: 2x2 f32x4.
__global__ __launch_bounds__(256) void k_conv(const unsigned short* __restrict__ freq2,
    const unsigned short* __restrict__ apack, const float* __restrict__ ep,
    float* __restrict__ sal, int b0) {
  int tid = threadIdx.x;
  int l = tid & 63, wv = tid >> 6;
  int y = blockIdx.y;
  int xw = blockIdx.x * 128 + wv * 32;
  int bi = blockIdx.z;
  const unsigned short* fb = freq2 + (size_t)bi * CHW * 32;

  int ln = l & 15, lg = l >> 4;
  int sl = lg >> 1;                              // s_local within K-step
  int c0 = (lg & 1) << 3;                        // channel base (ushorts)

  // epilogue per-lane scalars: co = mt*16 + lg*4 + r
  float sc[8], sh[8], w2v[8];
  #pragma unroll
  for (int mt = 0; mt < 2; ++mt)
    #pragma unroll
    for (int r = 0; r < 4; ++r) {
      int co = mt * 16 + lg * 4 + r;
      sc[mt * 4 + r]  = ep[co];
      sh[mt * 4 + r]  = ep[32 + co];
      w2v[mt * 4 + r] = ep[64 + co];
    }
  float b2v = ep[96];

  f32x4 acc[2][2] = {};                          // [mt][nt]

  #pragma unroll
  for (int ks = 0; ks < 5; ++ks) {
    int dy = sl ? KDY[ks * 2 + 1] : KDY[ks * 2];
    int dx = sl ? KDX[ks * 2 + 1] : KDX[ks * 2];
    int yy = y + dy;
    bool yok = (unsigned)yy < 512u;
    bf16x8 Ah[2], Al[2];
    #pragma unroll
    for (int mt = 0; mt < 2; ++mt) {
      const unsigned short* ab = apack + ((size_t)((mt * 5 + ks) * 2) * 64 + l) * 8;
      Ah[mt] = *(const bf16x8*)(ab);
      Al[mt] = *(const bf16x8*)(ab + 512);       // h=1 frag: +512 ushorts
    }
    #pragma unroll
    for (int nt = 0; nt < 2; ++nt) {
      int xx = xw + nt * 16 + ln + dx;
      bf16x8 Bh = {}, Bl = {};
      if (yok && (unsigned)xx < 512u) {
        const unsigned short* pb = fb + (size_t)(yy * 512 + xx) * 32 + c0;
        Bh = *(const bf16x8*)(pb);
        Bl = *(const bf16x8*)(pb + 16);
      }
      #pragma unroll
      for (int mt = 0; mt < 2; ++mt) {
        acc[mt][nt] = __builtin_amdgcn_mfma_f32_16x16x32_bf16(Ah[mt], Bh, acc[mt][nt], 0, 0, 0);
        acc[mt][nt] = __builtin_amdgcn_mfma_f32_16x16x32_bf16(Al[mt], Bh, acc[mt][nt], 0, 0, 0);
        acc[mt][nt] = __builtin_amdgcn_mfma_f32_16x16x32_bf16(Ah[mt], Bl, acc[mt][nt], 0, 0, 0);
      }
    }
  }

  // epilogue: BN + gelu + w2-dot (per-lane 4 co x 2 mt), cross-lane co sum,
  // sigmoid, store. D layout: col(px)=lane&15, row(co_local)=lg*4+reg.
  #pragma unroll
  for (int nt = 0; nt < 2; ++nt) {
    float s2 = 0.0f;
    #pragma unroll
    for (int mt = 0; mt < 2; ++mt)
      #pragma unroll
      for (int r = 0; r < 4; ++r) {
        float t = acc[mt][nt][r] * sc[mt * 4 + r] + sh[mt * 4 + r];
        float t2 = t * t;
        float z = t * (1.5957691216057308f + 0.07135481283247183f * t2);
        float g = t / (1.0f + __expf(-z));       // == 0.5t(1+tanh(.79788(t+.044715t^3)))
        s2 += g * w2v[mt * 4 + r];
      }
    s2 += __shfl_xor(s2, 16);
    s2 += __shfl_xor(s2, 32);
    s2 += b2v;
    float res = 1.0f / (1.0f + __expf(-s2));
    if (lg == 0)
      sal[(size_t)(b0 + bi) * CHW + (size_t)y * 512 + xw + nt * 16 + ln] = res;
  }
}

// ---------------------------------------------------------------- resize + box partials
__global__ __launch_bounds__(256) void k_resize(const float* __restrict__ sal,
                                                float* __restrict__ masks,
                                                int* __restrict__ part) {
  int b = blockIdx.y;
  int blk = blockIdx.x;
  int t = threadIdx.x;
  const float* sp = sal + (size_t)b * CHW;
  float* mp = masks + (size_t)b * FULLHW;
  int mnX = 0x7FFFFFFF, mxX = -1, mnY = 0x7FFFFFFF, mxY = -1;
  int c0 = 4 * t;
  #pragma unroll
  for (int r = 0; r < 4; ++r) {
    int Y = blk * 4 + r;
    int y0 = (Y - 1) >> 1;
    float wy = (Y & 1) ? 0.25f : 0.75f;
    int y0c = y0 < 0 ? 0 : y0, y1c = (y0 + 1 > 511) ? 511 : y0 + 1;
    const float* r0 = sp + y0c * 512;
    const float* r1 = sp + y1c * 512;
    float o[4];
    #pragma unroll
    for (int j = 0; j < 4; ++j) {
      int X = c0 + j;
      int x0 = (X - 1) >> 1;
      float wx = (X & 1) ? 0.25f : 0.75f;
      int x0c = x0 < 0 ? 0 : x0, x1c = (x0 + 1 > 511) ? 511 : x0 + 1;
      float v00 = r0[x0c], v01 = r0[x1c], v10 = r1[x0c], v11 = r1[x1c];
      o[j] = (1.0f - wy) * ((1.0f - wx) * v00 + wx * v01)
           + wy * ((1.0f - wx) * v10 + wx * v11);
      if (o[j] > 0.5f) {
        mnX = min(mnX, X); mxX = max(mxX, X);
        mnY = min(mnY, Y); mxY = max(mxY, Y);
      }
    }
    *(float4*)(mp + (size_t)Y * 1024 + c0) = make_float4(o[0], o[1], o[2], o[3]);
  }
  __shared__ int s0[256], s1[256], s2[256], s3[256];
  s0[t] = mnX; s1[t] = mxX; s2[t] = mnY; s3[t] = mxY;
  __syncthreads();
  for (int off = 128; off > 0; off >>= 1) {
    if (t < off) {
      s0[t] = min(s0[t], s0[t + off]); s1[t] = max(s1[t], s1[t + off]);
      s2[t] = min(s2[t], s2[t + off]); s3[t] = max(s3[t], s3[t + off]);
    }
    __syncthreads();
  }
  if (t == 0) {
    int* pp = part + (b * 256 + blk) * 4;
    pp[0] = s0[0]; pp[1] = s1[0]; pp[2] = s2[0]; pp[3] = s3[0];
  }
}

// ---------------------------------------------------------------- box reduce -> out
__global__ __launch_bounds__(256) void k_boxreduce(const int* __restrict__ part,
                                                   float* __restrict__ out) {
  int b = blockIdx.x, t = threadIdx.x;
  const int* pp = part + (b * 256 + t) * 4;
  __shared__ int s0[256], s1[256], s2[256], s3[256];
  s0[t] = pp[0]; s1[t] = pp[1]; s2[t] = pp[2]; s3[t] = pp[3];
  __syncthreads();
  for (int off = 128; off > 0; off >>= 1) {
    if (t < off) {
      s0[t] = min(s0[t], s0[t + off]); s1[t] = max(s1[t], s1[t + off]);
      s2[t] = min(s2[t], s2[t + off]); s3[t] = max(s3[t], s3[t + off]);
    }
    __syncthreads();
  }
  if (t == 0) {
    float x0, y0, x1, y1;
    if (s3[0] < 0) { x0 = 0.0f; y0 = 0.0f; x1 = 1023.0f; y1 = 1023.0f; }
    else { x0 = (float)s0[0]; y0 = (float)s2[0]; x1 = (float)s1[0]; y1 = (float)s3[0]; }
    out[240 + b * 4 + 0] = x0;
    out[240 + b * 4 + 1] = y0;
    out[240 + b * 4 + 2] = x1;
    out[240 + b * 4 + 3] = y1;
  }
}

// ---------------------------------------------------------------- peak helper
__device__ inline bool is_peak(const float* __restrict__ sp, int x, int y, float& sv) {
  float s = sp[y * 512 + x];
  sv = s;
  if (!(s > 0.0f)) return false;
  int x0 = (x > 0) ? x - 1 : x, x1 = (x < 511) ? x + 1 : x;
  int y0 = (y > 0) ? y - 1 : y, y1 = (y < 511) ? y + 1 : y;
  for (int yy = y0; yy <= y1; ++yy)
    for (int xx = x0; xx <= x1; ++xx)
      if (sp[yy * 512 + xx] > s) return false;     // s >= all neighbors == (s==maxpool)
  return true;
}

// ---------------------------------------------------------------- level-1 hist (+peak mask)
__global__ __launch_bounds__(256) void k_hist1(const float* __restrict__ sal,
                                               unsigned* __restrict__ hist,
                                               unsigned char* __restrict__ pkm) {
  __shared__ unsigned sH[4096];                   // [class][2048]
  int b = blockIdx.y, tid = threadIdx.x;
  for (int i = tid; i < 4096; i += 256) sH[i] = 0;
  __syncthreads();
  const float* sp = sal + (size_t)b * CHW;
  int base = blockIdx.x * 2048;
  for (int it = 0; it < 8; ++it) {
    int p = base + it * 256 + tid;
    int x = p & 511, y = p >> 9;
    float s;
    bool pk = is_peak(sp, x, y, s);
    pkm[(size_t)b * CHW + p] = pk ? 1 : 0;
    unsigned bin = (__float_as_uint(s) >> 21) & 2047;
    atomicAdd(&sH[(pk ? 0 : 2048) + bin], 1u);
  }
  __syncthreads();
  for (int i = tid; i < 4096; i += 256) {
    unsigned v = sH[i];
    if (v) atomicAdd(&hist[(i >= 2048 ? 16384 : 0) + b * 2048 + (i & 2047)], v);
  }
}

// ---------------------------------------------------------------- radix scan
__global__ __launch_bounds__(256) void k_scan(const unsigned* __restrict__ hist,
                                              int* __restrict__ thr, int level) {
  int c = blockIdx.x, b = blockIdx.y, t = threadIdx.x;
  __shared__ unsigned sBins[2048];
  __shared__ unsigned sS[256];
  __shared__ int sT;
  const unsigned* hp = hist + c * 16384 + b * 2048;
  unsigned part = 0;
  for (int r = 0; r < 8; ++r) {
    unsigned v = hp[t * 8 + r];
    sBins[t * 8 + r] = v;
    part += v;
  }
  sS[t] = part;
  __syncthreads();
  for (int off = 1; off < 256; off <<= 1) {
    unsigned add = (t + off < 256) ? sS[t + off] : 0;
    __syncthreads();
    sS[t] += add;
    __syncthreads();
  }
  int K = (c == 0) ? 512 : 10;
  int* tb = thr + (c * 8 + b) * 4;
  if (level == 1) { K -= tb[1]; if (K < 1) K = 1; }
  if (t == 0) sT = -1;
  __syncthreads();
  if (sS[t] >= (unsigned)K && (t == 255 || sS[t + 1] < (unsigned)K)) sT = t;
  __syncthreads();
  if (t == 0) {
    int T = 0;
    unsigned run = 0;
    if (sT >= 0) {
      int ts = sT;
      run = (ts < 255) ? sS[ts + 1] : 0;
      for (int r = 7; r >= 0; --r) {
        unsigned v = sBins[ts * 8 + r];
        run += v;
        if (run >= (unsigned)K) { T = ts * 8 + r; run -= v; break; }
      }
    } else {
      T = 0;
      run = sS[0] - sBins[0];                     // suffix(1); take everything
    }
    if (level == 0) { tb[0] = T; tb[1] = (int)run; }
    else           { tb[2] = (tb[0] << 11) | T; }
  }
}

// ---------------------------------------------------------------- level-2 hist
__global__ __launch_bounds__(256) void k_hist2(const float* __restrict__ sal,
                                               const unsigned char* __restrict__ pkm,
                                               const int* __restrict__ thr,
                                               unsigned* __restrict__ hist2) {
  int b = blockIdx.y;
  int p = blockIdx.x * 256 + threadIdx.x;
  const float* sp = sal + (size_t)b * CHW;
  bool pk = pkm[(size_t)b * CHW + p] != 0;
  float s = sp[p];
  int c = pk ? 0 : 1;
  unsigned bits = __float_as_uint(s);
  if ((int)(bits >> 21) == thr[(c * 8 + b) * 4])
    atomicAdd(&hist2[c * 16384 + b * 2048 + ((bits >> 10) & 2047)], 1u);
}

// ---------------------------------------------------------------- compact
__global__ __launch_bounds__(256) void k_compact(const float* __restrict__ sal,
                                                 const unsigned char* __restrict__ pkm,
                                                 const int* __restrict__ thr,
                                                 unsigned* __restrict__ cnt,
                                                 unsigned long long* __restrict__ cand) {
  int b = blockIdx.y;
  int p = blockIdx.x * 256 + threadIdx.x;
  const float* sp = sal + (size_t)b * CHW;
  bool pk = pkm[(size_t)b * CHW + p] != 0;
  float s = sp[p];
  int c = pk ? 0 : 1;
  unsigned bits = __float_as_uint(s);
  unsigned q = (unsigned)thr[(c * 8 + b) * 4 + 2];
  if ((bits >> 10) >= q) {
    unsigned pos = atomicAdd(&cnt[c * 8 + b], 1u);
    if (pos < 1024)
      cand[((size_t)(c * 8 + b) << 10) + pos] =
          ((unsigned long long)bits << 32) | (unsigned)(~p);   // score desc, idx asc
  }
}

// ---------------------------------------------------------------- sort + NMS
__device__ inline void bitonic1024_desc(unsigned long long* sKey) {
  int t = threadIdx.x;
  for (unsigned k = 2; k <= 1024; k <<= 1) {
    for (unsigned j = k >> 1; j > 0; j >>= 1) {
      __syncthreads();
      #pragma unroll
      for (int e = 0; e < 2; ++e) {
        unsigned i = (unsigned)t + (unsigned)e * 512u;
        unsigned l = i ^ j;
        if (l > i) {
          unsigned long long a = sKey[i], bb = sKey[l];
          if (((i & k) == 0) ? (a < bb) : (a > bb)) { sKey[i] = bb; sKey[l] = a; }
        }
      }
    }
  }
  __syncthreads();
}

__global__ __launch_bounds__(512) void k_nms(const unsigned long long* __restrict__ cand,
                                             const unsigned* __restrict__ cnt,
                                             float* __restrict__ out) {
  __shared__ unsigned long long sKey[1024];
  __shared__ unsigned sIdx[512];
  __shared__ int sAvail[512];
  __shared__ int sSel[16];
  int b = blockIdx.x, t = threadIdx.x;
  if (t < 10) out[160 + b * 10 + t] = 1.0f;       // labels
  int Cp = (int)cnt[b]; if (Cp > 1024) Cp = 1024;
  const unsigned long long* cp = cand + ((size_t)b << 10);
  sKey[t] = (t < Cp) ? cp[t] : 0ULL;
  sKey[t + 512] = (t + 512 < Cp) ? cp[t + 512] : 0ULL;
  bitonic1024_desc(sKey);
  sIdx[t] = (unsigned)(~sKey[t]);
  int ncand = (Cp < 512) ? Cp : 512;              // K_PEAKS cap
  sAvail[t] = (t < ncand) ? 1 : 0;
  __syncthreads();
  int nsel = 0;
  for (int i = 0; i < 512 && nsel < 10; ++i) {
    if (sAvail[i] != 0) {                         // uniform branch
      unsigned pi = sIdx[i];
      int xi = (int)(pi & 511), yi = (int)(pi >> 9);
      if (t > i && sAvail[t]) {
        int dx = (int)(sIdx[t] & 511) - xi;
        int dy = (int)(sIdx[t] >> 9) - yi;
        if (dx * dx + dy * dy < 625) sAvail[t] = 0;   // dist < 25
      }
      if (t == 0) sSel[nsel] = (int)pi;
      ++nsel;
      __syncthreads();
    }
  }
  __syncthreads();
  // fallback: top-10 non-peak pixels
  int Cf = (int)cnt[8 + b]; if (Cf > 1024) Cf = 1024;
  const unsigned long long* cf = cand + ((size_t)(8 + b) << 10);
  sKey[t] = (t < Cf) ? cf[t] : 0ULL;
  sKey[t + 512] = (t + 512 < Cf) ? cf[t + 512] : 0ULL;
  bitonic1024_desc(sKey);
  if (t < 10) {
    int fi;
    if (t < nsel) fi = sSel[t];
    else { int r = t - nsel; if (r > 9) r = 9; fi = (int)((unsigned)(~sKey[r])); }
    out[((size_t)b * 10 + t) * 2 + 0] = (float)(fi & 511) * (1.0f / 512.0f);
    out[((size_t)b * 10 + t) * 2 + 1] = (float)(fi >> 9) * (1.0f / 512.0f);
  }
}

// ---------------------------------------------------------------------------
extern "C" void kernel_launch(void* const* d_in, const int* in_sizes, int n_in,
                              void* d_out, int out_size, void* d_ws, size_t ws_size,
                              hipStream_t stream) {
  const float* rgb  = (const float*)d_in[0];
  const float* dep  = (const float*)d_in[1];
  const float* w1   = (const float*)d_in[2];
  const float* b1   = (const float*)d_in[3];
  const float* gam  = (const float*)d_in[4];
  const float* bet  = (const float*)d_in[5];
  const float* bmn  = (const float*)d_in[6];
  const float* bvr  = (const float*)d_in[7];
  const float* w2   = (const float*)d_in[8];
  const float* b2   = (const float*)d_in[9];
  float* out = (float*)d_out;
  char* ws = (char*)d_ws;

  float* sal = (float*)(ws + OFF_SAL);
  unsigned* hist1 = (unsigned*)(ws + OFF_HIST1);
  unsigned* hist2 = (unsigned*)(ws + OFF_HIST2);
  int* thr = (int*)(ws + OFF_THR);
  unsigned* cnt = (unsigned*)(ws + OFF_CNT);
  unsigned long long* cand = (unsigned long long*)(ws + OFF_CAND);
  int* part = (int*)(ws + OFF_PART);
  unsigned short* apack = (unsigned short*)(ws + OFF_APACK);
  float* ep = (float*)(ws + OFF_EP);
  unsigned char* pkm = (unsigned char*)(ws + OFF_PKM);

  // dynamic region: ebuf (nb*2*CHW f32) then freq2 (nb*CHW*32 ushorts)
  size_t perE = (size_t)2 * CHW * 4;             // 2 MB / batch
  size_t perF = (size_t)CHW * 64;                // 16 MB / batch
  long long avail = (long long)ws_size - (long long)OFF_DYN;
  int nb = 1;
  if (avail >= (long long)(perE + perF)) {
    long long m = avail / (long long)(perE + perF);
    nb = (m > 8) ? 8 : (int)m;
  }
  float* ebuf = (float*)(ws + OFF_DYN);
  unsigned short* freq2 = (unsigned short*)(ws + OFF_DYN + perE * (size_t)nb);

  k_init<<<256, 256, 0, stream>>>(hist1, cnt, w1, b1, gam, bet, bmn, bvr, w2, b2,
                                  apack, ep);

  for (int b0 = 0; b0 < 8; b0 += nb) {
    int nbc = (8 - b0 < nb) ? (8 - b0) : nb;
    k_freq<<<dim3(512, nbc), 256, 0, stream>>>(rgb, dep, freq2, ebuf, b0);
    k_smooth<<<dim3(1024, nbc), 256, 0, stream>>>(ebuf, freq2);
    k_conv<<<dim3(4, 512, nbc), 256, 0, stream>>>(freq2, apack, ep, sal, b0);
  }

  k_resize<<<dim3(256, 8), 256, 0, stream>>>(sal, out + 272, part);
  k_boxreduce<<<8, 256, 0, stream>>>(part, out);
  k_hist1<<<dim3(128, 8), 256, 0, stream>>>(sal, hist1, pkm);
  k_scan<<<dim3(2, 8), 256, 0, stream>>>(hist1, thr, 0);
  k_hist2<<<dim3(1024, 8), 256, 0, stream>>>(sal, pkm, thr, hist2);
  k_scan<<<dim3(2, 8), 256, 0, stream>>>(hist2, thr, 1);
  k_compact<<<dim3(1024, 8), 256, 0, stream>>>(sal, pkm, thr, cnt, cand);
  k_nms<<<8, 512, 0, stream>>>(cand, cnt, out);
}

// Round 3
// 611.838 us; speedup vs baseline: 1.5897x; 1.3548x over previous
//
#include <hip/hip_runtime.h>
#include <math.h>

// ---------------------------------------------------------------------------
// PromptGenerate: DWT->E->smooth->conv1+BN+GELU->conv2->sigmoid (sal, 512x512)
//  -> bilinear 2x upsample (masks), boxes from mask>0.5, greedy-NMS peak coords
// R6: k_conv on bf16 MFMA (16x16x32), hi/lo split (3-term). Conv = 9 shifted
//     1x1 convs, K = 10 shifts x 16 padded ch -> 5 K-steps. freq channel-last
//     bf16 hi/lo (64B/px): each B fragment is one 16B global load. Weights
//     pre-packed per-lane (20KB). No LDS/syncthreads in k_conv.
// R8: k_hist2 was 270us at VALUBusy 0.4% / WRITE_SIZE 25MB -> ~400-800K
//     contended cross-XCD global atomics into 2048 hot bins. Fix: both hist
//     kernels now write per-block LDS histograms to NON-ATOMIC global partials
//     (k_hist1: 64 blk/batch, k_hist2: 32 blk/batch, vectorized loads);
//     k_scan sums partials during its bin read (coalesced uint4 streaming).
//     Zero global atomics on the histogram path. Partials (8MB+4MB) overlap
//     the dead ebuf/freq2 region (temporally disjoint, single stream).
// ---------------------------------------------------------------------------

#define CHW 262144          // 512*512
#define FULLHW 1048576      // 1024*1024
#define NB1 64              // k_hist1 blocks per batch (4096 px each)
#define NB2 32              // k_hist2 blocks per batch (8192 px each)

typedef __attribute__((ext_vector_type(8))) short bf16x8;
typedef __attribute__((ext_vector_type(4))) float f32x4;

static __device__ __forceinline__ unsigned short f2bf(float x) {
  unsigned u = __float_as_uint(x);
  u += 0x7FFFu + ((u >> 16) & 1u);
  return (unsigned short)(u >> 16);
}
static __device__ __forceinline__ float bf2f(unsigned short h) {
  return __uint_as_float(((unsigned)h) << 16);
}

static constexpr size_t OFF_SAL   = 0;                       // 8*CHW*4
static constexpr size_t OFF_THR   = 8388608;                 // 256
static constexpr size_t OFF_CNT   = OFF_THR + 256;           // 256
static constexpr size_t OFF_CAND  = OFF_CNT + 256;           // 131072
static constexpr size_t OFF_PART  = OFF_CAND + 131072;       // 32768
static constexpr size_t OFF_APACK = OFF_PART + 32768;        // 20480 (A frags)
static constexpr size_t OFF_EP    = OFF_APACK + 20480;       // 512 (epilogue)
static constexpr size_t OFF_PKM   = OFF_EP + 512;            // 8*CHW u8
static constexpr size_t OFF_DYN   = OFF_PKM + 2097152;
// dynamic region (temporally disjoint uses):
//   conv phase : ebuf (nb*2MB) + freq2 (nb*16MB)
//   hist phase : h1p (8*NB1*4096*4 = 8MB) + h2p (8*NB2*4096*4 = 4MB)

// shift s = ky*3+kx (0..8), s=9 is K-padding (zero weights)
static constexpr int KDY[10] = {-1,-1,-1, 0,0,0, 1,1,1, 0};
static constexpr int KDX[10] = {-1, 0, 1,-1,0,1,-1,0,1, 0};

// ---------------------------------------------------------------- init + weight pack
// apack layout (ushort): frag = (mt*5+ks)*2+h, element [frag][lane][e] with
//   co = mt*16+(lane&15), k = (lane>>4)*8+e, c = k&15, shift = ks*2+(k>>4)
//   val = (shift<9 && c<12) ? w1[co][c][shift] : 0 ; h=0 -> bf16 hi, h=1 -> lo
// ep layout (float): [0,32) sc | [32,64) sh2 = (b1-mean)*sc+beta | [64,96) w2 | [96] b2
__global__ void k_init(unsigned* __restrict__ cnt,
                       const float* __restrict__ w1, const float* __restrict__ b1,
                       const float* __restrict__ gam, const float* __restrict__ bet,
                       const float* __restrict__ mean, const float* __restrict__ var,
                       const float* __restrict__ w2, const float* __restrict__ b2,
                       unsigned short* __restrict__ apack, float* __restrict__ ep) {
  int i = blockIdx.x * 256 + threadIdx.x;
  if (i < 16) cnt[i] = 0;
  if (i < 10240) {
    int frag = i >> 9, lane = (i >> 3) & 63, e = i & 7;
    int hh = frag & 1, mtks = frag >> 1;
    int mt = mtks / 5, ks = mtks % 5;
    int co = mt * 16 + (lane & 15);
    int k = ((lane >> 4) << 3) + e;
    int c = k & 15, shift = ks * 2 + (k >> 4);
    float val = (shift < 9 && c < 12) ? w1[co * 108 + c * 9 + shift] : 0.0f;
    unsigned short hb = f2bf(val);
    apack[i] = hh ? f2bf(val - bf2f(hb)) : hb;
  }
  int j = i - 10240;
  if (j >= 0 && j < 97) {
    if (j < 32) {
      ep[j] = gam[j] * rsqrtf(var[j] + 1e-5f);
    } else if (j < 64) {
      int c = j - 32;
      float sc = gam[c] * rsqrtf(var[c] + 1e-5f);
      ep[j] = (b1[c] - mean[c]) * sc + bet[c];
    } else if (j < 96) {
      ep[j] = w2[j - 64];
    } else {
      ep[j] = b2[0];
    }
  }
}

// ---------------------------------------------------------------- freq ch 0..9
// writes channel-last bf16 hi/lo: freq2[px][0..15]=hi ch0-15, [16..31]=lo.
// ch10..15 zeroed here (10,11 filled by k_smooth). Er/Ed also to f32 ebuf.
__global__ __launch_bounds__(256) void k_freq(const float* __restrict__ rgb,
                                              const float* __restrict__ dep,
                                              unsigned short* __restrict__ freq2,
                                              float* __restrict__ ebuf, int b0) {
  int t = blockIdx.x * 256 + threadIdx.x;        // [0, 131072)
  int bi = blockIdx.y;
  int b = b0 + bi;
  int xp = t & 255, y = t >> 8;                  // xp: pair idx, outputs x=2xp,2xp+1
  const float* base = rgb + (size_t)b * 3 * FULLHW + (size_t)(2 * y) * 1024 + 4 * xp;
  float4 R0 = *(const float4*)(base);
  float4 R1 = *(const float4*)(base + 1024);
  float4 G0 = *(const float4*)(base + FULLHW);
  float4 G1 = *(const float4*)(base + FULLHW + 1024);
  float4 Bl0 = *(const float4*)(base + 2 * FULLHW);
  float4 Bl1 = *(const float4*)(base + 2 * FULLHW + 1024);
  const float* dbase = dep + (size_t)b * FULLHW + (size_t)(2 * y) * 1024 + 4 * xp;
  float4 D0 = *(const float4*)(dbase);
  float4 D1 = *(const float4*)(dbase + 1024);

  float gt[4], gb[4], dt[4], db_[4];
  gt[0] = (R0.x + G0.x + Bl0.x) / 3.0f; gt[1] = (R0.y + G0.y + Bl0.y) / 3.0f;
  gt[2] = (R0.z + G0.z + Bl0.z) / 3.0f; gt[3] = (R0.w + G0.w + Bl0.w) / 3.0f;
  gb[0] = (R1.x + G1.x + Bl1.x) / 3.0f; gb[1] = (R1.y + G1.y + Bl1.y) / 3.0f;
  gb[2] = (R1.z + G1.z + Bl1.z) / 3.0f; gb[3] = (R1.w + G1.w + Bl1.w) / 3.0f;
  dt[0] = D0.x; dt[1] = D0.y; dt[2] = D0.z; dt[3] = D0.w;
  db_[0] = D1.x; db_[1] = D1.y; db_[2] = D1.z; db_[3] = D1.w;

  unsigned short hs[2][16], ls[2][16];
  float er[2], ed[2];
  #pragma unroll
  for (int j = 0; j < 2; ++j) {
    float a = gt[2 * j] * 0.5f, bb = gb[2 * j] * 0.5f;
    float c = gt[2 * j + 1] * 0.5f, d = gb[2 * j + 1] * 0.5f;
    float v[10];
    v[0] = a + bb; v[1] = a - bb; v[2] = c + d; v[3] = c - d;
    float da = dt[2 * j] * 0.5f, db2 = db_[2 * j] * 0.5f;
    float dc = dt[2 * j + 1] * 0.5f, dd = db_[2 * j + 1] * 0.5f;
    v[4] = da + db2; v[5] = da - db2; v[6] = dc + dd; v[7] = dc - dd;
    v[8] = sqrtf(v[1] * v[1] + v[2] * v[2] + v[3] * v[3] + 1e-8f);
    v[9] = sqrtf(v[5] * v[5] + v[6] * v[6] + v[7] * v[7] + 1e-8f);
    er[j] = v[8]; ed[j] = v[9];
    #pragma unroll
    for (int cc = 0; cc < 10; ++cc) {
      unsigned short hb = f2bf(v[cc]);
      hs[j][cc] = hb;
      ls[j][cc] = f2bf(v[cc] - bf2f(hb));
    }
    #pragma unroll
    for (int cc = 10; cc < 16; ++cc) { hs[j][cc] = 0; ls[j][cc] = 0; }
  }
  unsigned short* dst = freq2 + (size_t)bi * CHW * 32 + (size_t)(y * 512 + 2 * xp) * 32;
  uint4* d4 = (uint4*)dst;
  d4[0] = ((const uint4*)hs[0])[0]; d4[1] = ((const uint4*)hs[0])[1];
  d4[2] = ((const uint4*)ls[0])[0]; d4[3] = ((const uint4*)ls[0])[1];
  d4[4] = ((const uint4*)hs[1])[0]; d4[5] = ((const uint4*)hs[1])[1];
  d4[6] = ((const uint4*)ls[1])[0]; d4[7] = ((const uint4*)ls[1])[1];
  float* eb = ebuf + (size_t)bi * 2 * CHW + (size_t)y * 512 + 2 * xp;
  *(float2*)(eb) = make_float2(er[0], er[1]);
  *(float2*)(eb + CHW) = make_float2(ed[0], ed[1]);
}

// ---------------------------------------------------------------- freq ch 10,11
__constant__ float GW[25] = {
  0.00296901f, 0.01330621f, 0.02193824f, 0.01330621f, 0.00296901f,
  0.01330621f, 0.05963435f, 0.09832035f, 0.05963435f, 0.01330621f,
  0.02193824f, 0.09832035f, 0.16210276f, 0.09832035f, 0.02193824f,
  0.01330621f, 0.05963435f, 0.09832035f, 0.05963435f, 0.01330621f,
  0.00296901f, 0.01330621f, 0.02193824f, 0.01330621f, 0.00296901f};

__global__ __launch_bounds__(256) void k_smooth(const float* __restrict__ ebuf,
                                                unsigned short* __restrict__ freq2) {
  int t = blockIdx.x * 256 + threadIdx.x;
  int bi = blockIdx.y;
  int x = t & 511, y = t >> 9;
  const float* eb = ebuf + (size_t)bi * 2 * CHW;
  float accv[2];
  #pragma unroll
  for (int ch = 0; ch < 2; ++ch) {
    const float* fin = eb + ch * CHW;
    float acc = 0.0f;
    #pragma unroll
    for (int i = 0; i < 5; ++i) {
      int yy = y + i - 2;
      if (yy < 0 || yy > 511) continue;
      #pragma unroll
      for (int j = 0; j < 5; ++j) {
        int xx = x + j - 2;
        if (xx < 0 || xx > 511) continue;
        acc += GW[i * 5 + j] * fin[yy * 512 + xx];
      }
    }
    accv[ch] = acc;
  }
  unsigned short* px = freq2 + (size_t)bi * CHW * 32 + (size_t)t * 32;
  unsigned short h0 = f2bf(accv[0]), h1 = f2bf(accv[1]);
  unsigned short l0 = f2bf(accv[0] - bf2f(h0)), l1 = f2bf(accv[1] - bf2f(h1));
  *(unsigned*)(px + 10) = (unsigned)h0 | ((unsigned)h1 << 16);
  *(unsigned*)(px + 26) = (unsigned)l0 | ((unsigned)l1 << 16);
}

// ---------------------------------------------------------------- conv fused (MFMA)
// Wave = 32 px x-strip (2 N-tiles of 16), all 32 co (2 M-tiles). Block = 4
// independent waves (128 px strip at one row). 5 K-steps of 32 (=2 shifts x
// 16ch), 3 precision terms: AhBh + AlBh + AhBl. acc: 2x2 f32x4.
__global__ __launch_bounds__(256) void k_conv(const unsigned short* __restrict__ freq2,
    const unsigned short* __restrict__ apack, const float* __restrict__ ep,
    float* __restrict__ sal, int b0) {
  int tid = threadIdx.x;
  int l = tid & 63, wv = tid >> 6;
  int y = blockIdx.y;
  int xw = blockIdx.x * 128 + wv * 32;
  int bi = blockIdx.z;
  const unsigned short* fb = freq2 + (size_t)bi * CHW * 32;

  int ln = l & 15, lg = l >> 4;
  int sl = lg >> 1;                              // s_local within K-step
  int c0 = (lg & 1) << 3;                        // channel base (ushorts)

  // epilogue per-lane scalars: co = mt*16 + lg*4 + r
  float sc[8], sh[8], w2v[8];
  #pragma unroll
  for (int mt = 0; mt < 2; ++mt)
    #pragma unroll
    for (int r = 0; r < 4; ++r) {
      int co = mt * 16 + lg * 4 + r;
      sc[mt * 4 + r]  = ep[co];
      sh[mt * 4 + r]  = ep[32 + co];
      w2v[mt * 4 + r] = ep[64 + co];
    }
  float b2v = ep[96];

  f32x4 acc[2][2] = {};                          // [mt][nt]

  #pragma unroll
  for (int ks = 0; ks < 5; ++ks) {
    int dy = sl ? KDY[ks * 2 + 1] : KDY[ks * 2];
    int dx = sl ? KDX[ks * 2 + 1] : KDX[ks * 2];
    int yy = y + dy;
    bool yok = (unsigned)yy < 512u;
    bf16x8 Ah[2], Al[2];
    #pragma unroll
    for (int mt = 0; mt < 2; ++mt) {
      const unsigned short* ab = apack + ((size_t)((mt * 5 + ks) * 2) * 64 + l) * 8;
      Ah[mt] = *(const bf16x8*)(ab);
      Al[mt] = *(const bf16x8*)(ab + 512);       // h=1 frag: +512 ushorts
    }
    #pragma unroll
    for (int nt = 0; nt < 2; ++nt) {
      int xx = xw + nt * 16 + ln + dx;
      bf16x8 Bh = {}, Bl = {};
      if (yok && (unsigned)xx < 512u) {
        const unsigned short* pb = fb + (size_t)(yy * 512 + xx) * 32 + c0;
        Bh = *(const bf16x8*)(pb);
        Bl = *(const bf16x8*)(pb + 16);
      }
      #pragma unroll
      for (int mt = 0; mt < 2; ++mt) {
        acc[mt][nt] = __builtin_amdgcn_mfma_f32_16x16x32_bf16(Ah[mt], Bh, acc[mt][nt], 0, 0, 0);
        acc[mt][nt] = __builtin_amdgcn_mfma_f32_16x16x32_bf16(Al[mt], Bh, acc[mt][nt], 0, 0, 0);
        acc[mt][nt] = __builtin_amdgcn_mfma_f32_16x16x32_bf16(Ah[mt], Bl, acc[mt][nt], 0, 0, 0);
      }
    }
  }

  // epilogue: BN + gelu + w2-dot (per-lane 4 co x 2 mt), cross-lane co sum,
  // sigmoid, store. D layout: col(px)=lane&15, row(co_local)=lg*4+reg.
  #pragma unroll
  for (int nt = 0; nt < 2; ++nt) {
    float s2 = 0.0f;
    #pragma unroll
    for (int mt = 0; mt < 2; ++mt)
      #pragma unroll
      for (int r = 0; r < 4; ++r) {
        float t = acc[mt][nt][r] * sc[mt * 4 + r] + sh[mt * 4 + r];
        float t2 = t * t;
        float z = t * (1.5957691216057308f + 0.07135481283247183f * t2);
        float g = t / (1.0f + __expf(-z));       // == 0.5t(1+tanh(.79788(t+.044715t^3)))
        s2 += g * w2v[mt * 4 + r];
      }
    s2 += __shfl_xor(s2, 16);
    s2 += __shfl_xor(s2, 32);
    s2 += b2v;
    float res = 1.0f / (1.0f + __expf(-s2));
    if (lg == 0)
      sal[(size_t)(b0 + bi) * CHW + (size_t)y * 512 + xw + nt * 16 + ln] = res;
  }
}

// ---------------------------------------------------------------- resize + box partials
__global__ __launch_bounds__(256) void k_resize(const float* __restrict__ sal,
                                                float* __restrict__ masks,
                                                int* __restrict__ part) {
  int b = blockIdx.y;
  int blk = blockIdx.x;
  int t = threadIdx.x;
  const float* sp = sal + (size_t)b * CHW;
  float* mp = masks + (size_t)b * FULLHW;
  int mnX = 0x7FFFFFFF, mxX = -1, mnY = 0x7FFFFFFF, mxY = -1;
  int c0 = 4 * t;
  #pragma unroll
  for (int r = 0; r < 4; ++r) {
    int Y = blk * 4 + r;
    int y0 = (Y - 1) >> 1;
    float wy = (Y & 1) ? 0.25f : 0.75f;
    int y0c = y0 < 0 ? 0 : y0, y1c = (y0 + 1 > 511) ? 511 : y0 + 1;
    const float* r0 = sp + y0c * 512;
    const float* r1 = sp + y1c * 512;
    float o[4];
    #pragma unroll
    for (int j = 0; j < 4; ++j) {
      int X = c0 + j;
      int x0 = (X - 1) >> 1;
      float wx = (X & 1) ? 0.25f : 0.75f;
      int x0c = x0 < 0 ? 0 : x0, x1c = (x0 + 1 > 511) ? 511 : x0 + 1;
      float v00 = r0[x0c], v01 = r0[x1c], v10 = r1[x0c], v11 = r1[x1c];
      o[j] = (1.0f - wy) * ((1.0f - wx) * v00 + wx * v01)
           + wy * ((1.0f - wx) * v10 + wx * v11);
      if (o[j] > 0.5f) {
        mnX = min(mnX, X); mxX = max(mxX, X);
        mnY = min(mnY, Y); mxY = max(mxY, Y);
      }
    }
    *(float4*)(mp + (size_t)Y * 1024 + c0) = make_float4(o[0], o[1], o[2], o[3]);
  }
  __shared__ int s0[256], s1[256], s2[256], s3[256];
  s0[t] = mnX; s1[t] = mxX; s2[t] = mnY; s3[t] = mxY;
  __syncthreads();
  for (int off = 128; off > 0; off >>= 1) {
    if (t < off) {
      s0[t] = min(s0[t], s0[t + off]); s1[t] = max(s1[t], s1[t + off]);
      s2[t] = min(s2[t], s2[t + off]); s3[t] = max(s3[t], s3[t + off]);
    }
    __syncthreads();
  }
  if (t == 0) {
    int* pp = part + (b * 256 + blk) * 4;
    pp[0] = s0[0]; pp[1] = s1[0]; pp[2] = s2[0]; pp[3] = s3[0];
  }
}

// ---------------------------------------------------------------- box reduce -> out
__global__ __launch_bounds__(256) void k_boxreduce(const int* __restrict__ part,
                                                   float* __restrict__ out) {
  int b = blockIdx.x, t = threadIdx.x;
  const int* pp = part + (b * 256 + t) * 4;
  __shared__ int s0[256], s1[256], s2[256], s3[256];
  s0[t] = pp[0]; s1[t] = pp[1]; s2[t] = pp[2]; s3[t] = pp[3];
  __syncthreads();
  for (int off = 128; off > 0; off >>= 1) {
    if (t < off) {
      s0[t] = min(s0[t], s0[t + off]); s1[t] = max(s1[t], s1[t + off]);
      s2[t] = min(s2[t], s2[t + off]); s3[t] = max(s3[t], s3[t + off]);
    }
    __syncthreads();
  }
  if (t == 0) {
    float x0, y0, x1, y1;
    if (s3[0] < 0) { x0 = 0.0f; y0 = 0.0f; x1 = 1023.0f; y1 = 1023.0f; }
    else { x0 = (float)s0[0]; y0 = (float)s2[0]; x1 = (float)s1[0]; y1 = (float)s3[0]; }
    out[240 + b * 4 + 0] = x0;
    out[240 + b * 4 + 1] = y0;
    out[240 + b * 4 + 2] = x1;
    out[240 + b * 4 + 3] = y1;
  }
}

// ---------------------------------------------------------------- peak helper
__device__ inline bool is_peak(const float* __restrict__ sp, int x, int y, float& sv) {
  float s = sp[y * 512 + x];
  sv = s;
  if (!(s > 0.0f)) return false;
  int x0 = (x > 0) ? x - 1 : x, x1 = (x < 511) ? x + 1 : x;
  int y0 = (y > 0) ? y - 1 : y, y1 = (y < 511) ? y + 1 : y;
  for (int yy = y0; yy <= y1; ++yy)
    for (int xx = x0; xx <= x1; ++xx)
      if (sp[yy * 512 + xx] > s) return false;     // s >= all neighbors == (s==maxpool)
  return true;
}

// ---------------------------------------------------------------- level-1 hist (+peak mask)
// per-block LDS hist -> NON-ATOMIC partial write. h1p[(b*NB1+blk)*4096 + cls*2048 + bin]
__global__ __launch_bounds__(256) void k_hist1(const float* __restrict__ sal,
                                               unsigned* __restrict__ h1p,
                                               unsigned char* __restrict__ pkm) {
  __shared__ unsigned sH[4096];                   // [class][2048]
  int b = blockIdx.y, tid = threadIdx.x;
  for (int i = tid; i < 4096; i += 256) sH[i] = 0;
  __syncthreads();
  const float* sp = sal + (size_t)b * CHW;
  int base = blockIdx.x * 4096;
  for (int it = 0; it < 16; ++it) {
    int p = base + it * 256 + tid;
    int x = p & 511, y = p >> 9;
    float s;
    bool pk = is_peak(sp, x, y, s);
    pkm[(size_t)b * CHW + p] = pk ? 1 : 0;
    unsigned bin = (__float_as_uint(s) >> 21) & 2047;
    atomicAdd(&sH[(pk ? 0 : 2048) + bin], 1u);
  }
  __syncthreads();
  unsigned* dst = h1p + ((size_t)b * NB1 + blockIdx.x) * 4096;
  for (int i = tid; i < 4096; i += 256) dst[i] = sH[i];
}

// ---------------------------------------------------------------- radix scan (sums partials)
// hp layout: [(b*np + p)*4096 + c*2048 + bin]
__global__ __launch_bounds__(256) void k_scan(const unsigned* __restrict__ hp,
                                              int* __restrict__ thr, int level,
                                              int np) {
  int c = blockIdx.x, b = blockIdx.y, t = threadIdx.x;
  __shared__ unsigned sBins[2048];
  __shared__ unsigned sS[256];
  __shared__ int sT;
  unsigned bv[8] = {0, 0, 0, 0, 0, 0, 0, 0};
  for (int p = 0; p < np; ++p) {
    const unsigned* q = hp + ((size_t)(b * np + p)) * 4096 + c * 2048 + t * 8;
    uint4 a = *(const uint4*)(q);
    uint4 d = *(const uint4*)(q + 4);
    bv[0] += a.x; bv[1] += a.y; bv[2] += a.z; bv[3] += a.w;
    bv[4] += d.x; bv[5] += d.y; bv[6] += d.z; bv[7] += d.w;
  }
  unsigned part = 0;
  #pragma unroll
  for (int r = 0; r < 8; ++r) {
    sBins[t * 8 + r] = bv[r];
    part += bv[r];
  }
  sS[t] = part;
  __syncthreads();
  for (int off = 1; off < 256; off <<= 1) {
    unsigned add = (t + off < 256) ? sS[t + off] : 0;
    __syncthreads();
    sS[t] += add;
    __syncthreads();
  }
  int K = (c == 0) ? 512 : 10;
  int* tb = thr + (c * 8 + b) * 4;
  if (level == 1) { K -= tb[1]; if (K < 1) K = 1; }
  if (t == 0) sT = -1;
  __syncthreads();
  if (sS[t] >= (unsigned)K && (t == 255 || sS[t + 1] < (unsigned)K)) sT = t;
  __syncthreads();
  if (t == 0) {
    int T = 0;
    unsigned run = 0;
    if (sT >= 0) {
      int ts = sT;
      run = (ts < 255) ? sS[ts + 1] : 0;
      for (int r = 7; r >= 0; --r) {
        unsigned v = sBins[ts * 8 + r];
        run += v;
        if (run >= (unsigned)K) { T = ts * 8 + r; run -= v; break; }
      }
    } else {
      T = 0;
      run = sS[0] - sBins[0];                     // suffix(1); take everything
    }
    if (level == 0) { tb[0] = T; tb[1] = (int)run; }
    else           { tb[2] = (tb[0] << 11) | T; }
  }
}

// ---------------------------------------------------------------- level-2 hist
// per-block LDS hist (both classes) -> NON-ATOMIC partial write.
// h2p[(b*NB2+blk)*4096 + c*2048 + bin]. Vectorized float4/uchar4 input.
__global__ __launch_bounds__(256) void k_hist2(const float* __restrict__ sal,
                                               const unsigned char* __restrict__ pkm,
                                               const int* __restrict__ thr,
                                               unsigned* __restrict__ h2p) {
  __shared__ unsigned sH[4096];
  int b = blockIdx.y, tid = threadIdx.x;
  for (int i = tid; i < 4096; i += 256) sH[i] = 0;
  __syncthreads();
  int t0 = thr[(0 * 8 + b) * 4];
  int t1 = thr[(1 * 8 + b) * 4];
  const float* sp = sal + (size_t)b * CHW;
  const unsigned char* pp = pkm + (size_t)b * CHW;
  int base = blockIdx.x * 8192;
  for (int it = 0; it < 8; ++it) {
    int p = base + it * 1024 + tid * 4;
    float4 s4 = *(const float4*)(sp + p);
    unsigned pk4 = *(const unsigned*)(pp + p);
    float sv[4] = {s4.x, s4.y, s4.z, s4.w};
    #pragma unroll
    for (int j = 0; j < 4; ++j) {
      bool pk = ((pk4 >> (8 * j)) & 255u) != 0;
      unsigned bits = __float_as_uint(sv[j]);
      int tt = pk ? t0 : t1;
      if ((int)(bits >> 21) == tt)
        atomicAdd(&sH[(pk ? 0 : 2048) + ((bits >> 10) & 2047)], 1u);
    }
  }
  __syncthreads();
  unsigned* dst = h2p + ((size_t)b * NB2 + blockIdx.x) * 4096;
  for (int i = tid; i < 4096; i += 256) dst[i] = sH[i];
}

// ---------------------------------------------------------------- compact
__global__ __launch_bounds__(256) void k_compact(const float* __restrict__ sal,
                                                 const unsigned char* __restrict__ pkm,
                                                 const int* __restrict__ thr,
                                                 unsigned* __restrict__ cnt,
                                                 unsigned long long* __restrict__ cand) {
  int b = blockIdx.y;
  int p = blockIdx.x * 256 + threadIdx.x;
  const float* sp = sal + (size_t)b * CHW;
  bool pk = pkm[(size_t)b * CHW + p] != 0;
  float s = sp[p];
  int c = pk ? 0 : 1;
  unsigned bits = __float_as_uint(s);
  unsigned q = (unsigned)thr[(c * 8 + b) * 4 + 2];
  if ((bits >> 10) >= q) {
    unsigned pos = atomicAdd(&cnt[c * 8 + b], 1u);
    if (pos < 1024)
      cand[((size_t)(c * 8 + b) << 10) + pos] =
          ((unsigned long long)bits << 32) | (unsigned)(~p);   // score desc, idx asc
  }
}

// ---------------------------------------------------------------- sort + NMS
__device__ inline void bitonic1024_desc(unsigned long long* sKey) {
  int t = threadIdx.x;
  for (unsigned k = 2; k <= 1024; k <<= 1) {
    for (unsigned j = k >> 1; j > 0; j >>= 1) {
      __syncthreads();
      #pragma unroll
      for (int e = 0; e < 2; ++e) {
        unsigned i = (unsigned)t + (unsigned)e * 512u;
        unsigned l = i ^ j;
        if (l > i) {
          unsigned long long a = sKey[i], bb = sKey[l];
          if (((i & k) == 0) ? (a < bb) : (a > bb)) { sKey[i] = bb; sKey[l] = a; }
        }
      }
    }
  }
  __syncthreads();
}

__global__ __launch_bounds__(512) void k_nms(const unsigned long long* __restrict__ cand,
                                             const unsigned* __restrict__ cnt,
                                             float* __restrict__ out) {
  __shared__ unsigned long long sKey[1024];
  __shared__ unsigned sIdx[512];
  __shared__ int sAvail[512];
  __shared__ int sSel[16];
  int b = blockIdx.x, t = threadIdx.x;
  if (t < 10) out[160 + b * 10 + t] = 1.0f;       // labels
  int Cp = (int)cnt[b]; if (Cp > 1024) Cp = 1024;
  const unsigned long long* cp = cand + ((size_t)b << 10);
  sKey[t] = (t < Cp) ? cp[t] : 0ULL;
  sKey[t + 512] = (t + 512 < Cp) ? cp[t + 512] : 0ULL;
  bitonic1024_desc(sKey);
  sIdx[t] = (unsigned)(~sKey[t]);
  int ncand = (Cp < 512) ? Cp : 512;              // K_PEAKS cap
  sAvail[t] = (t < ncand) ? 1 : 0;
  __syncthreads();
  int nsel = 0;
  for (int i = 0; i < 512 && nsel < 10; ++i) {
    if (sAvail[i] != 0) {                         // uniform branch
      unsigned pi = sIdx[i];
      int xi = (int)(pi & 511), yi = (int)(pi >> 9);
      if (t > i && sAvail[t]) {
        int dx = (int)(sIdx[t] & 511) - xi;
        int dy = (int)(sIdx[t] >> 9) - yi;
        if (dx * dx + dy * dy < 625) sAvail[t] = 0;   // dist < 25
      }
      if (t == 0) sSel[nsel] = (int)pi;
      ++nsel;
      __syncthreads();
    }
  }
  __syncthreads();
  // fallback: top-10 non-peak pixels
  int Cf = (int)cnt[8 + b]; if (Cf > 1024) Cf = 1024;
  const unsigned long long* cf = cand + ((size_t)(8 + b) << 10);
  sKey[t] = (t < Cf) ? cf[t] : 0ULL;
  sKey[t + 512] = (t + 512 < Cf) ? cf[t + 512] : 0ULL;
  bitonic1024_desc(sKey);
  if (t < 10) {
    int fi;
    if (t < nsel) fi = sSel[t];
    else { int r = t - nsel; if (r > 9) r = 9; fi = (int)((unsigned)(~sKey[r])); }
    out[((size_t)b * 10 + t) * 2 + 0] = (float)(fi & 511) * (1.0f / 512.0f);
    out[((size_t)b * 10 + t) * 2 + 1] = (float)(fi >> 9) * (1.0f / 512.0f);
  }
}

// ---------------------------------------------------------------------------
extern "C" void kernel_launch(void* const* d_in, const int* in_sizes, int n_in,
                              void* d_out, int out_size, void* d_ws, size_t ws_size,
                              hipStream_t stream) {
  const float* rgb  = (const float*)d_in[0];
  const float* dep  = (const float*)d_in[1];
  const float* w1   = (const float*)d_in[2];
  const float* b1   = (const float*)d_in[3];
  const float* gam  = (const float*)d_in[4];
  const float* bet  = (const float*)d_in[5];
  const float* bmn  = (const float*)d_in[6];
  const float* bvr  = (const float*)d_in[7];
  const float* w2   = (const float*)d_in[8];
  const float* b2   = (const float*)d_in[9];
  float* out = (float*)d_out;
  char* ws = (char*)d_ws;

  float* sal = (float*)(ws + OFF_SAL);
  int* thr = (int*)(ws + OFF_THR);
  unsigned* cnt = (unsigned*)(ws + OFF_CNT);
  unsigned long long* cand = (unsigned long long*)(ws + OFF_CAND);
  int* part = (int*)(ws + OFF_PART);
  unsigned short* apack = (unsigned short*)(ws + OFF_APACK);
  float* ep = (float*)(ws + OFF_EP);
  unsigned char* pkm = (unsigned char*)(ws + OFF_PKM);

  // dynamic region, phase 1 (conv): ebuf (nb*2MB) then freq2 (nb*16MB)
  size_t perE = (size_t)2 * CHW * 4;             // 2 MB / batch
  size_t perF = (size_t)CHW * 64;                // 16 MB / batch
  long long avail = (long long)ws_size - (long long)OFF_DYN;
  int nb = 1;
  if (avail >= (long long)(perE + perF)) {
    long long m = avail / (long long)(perE + perF);
    nb = (m > 8) ? 8 : (int)m;
  }
  float* ebuf = (float*)(ws + OFF_DYN);
  unsigned short* freq2 = (unsigned short*)(ws + OFF_DYN + perE * (size_t)nb);
  // dynamic region, phase 2 (hist): partials overlap the dead conv buffers
  unsigned* h1p = (unsigned*)(ws + OFF_DYN);                       // 8 MB
  unsigned* h2p = (unsigned*)(ws + OFF_DYN + (size_t)8 * NB1 * 4096 * 4);  // 4 MB

  k_init<<<256, 256, 0, stream>>>(cnt, w1, b1, gam, bet, bmn, bvr, w2, b2,
                                  apack, ep);

  for (int b0 = 0; b0 < 8; b0 += nb) {
    int nbc = (8 - b0 < nb) ? (8 - b0) : nb;
    k_freq<<<dim3(512, nbc), 256, 0, stream>>>(rgb, dep, freq2, ebuf, b0);
    k_smooth<<<dim3(1024, nbc), 256, 0, stream>>>(ebuf, freq2);
    k_conv<<<dim3(4, 512, nbc), 256, 0, stream>>>(freq2, apack, ep, sal, b0);
  }

  k_resize<<<dim3(256, 8), 256, 0, stream>>>(sal, out + 272, part);
  k_boxreduce<<<8, 256, 0, stream>>>(part, out);
  k_hist1<<<dim3(NB1, 8), 256, 0, stream>>>(sal, h1p, pkm);
  k_scan<<<dim3(2, 8), 256, 0, stream>>>(h1p, thr, 0, NB1);
  k_hist2<<<dim3(NB2, 8), 256, 0, stream>>>(sal, pkm, thr, h2p);
  k_scan<<<dim3(2, 8), 256, 0, stream>>>(h2p, thr, 1, NB2);
  k_compact<<<dim3(1024, 8), 256, 0, stream>>>(sal, pkm, thr, cnt, cand);
  k_nms<<<8, 512, 0, stream>>>(cand, cnt, out);
}

// Round 4
// 581.683 us; speedup vs baseline: 1.6721x; 1.0518x over previous
//
#include <hip/hip_runtime.h>
#include <math.h>

// ---------------------------------------------------------------------------
// PromptGenerate: DWT->E->smooth->conv1+BN+GELU->conv2->sigmoid (sal, 512x512)
//  -> bilinear 2x upsample (masks), boxes from mask>0.5, greedy-NMS peak coords
// R6: k_conv on bf16 MFMA hi/lo 3-term. R8: hist kernels -> LDS + non-atomic
//     partials (killed 270us cross-XCD atomic ping-pong).
// R9: k_conv was VALU-issue-bound (52% busy, ~1400 insts/wave vs 60 MFMA).
//     (a) freq2 physically zero-padded 514x514 -> no bounds checks/cndmask;
//         B addr = per-lane base + compile-time shift offset.
//     (b) 16x16x32 -> 32x32x16 MFMA: M=32co x N=32px in ONE fragment, K=16 =
//         one shift x 16ch -> zero-shift dropped: 27 MFMAs (was 60), better
//         rate. D: col=lane&31, row=(reg&3)+8*(reg>>2)+4*(lane>>5) [verified].
//     (c) epilogue tables pre-reordered to register order.
//     k_hist1 vectorized (float4 rows + max3 peak test, 9 loads/4px vs 36);
//     k_compact vectorized (float4/uchar4).
// ---------------------------------------------------------------------------

#define CHW 262144          // 512*512
#define FULLHW 1048576      // 1024*1024
#define NB1 64              // k_hist1 blocks per batch (4096 px each)
#define NB2 32              // k_hist2 blocks per batch (8192 px each)
#define PROW 514            // padded row stride (records)
#define PREC (514*514)      // padded records per batch

typedef __attribute__((ext_vector_type(8))) short bf16x8;
typedef __attribute__((ext_vector_type(16))) float f32x16;

static __device__ __forceinline__ unsigned short f2bf(float x) {
  unsigned u = __float_as_uint(x);
  u += 0x7FFFu + ((u >> 16) & 1u);
  return (unsigned short)(u >> 16);
}
static __device__ __forceinline__ float bf2f(unsigned short h) {
  return __uint_as_float(((unsigned)h) << 16);
}

static constexpr size_t OFF_SAL   = 0;                       // 8*CHW*4
static constexpr size_t OFF_THR   = 8388608;                 // 256
static constexpr size_t OFF_CNT   = OFF_THR + 256;           // 256
static constexpr size_t OFF_CAND  = OFF_CNT + 256;           // 131072
static constexpr size_t OFF_PART  = OFF_CAND + 131072;       // 32768
static constexpr size_t OFF_APACK = OFF_PART + 32768;        // 18432 used
static constexpr size_t OFF_EP    = OFF_APACK + 20480;       // 512 (epilogue)
static constexpr size_t OFF_PKM   = OFF_EP + 512;            // 8*CHW u8
static constexpr size_t OFF_DYN   = OFF_PKM + 2097152;
// dynamic region (temporally disjoint uses):
//   conv phase : ebuf (nb*2MB) + freq2 (nb*PREC*64B ~= 16.9MB)
//   hist phase : h1p (8MB) + h2p (4MB)

// shift s = ky*3+kx (0..8)
static constexpr int SDY[9] = {-1,-1,-1, 0,0,0, 1,1,1};
static constexpr int SDX[9] = {-1, 0, 1,-1,0,1,-1,0,1};

// ---------------------------------------------------------------- init + weight pack
// apack (ushort): idx = ((s*2+h)*64 + lane)*8 + e ; co=lane&31,
//   c=(lane>>5)*8+e ; val = (c<12) ? w1[co][c][s] : 0 ; h=0 hi, h=1 lo.
// ep (float): reordered to 32x32 D-register order, co=(reg&3)+8*(reg>>2)+4*kg:
//   [0,32) sc[kg][reg] | [32,64) shift | [64,96) w2 | [96] b2
__global__ void k_init(unsigned* __restrict__ cnt,
                       const float* __restrict__ w1, const float* __restrict__ b1,
                       const float* __restrict__ gam, const float* __restrict__ bet,
                       const float* __restrict__ mean, const float* __restrict__ var,
                       const float* __restrict__ w2, const float* __restrict__ b2,
                       unsigned short* __restrict__ apack, float* __restrict__ ep) {
  int i = blockIdx.x * 256 + threadIdx.x;
  if (i < 16) cnt[i] = 0;
  if (i < 9216) {
    int e = i & 7, lane = (i >> 3) & 63, frag = i >> 9;   // frag 0..17
    int s = frag >> 1, hh = frag & 1;
    int co = lane & 31;
    int c = ((lane >> 5) << 3) + e;
    float val = (c < 12) ? w1[co * 108 + c * 9 + s] : 0.0f;
    unsigned short hb = f2bf(val);
    apack[i] = hh ? f2bf(val - bf2f(hb)) : hb;
  }
  if (i < 96) {
    int t = i >> 5, rem = i & 31, kg = rem >> 4, reg = rem & 15;
    int co = (reg & 3) + 8 * (reg >> 2) + 4 * kg;
    float sc = gam[co] * rsqrtf(var[co] + 1e-5f);
    float v = (t == 0) ? sc
            : (t == 1) ? (b1[co] - mean[co]) * sc + bet[co]
                       : w2[co];
    ep[i] = v;
  } else if (i == 96) {
    ep[96] = b2[0];
  }
}

// ---------------------------------------------------------------- border zero
__global__ __launch_bounds__(256) void k_zero(unsigned short* __restrict__ freq2) {
  int i = blockIdx.x * 256 + threadIdx.x;        // uint4 index within border
  int bi = blockIdx.y;
  if (i >= 8208) return;                          // 2052 records * 4 uint4
  int rec = i >> 2, q = i & 3;
  int row, col;
  if (rec < 514)       { row = 0;   col = rec; }
  else if (rec < 1028) { row = 513; col = rec - 514; }
  else if (rec < 1540) { row = rec - 1028 + 1; col = 0; }
  else                 { row = rec - 1540 + 1; col = 513; }
  uint4* p = (uint4*)(freq2 + ((size_t)bi * PREC + (size_t)row * PROW + col) * 32) + q;
  *p = make_uint4(0u, 0u, 0u, 0u);
}

// ---------------------------------------------------------------- freq ch 0..9
// writes channel-last bf16 hi/lo into PADDED freq2: record (y+1, x+1).
// ch10..15 zeroed here (10,11 filled by k_smooth). Er/Ed also to f32 ebuf.
__global__ __launch_bounds__(256) void k_freq(const float* __restrict__ rgb,
                                              const float* __restrict__ dep,
                                              unsigned short* __restrict__ freq2,
                                              float* __restrict__ ebuf, int b0) {
  int t = blockIdx.x * 256 + threadIdx.x;        // [0, 131072)
  int bi = blockIdx.y;
  int b = b0 + bi;
  int xp = t & 255, y = t >> 8;                  // xp: pair idx, outputs x=2xp,2xp+1
  const float* base = rgb + (size_t)b * 3 * FULLHW + (size_t)(2 * y) * 1024 + 4 * xp;
  float4 R0 = *(const float4*)(base);
  float4 R1 = *(const float4*)(base + 1024);
  float4 G0 = *(const float4*)(base + FULLHW);
  float4 G1 = *(const float4*)(base + FULLHW + 1024);
  float4 Bl0 = *(const float4*)(base + 2 * FULLHW);
  float4 Bl1 = *(const float4*)(base + 2 * FULLHW + 1024);
  const float* dbase = dep + (size_t)b * FULLHW + (size_t)(2 * y) * 1024 + 4 * xp;
  float4 D0 = *(const float4*)(dbase);
  float4 D1 = *(const float4*)(dbase + 1024);

  float gt[4], gb[4], dt[4], db_[4];
  gt[0] = (R0.x + G0.x + Bl0.x) / 3.0f; gt[1] = (R0.y + G0.y + Bl0.y) / 3.0f;
  gt[2] = (R0.z + G0.z + Bl0.z) / 3.0f; gt[3] = (R0.w + G0.w + Bl0.w) / 3.0f;
  gb[0] = (R1.x + G1.x + Bl1.x) / 3.0f; gb[1] = (R1.y + G1.y + Bl1.y) / 3.0f;
  gb[2] = (R1.z + G1.z + Bl1.z) / 3.0f; gb[3] = (R1.w + G1.w + Bl1.w) / 3.0f;
  dt[0] = D0.x; dt[1] = D0.y; dt[2] = D0.z; dt[3] = D0.w;
  db_[0] = D1.x; db_[1] = D1.y; db_[2] = D1.z; db_[3] = D1.w;

  unsigned short hs[2][16], ls[2][16];
  float er[2], ed[2];
  #pragma unroll
  for (int j = 0; j < 2; ++j) {
    float a = gt[2 * j] * 0.5f, bb = gb[2 * j] * 0.5f;
    float c = gt[2 * j + 1] * 0.5f, d = gb[2 * j + 1] * 0.5f;
    float v[10];
    v[0] = a + bb; v[1] = a - bb; v[2] = c + d; v[3] = c - d;
    float da = dt[2 * j] * 0.5f, db2 = db_[2 * j] * 0.5f;
    float dc = dt[2 * j + 1] * 0.5f, dd = db_[2 * j + 1] * 0.5f;
    v[4] = da + db2; v[5] = da - db2; v[6] = dc + dd; v[7] = dc - dd;
    v[8] = sqrtf(v[1] * v[1] + v[2] * v[2] + v[3] * v[3] + 1e-8f);
    v[9] = sqrtf(v[5] * v[5] + v[6] * v[6] + v[7] * v[7] + 1e-8f);
    er[j] = v[8]; ed[j] = v[9];
    #pragma unroll
    for (int cc = 0; cc < 10; ++cc) {
      unsigned short hb = f2bf(v[cc]);
      hs[j][cc] = hb;
      ls[j][cc] = f2bf(v[cc] - bf2f(hb));
    }
    #pragma unroll
    for (int cc = 10; cc < 16; ++cc) { hs[j][cc] = 0; ls[j][cc] = 0; }
  }
  unsigned short* dst = freq2 +
      ((size_t)bi * PREC + (size_t)(y + 1) * PROW + (2 * xp + 1)) * 32;
  uint4* d4 = (uint4*)dst;
  d4[0] = ((const uint4*)hs[0])[0]; d4[1] = ((const uint4*)hs[0])[1];
  d4[2] = ((const uint4*)ls[0])[0]; d4[3] = ((const uint4*)ls[0])[1];
  d4[4] = ((const uint4*)hs[1])[0]; d4[5] = ((const uint4*)hs[1])[1];
  d4[6] = ((const uint4*)ls[1])[0]; d4[7] = ((const uint4*)ls[1])[1];
  float* eb = ebuf + (size_t)bi * 2 * CHW + (size_t)y * 512 + 2 * xp;
  *(float2*)(eb) = make_float2(er[0], er[1]);
  *(float2*)(eb + CHW) = make_float2(ed[0], ed[1]);
}

// ---------------------------------------------------------------- freq ch 10,11
__constant__ float GW[25] = {
  0.00296901f, 0.01330621f, 0.02193824f, 0.01330621f, 0.00296901f,
  0.01330621f, 0.05963435f, 0.09832035f, 0.05963435f, 0.01330621f,
  0.02193824f, 0.09832035f, 0.16210276f, 0.09832035f, 0.02193824f,
  0.01330621f, 0.05963435f, 0.09832035f, 0.05963435f, 0.01330621f,
  0.00296901f, 0.01330621f, 0.02193824f, 0.01330621f, 0.00296901f};

__global__ __launch_bounds__(256) void k_smooth(const float* __restrict__ ebuf,
                                                unsigned short* __restrict__ freq2) {
  int t = blockIdx.x * 256 + threadIdx.x;
  int bi = blockIdx.y;
  int x = t & 511, y = t >> 9;
  const float* eb = ebuf + (size_t)bi * 2 * CHW;
  float accv[2];
  #pragma unroll
  for (int ch = 0; ch < 2; ++ch) {
    const float* fin = eb + ch * CHW;
    float acc = 0.0f;
    #pragma unroll
    for (int i = 0; i < 5; ++i) {
      int yy = y + i - 2;
      if (yy < 0 || yy > 511) continue;
      #pragma unroll
      for (int j = 0; j < 5; ++j) {
        int xx = x + j - 2;
        if (xx < 0 || xx > 511) continue;
        acc += GW[i * 5 + j] * fin[yy * 512 + xx];
      }
    }
    accv[ch] = acc;
  }
  unsigned short* px = freq2 +
      ((size_t)bi * PREC + (size_t)(y + 1) * PROW + (x + 1)) * 32;
  unsigned short h0 = f2bf(accv[0]), h1 = f2bf(accv[1]);
  unsigned short l0 = f2bf(accv[0] - bf2f(h0)), l1 = f2bf(accv[1] - bf2f(h1));
  *(unsigned*)(px + 10) = (unsigned)h0 | ((unsigned)h1 << 16);
  *(unsigned*)(px + 26) = (unsigned)l0 | ((unsigned)l1 << 16);
}

// ---------------------------------------------------------------- conv fused (MFMA)
// Wave = 32 px x-strip (N) x 32 co (M), 32x32x16 bf16: one fragment pair per
// shift (K=16 = 16 padded ch). 9 shifts x 3 precision terms = 27 MFMAs.
// Padded freq2 -> zero bounds logic; B addr = lane base + const offset.
__global__ __launch_bounds__(256) void k_conv(const unsigned short* __restrict__ freq2,
    const unsigned short* __restrict__ apack, const float* __restrict__ ep,
    float* __restrict__ sal, int b0) {
  int tid = threadIdx.x;
  int l = tid & 63, wv = tid >> 6;
  int y = blockIdx.y;
  int xw = blockIdx.x * 128 + wv * 32;
  int bi = blockIdx.z;
  int n = l & 31, kg = l >> 5;

  const unsigned short* fb = freq2 + (size_t)bi * PREC * 32;
  const unsigned short* pb0 = fb + ((size_t)(y + 1) * PROW + (xw + n + 1)) * 32 + kg * 8;
  const unsigned short* ab = apack + l * 8;

  f32x16 acc = {};
  #pragma unroll
  for (int s = 0; s < 9; ++s) {
    const int doff = (SDY[s] * PROW + SDX[s]) * 32;   // compile-time
    const unsigned short* pb = pb0 + doff;
    bf16x8 Bh = *(const bf16x8*)(pb);
    bf16x8 Bl = *(const bf16x8*)(pb + 16);
    bf16x8 Ah = *(const bf16x8*)(ab + s * 1024);
    bf16x8 Al = *(const bf16x8*)(ab + s * 1024 + 512);
    acc = __builtin_amdgcn_mfma_f32_32x32x16_bf16(Ah, Bh, acc, 0, 0, 0);
    acc = __builtin_amdgcn_mfma_f32_32x32x16_bf16(Al, Bh, acc, 0, 0, 0);
    acc = __builtin_amdgcn_mfma_f32_32x32x16_bf16(Ah, Bl, acc, 0, 0, 0);
  }

  // epilogue: BN + gelu + w2-dot over 16 regs (co=(reg&3)+8*(reg>>2)+4*kg),
  // pair-lane reduce (l ^ 32), sigmoid, store px n by lanes 0..31.
  const float* e0 = ep + kg * 16;
  const float* e1 = ep + 32 + kg * 16;
  const float* e2 = ep + 64 + kg * 16;
  float s2 = 0.0f;
  #pragma unroll
  for (int r = 0; r < 16; ++r) {
    float t = acc[r] * e0[r] + e1[r];
    float z = t * (1.5957691216057308f + 0.07135481283247183f * (t * t));
    s2 += (t / (1.0f + __expf(-z))) * e2[r];   // == gelu(t)
  }
  s2 += __shfl_xor(s2, 32);
  s2 += ep[96];
  float res = 1.0f / (1.0f + __expf(-s2));
  if (l < 32)
    sal[(size_t)(b0 + bi) * CHW + (size_t)y * 512 + xw + n] = res;
}

// ---------------------------------------------------------------- resize + box partials
__global__ __launch_bounds__(256) void k_resize(const float* __restrict__ sal,
                                                float* __restrict__ masks,
                                                int* __restrict__ part) {
  int b = blockIdx.y;
  int blk = blockIdx.x;
  int t = threadIdx.x;
  const float* sp = sal + (size_t)b * CHW;
  float* mp = masks + (size_t)b * FULLHW;
  int mnX = 0x7FFFFFFF, mxX = -1, mnY = 0x7FFFFFFF, mxY = -1;
  int c0 = 4 * t;
  #pragma unroll
  for (int r = 0; r < 4; ++r) {
    int Y = blk * 4 + r;
    int y0 = (Y - 1) >> 1;
    float wy = (Y & 1) ? 0.25f : 0.75f;
    int y0c = y0 < 0 ? 0 : y0, y1c = (y0 + 1 > 511) ? 511 : y0 + 1;
    const float* r0 = sp + y0c * 512;
    const float* r1 = sp + y1c * 512;
    float o[4];
    #pragma unroll
    for (int j = 0; j < 4; ++j) {
      int X = c0 + j;
      int x0 = (X - 1) >> 1;
      float wx = (X & 1) ? 0.25f : 0.75f;
      int x0c = x0 < 0 ? 0 : x0, x1c = (x0 + 1 > 511) ? 511 : x0 + 1;
      float v00 = r0[x0c], v01 = r0[x1c], v10 = r1[x0c], v11 = r1[x1c];
      o[j] = (1.0f - wy) * ((1.0f - wx) * v00 + wx * v01)
           + wy * ((1.0f - wx) * v10 + wx * v11);
      if (o[j] > 0.5f) {
        mnX = min(mnX, X); mxX = max(mxX, X);
        mnY = min(mnY, Y); mxY = max(mxY, Y);
      }
    }
    *(float4*)(mp + (size_t)Y * 1024 + c0) = make_float4(o[0], o[1], o[2], o[3]);
  }
  __shared__ int s0[256], s1[256], s2[256], s3[256];
  s0[t] = mnX; s1[t] = mxX; s2[t] = mnY; s3[t] = mxY;
  __syncthreads();
  for (int off = 128; off > 0; off >>= 1) {
    if (t < off) {
      s0[t] = min(s0[t], s0[t + off]); s1[t] = max(s1[t], s1[t + off]);
      s2[t] = min(s2[t], s2[t + off]); s3[t] = max(s3[t], s3[t + off]);
    }
    __syncthreads();
  }
  if (t == 0) {
    int* pp = part + (b * 256 + blk) * 4;
    pp[0] = s0[0]; pp[1] = s1[0]; pp[2] = s2[0]; pp[3] = s3[0];
  }
}

// ---------------------------------------------------------------- box reduce -> out
__global__ __launch_bounds__(256) void k_boxreduce(const int* __restrict__ part,
                                                   float* __restrict__ out) {
  int b = blockIdx.x, t = threadIdx.x;
  const int* pp = part + (b * 256 + t) * 4;
  __shared__ int s0[256], s1[256], s2[256], s3[256];
  s0[t] = pp[0]; s1[t] = pp[1]; s2[t] = pp[2]; s3[t] = pp[3];
  __syncthreads();
  for (int off = 128; off > 0; off >>= 1) {
    if (t < off) {
      s0[t] = min(s0[t], s0[t + off]); s1[t] = max(s1[t], s1[t + off]);
      s2[t] = min(s2[t], s2[t + off]); s3[t] = max(s3[t], s3[t + off]);
    }
    __syncthreads();
  }
  if (t == 0) {
    float x0, y0, x1, y1;
    if (s3[0] < 0) { x0 = 0.0f; y0 = 0.0f; x1 = 1023.0f; y1 = 1023.0f; }
    else { x0 = (float)s0[0]; y0 = (float)s2[0]; x1 = (float)s1[0]; y1 = (float)s3[0]; }
    out[240 + b * 4 + 0] = x0;
    out[240 + b * 4 + 1] = y0;
    out[240 + b * 4 + 2] = x1;
    out[240 + b * 4 + 3] = y1;
  }
}

// ---------------------------------------------------------------- level-1 hist (+peak mask)
// vectorized 4px/thread: 3 rows x (float4 + 2 scalars), max3 trees, uchar4 pkm.
// per-block LDS hist -> NON-ATOMIC partials h1p[(b*NB1+blk)*4096 + cls*2048+bin]
__global__ __launch_bounds__(256) void k_hist1(const float* __restrict__ sal,
                                               unsigned* __restrict__ h1p,
                                               unsigned char* __restrict__ pkm) {
  __shared__ unsigned sH[4096];                   // [class][2048]
  int b = blockIdx.y, tid = threadIdx.x;
  for (int i = tid; i < 4096; i += 256) sH[i] = 0;
  __syncthreads();
  const float* sp = sal + (size_t)b * CHW;
  int base = blockIdx.x * 4096;
  for (int it = 0; it < 4; ++it) {
    int p = base + it * 1024 + tid * 4;
    int x0 = p & 511, y = p >> 9;
    int ym = (y > 0) ? y - 1 : 0, yp = (y < 511) ? y + 1 : 511;
    const float* r0 = sp + ym * 512;
    const float* r1 = sp + y * 512;
    const float* r2 = sp + yp * 512;
    float4 m0 = *(const float4*)(r0 + x0);
    float4 m1 = *(const float4*)(r1 + x0);
    float4 m2 = *(const float4*)(r2 + x0);
    float l0 = x0 ? r0[x0 - 1] : m0.x;
    float l1 = x0 ? r1[x0 - 1] : m1.x;
    float l2 = x0 ? r2[x0 - 1] : m2.x;
    float q0 = (x0 < 508) ? r0[x0 + 4] : m0.w;
    float q1 = (x0 < 508) ? r1[x0 + 4] : m1.w;
    float q2 = (x0 < 508) ? r2[x0 + 4] : m2.w;
    float a0[6] = {l0, m0.x, m0.y, m0.z, m0.w, q0};
    float a1[6] = {l1, m1.x, m1.y, m1.z, m1.w, q1};
    float a2[6] = {l2, m2.x, m2.y, m2.z, m2.w, q2};
    unsigned pw = 0;
    #pragma unroll
    for (int j = 0; j < 4; ++j) {
      float r0m = fmaxf(fmaxf(a0[j], a0[j + 1]), a0[j + 2]);
      float r1m = fmaxf(fmaxf(a1[j], a1[j + 1]), a1[j + 2]);
      float r2m = fmaxf(fmaxf(a2[j], a2[j + 1]), a2[j + 2]);
      float cmax = fmaxf(fmaxf(r0m, r1m), r2m);
      float sv = a1[j + 1];
      bool pk = (sv > 0.0f) && (sv >= cmax);      // no neighbor strictly greater
      pw |= (pk ? 1u : 0u) << (8 * j);
      unsigned bin = (__float_as_uint(sv) >> 21) & 2047;
      atomicAdd(&sH[(pk ? 0 : 2048) + bin], 1u);
    }
    *(unsigned*)(pkm + (size_t)b * CHW + p) = pw;
  }
  __syncthreads();
  unsigned* dst = h1p + ((size_t)b * NB1 + blockIdx.x) * 4096;
  for (int i = tid; i < 4096; i += 256) dst[i] = sH[i];
}

// ---------------------------------------------------------------- radix scan (sums partials)
// hp layout: [(b*np + p)*4096 + c*2048 + bin]
__global__ __launch_bounds__(256) void k_scan(const unsigned* __restrict__ hp,
                                              int* __restrict__ thr, int level,
                                              int np) {
  int c = blockIdx.x, b = blockIdx.y, t = threadIdx.x;
  __shared__ unsigned sBins[2048];
  __shared__ unsigned sS[256];
  __shared__ int sT;
  unsigned bv[8] = {0, 0, 0, 0, 0, 0, 0, 0};
  for (int p = 0; p < np; ++p) {
    const unsigned* q = hp + ((size_t)(b * np + p)) * 4096 + c * 2048 + t * 8;
    uint4 a = *(const uint4*)(q);
    uint4 d = *(const uint4*)(q + 4);
    bv[0] += a.x; bv[1] += a.y; bv[2] += a.z; bv[3] += a.w;
    bv[4] += d.x; bv[5] += d.y; bv[6] += d.z; bv[7] += d.w;
  }
  unsigned part = 0;
  #pragma unroll
  for (int r = 0; r < 8; ++r) {
    sBins[t * 8 + r] = bv[r];
    part += bv[r];
  }
  sS[t] = part;
  __syncthreads();
  for (int off = 1; off < 256; off <<= 1) {
    unsigned add = (t + off < 256) ? sS[t + off] : 0;
    __syncthreads();
    sS[t] += add;
    __syncthreads();
  }
  int K = (c == 0) ? 512 : 10;
  int* tb = thr + (c * 8 + b) * 4;
  if (level == 1) { K -= tb[1]; if (K < 1) K = 1; }
  if (t == 0) sT = -1;
  __syncthreads();
  if (sS[t] >= (unsigned)K && (t == 255 || sS[t + 1] < (unsigned)K)) sT = t;
  __syncthreads();
  if (t == 0) {
    int T = 0;
    unsigned run = 0;
    if (sT >= 0) {
      int ts = sT;
      run = (ts < 255) ? sS[ts + 1] : 0;
      for (int r = 7; r >= 0; --r) {
        unsigned v = sBins[ts * 8 + r];
        run += v;
        if (run >= (unsigned)K) { T = ts * 8 + r; run -= v; break; }
      }
    } else {
      T = 0;
      run = sS[0] - sBins[0];                     // suffix(1); take everything
    }
    if (level == 0) { tb[0] = T; tb[1] = (int)run; }
    else           { tb[2] = (tb[0] << 11) | T; }
  }
}

// ---------------------------------------------------------------- level-2 hist
__global__ __launch_bounds__(256) void k_hist2(const float* __restrict__ sal,
                                               const unsigned char* __restrict__ pkm,
                                               const int* __restrict__ thr,
                                               unsigned* __restrict__ h2p) {
  __shared__ unsigned sH[4096];
  int b = blockIdx.y, tid = threadIdx.x;
  for (int i = tid; i < 4096; i += 256) sH[i] = 0;
  __syncthreads();
  int t0 = thr[(0 * 8 + b) * 4];
  int t1 = thr[(1 * 8 + b) * 4];
  const float* sp = sal + (size_t)b * CHW;
  const unsigned char* pp = pkm + (size_t)b * CHW;
  int base = blockIdx.x * 8192;
  for (int it = 0; it < 8; ++it) {
    int p = base + it * 1024 + tid * 4;
    float4 s4 = *(const float4*)(sp + p);
    unsigned pk4 = *(const unsigned*)(pp + p);
    float sv[4] = {s4.x, s4.y, s4.z, s4.w};
    #pragma unroll
    for (int j = 0; j < 4; ++j) {
      bool pk = ((pk4 >> (8 * j)) & 255u) != 0;
      unsigned bits = __float_as_uint(sv[j]);
      int tt = pk ? t0 : t1;
      if ((int)(bits >> 21) == tt)
        atomicAdd(&sH[(pk ? 0 : 2048) + ((bits >> 10) & 2047)], 1u);
    }
  }
  __syncthreads();
  unsigned* dst = h2p + ((size_t)b * NB2 + blockIdx.x) * 4096;
  for (int i = tid; i < 4096; i += 256) dst[i] = sH[i];
}

// ---------------------------------------------------------------- compact
__global__ __launch_bounds__(256) void k_compact(const float* __restrict__ sal,
                                                 const unsigned char* __restrict__ pkm,
                                                 const int* __restrict__ thr,
                                                 unsigned* __restrict__ cnt,
                                                 unsigned long long* __restrict__ cand) {
  int b = blockIdx.y;
  int p = (blockIdx.x * 256 + threadIdx.x) * 4;
  const float* sp = sal + (size_t)b * CHW;
  float4 s4 = *(const float4*)(sp + p);
  unsigned pk4 = *(const unsigned*)(pkm + (size_t)b * CHW + p);
  unsigned q0 = (unsigned)thr[(0 * 8 + b) * 4 + 2];
  unsigned q1 = (unsigned)thr[(1 * 8 + b) * 4 + 2];
  float sv[4] = {s4.x, s4.y, s4.z, s4.w};
  #pragma unroll
  for (int j = 0; j < 4; ++j) {
    bool pk = ((pk4 >> (8 * j)) & 255u) != 0;
    unsigned bits = __float_as_uint(sv[j]);
    unsigned q = pk ? q0 : q1;
    int c = pk ? 0 : 1;
    if ((bits >> 10) >= q) {
      unsigned pos = atomicAdd(&cnt[c * 8 + b], 1u);
      if (pos < 1024)
        cand[((size_t)(c * 8 + b) << 10) + pos] =
            ((unsigned long long)bits << 32) | (unsigned)(~(p + j));
    }
  }
}

// ---------------------------------------------------------------- sort + NMS
__device__ inline void bitonic1024_desc(unsigned long long* sKey) {
  int t = threadIdx.x;
  for (unsigned k = 2; k <= 1024; k <<= 1) {
    for (unsigned j = k >> 1; j > 0; j >>= 1) {
      __syncthreads();
      #pragma unroll
      for (int e = 0; e < 2; ++e) {
        unsigned i = (unsigned)t + (unsigned)e * 512u;
        unsigned l = i ^ j;
        if (l > i) {
          unsigned long long a = sKey[i], bb = sKey[l];
          if (((i & k) == 0) ? (a < bb) : (a > bb)) { sKey[i] = bb; sKey[l] = a; }
        }
      }
    }
  }
  __syncthreads();
}

__global__ __launch_bounds__(512) void k_nms(const unsigned long long* __restrict__ cand,
                                             const unsigned* __restrict__ cnt,
                                             float* __restrict__ out) {
  __shared__ unsigned long long sKey[1024];
  __shared__ unsigned sIdx[512];
  __shared__ int sAvail[512];
  __shared__ int sSel[16];
  int b = blockIdx.x, t = threadIdx.x;
  if (t < 10) out[160 + b * 10 + t] = 1.0f;       // labels
  int Cp = (int)cnt[b]; if (Cp > 1024) Cp = 1024;
  const unsigned long long* cp = cand + ((size_t)b << 10);
  sKey[t] = (t < Cp) ? cp[t] : 0ULL;
  sKey[t + 512] = (t + 512 < Cp) ? cp[t + 512] : 0ULL;
  bitonic1024_desc(sKey);
  sIdx[t] = (unsigned)(~sKey[t]);
  int ncand = (Cp < 512) ? Cp : 512;              // K_PEAKS cap
  sAvail[t] = (t < ncand) ? 1 : 0;
  __syncthreads();
  int nsel = 0;
  for (int i = 0; i < 512 && nsel < 10; ++i) {
    if (sAvail[i] != 0) {                         // uniform branch
      unsigned pi = sIdx[i];
      int xi = (int)(pi & 511), yi = (int)(pi >> 9);
      if (t > i && sAvail[t]) {
        int dx = (int)(sIdx[t] & 511) - xi;
        int dy = (int)(sIdx[t] >> 9) - yi;
        if (dx * dx + dy * dy < 625) sAvail[t] = 0;   // dist < 25
      }
      if (t == 0) sSel[nsel] = (int)pi;
      ++nsel;
      __syncthreads();
    }
  }
  __syncthreads();
  // fallback: top-10 non-peak pixels
  int Cf = (int)cnt[8 + b]; if (Cf > 1024) Cf = 1024;
  const unsigned long long* cf = cand + ((size_t)(8 + b) << 10);
  sKey[t] = (t < Cf) ? cf[t] : 0ULL;
  sKey[t + 512] = (t + 512 < Cf) ? cf[t + 512] : 0ULL;
  bitonic1024_desc(sKey);
  if (t < 10) {
    int fi;
    if (t < nsel) fi = sSel[t];
    else { int r = t - nsel; if (r > 9) r = 9; fi = (int)((unsigned)(~sKey[r])); }
    out[((size_t)b * 10 + t) * 2 + 0] = (float)(fi & 511) * (1.0f / 512.0f);
    out[((size_t)b * 10 + t) * 2 + 1] = (float)(fi >> 9) * (1.0f / 512.0f);
  }
}

// ---------------------------------------------------------------------------
extern "C" void kernel_launch(void* const* d_in, const int* in_sizes, int n_in,
                              void* d_out, int out_size, void* d_ws, size_t ws_size,
                              hipStream_t stream) {
  const float* rgb  = (const float*)d_in[0];
  const float* dep  = (const float*)d_in[1];
  const float* w1   = (const float*)d_in[2];
  const float* b1   = (const float*)d_in[3];
  const float* gam  = (const float*)d_in[4];
  const float* bet  = (const float*)d_in[5];
  const float* bmn  = (const float*)d_in[6];
  const float* bvr  = (const float*)d_in[7];
  const float* w2   = (const float*)d_in[8];
  const float* b2   = (const float*)d_in[9];
  float* out = (float*)d_out;
  char* ws = (char*)d_ws;

  float* sal = (float*)(ws + OFF_SAL);
  int* thr = (int*)(ws + OFF_THR);
  unsigned* cnt = (unsigned*)(ws + OFF_CNT);
  unsigned long long* cand = (unsigned long long*)(ws + OFF_CAND);
  int* part = (int*)(ws + OFF_PART);
  unsigned short* apack = (unsigned short*)(ws + OFF_APACK);
  float* ep = (float*)(ws + OFF_EP);
  unsigned char* pkm = (unsigned char*)(ws + OFF_PKM);

  // dynamic region, phase 1 (conv): ebuf (nb*2MB) then padded freq2
  size_t perE = (size_t)2 * CHW * 4;             // 2 MB / batch
  size_t perF = (size_t)PREC * 64;               // ~16.9 MB / batch (padded)
  long long avail = (long long)ws_size - (long long)OFF_DYN;
  int nb = 1;
  if (avail >= (long long)(perE + perF)) {
    long long m = avail / (long long)(perE + perF);
    nb = (m > 8) ? 8 : (int)m;
  }
  float* ebuf = (float*)(ws + OFF_DYN);
  unsigned short* freq2 = (unsigned short*)(ws + OFF_DYN + perE * (size_t)nb);
  // dynamic region, phase 2 (hist): partials overlap the dead conv buffers
  unsigned* h1p = (unsigned*)(ws + OFF_DYN);                       // 8 MB
  unsigned* h2p = (unsigned*)(ws + OFF_DYN + (size_t)8 * NB1 * 4096 * 4);  // 4 MB

  k_init<<<40, 256, 0, stream>>>(cnt, w1, b1, gam, bet, bmn, bvr, w2, b2,
                                 apack, ep);
  k_zero<<<dim3(33, nb), 256, 0, stream>>>(freq2);

  for (int b0 = 0; b0 < 8; b0 += nb) {
    int nbc = (8 - b0 < nb) ? (8 - b0) : nb;
    k_freq<<<dim3(512, nbc), 256, 0, stream>>>(rgb, dep, freq2, ebuf, b0);
    k_smooth<<<dim3(1024, nbc), 256, 0, stream>>>(ebuf, freq2);
    k_conv<<<dim3(4, 512, nbc), 256, 0, stream>>>(freq2, apack, ep, sal, b0);
  }

  k_resize<<<dim3(256, 8), 256, 0, stream>>>(sal, out + 272, part);
  k_boxreduce<<<8, 256, 0, stream>>>(part, out);
  k_hist1<<<dim3(NB1, 8), 256, 0, stream>>>(sal, h1p, pkm);
  k_scan<<<dim3(2, 8), 256, 0, stream>>>(h1p, thr, 0, NB1);
  k_hist2<<<dim3(NB2, 8), 256, 0, stream>>>(sal, pkm, thr, h2p);
  k_scan<<<dim3(2, 8), 256, 0, stream>>>(h2p, thr, 1, NB2);
  k_compact<<<dim3(256, 8), 256, 0, stream>>>(sal, pkm, thr, cnt, cand);
  k_nms<<<8, 512, 0, stream>>>(cand, cnt, out);
}

// Round 5
// 524.137 us; speedup vs baseline: 1.8557x; 1.1098x over previous
//
#include <hip/hip_runtime.h>
#include <math.h>

// ---------------------------------------------------------------------------
// PromptGenerate: DWT->E->smooth->conv1+BN+GELU->conv2->sigmoid (sal, 512x512)
//  -> bilinear 2x upsample (masks), boxes from mask>0.5, greedy-NMS peak coords
// R6: k_conv on bf16 MFMA hi/lo 3-term. R8: hist -> LDS + non-atomic partials.
// R9: padded freq2, 32x32x16 MFMA (27/wave). Result: 141us, VGPR=32, occ 81%,
//     MfmaUtil 17%, HBM 13% -> LATENCY-bound: compiler serialized the 36
//     B-loads into ~9 dependent groups (only ~4 loads in flight per wave).
// R10: (a) k_conv phase-split: ALL 18 Bh/Bl pairs prefetched into registers
//      (static-index arrays) before the 27-MFMA chain -> 18 loads in flight,
//      one latency round-trip. VGPR ~120, occ ~50% (deliberate trade).
//      (b) freq2 split into 2 planes of 32B/px: P0=ch0-7 (k_freq streams full
//      lines, no zero-channel stores), P1=[Er,Ed,Ers,Eds,0..] (k_smooth now
//      streams 32B/px instead of 8B-per-64B partial-line RMW on 135MB).
//      k_conv selects plane by kg (c=kg*8+e unchanged).
// ---------------------------------------------------------------------------

#define CHW 262144          // 512*512
#define FULLHW 1048576      // 1024*1024
#define NB1 64              // k_hist1 blocks per batch (4096 px each)
#define NB2 32              // k_hist2 blocks per batch (8192 px each)
#define PROW 514            // padded row stride (records)
#define PREC (514*514)      // padded records per plane per batch

typedef __attribute__((ext_vector_type(8))) short bf16x8;
typedef __attribute__((ext_vector_type(16))) float f32x16;

static __device__ __forceinline__ unsigned short f2bf(float x) {
  unsigned u = __float_as_uint(x);
  u += 0x7FFFu + ((u >> 16) & 1u);
  return (unsigned short)(u >> 16);
}
static __device__ __forceinline__ float bf2f(unsigned short h) {
  return __uint_as_float(((unsigned)h) << 16);
}

static constexpr size_t OFF_SAL   = 0;                       // 8*CHW*4
static constexpr size_t OFF_THR   = 8388608;                 // 256
static constexpr size_t OFF_CNT   = OFF_THR + 256;           // 256
static constexpr size_t OFF_CAND  = OFF_CNT + 256;           // 131072
static constexpr size_t OFF_PART  = OFF_CAND + 131072;       // 32768
static constexpr size_t OFF_APACK = OFF_PART + 32768;        // 18432 used
static constexpr size_t OFF_EP    = OFF_APACK + 20480;       // 512 (epilogue)
static constexpr size_t OFF_PKM   = OFF_EP + 512;            // 8*CHW u8
static constexpr size_t OFF_DYN   = OFF_PKM + 2097152;
// dynamic region (temporally disjoint uses):
//   conv phase : ebuf (nb*2MB) + freq2 (nb * 2 planes * PREC*32B ~= 16.9MB)
//   hist phase : h1p (8MB) + h2p (4MB)

// shift s = ky*3+kx (0..8)
static constexpr int SDY[9] = {-1,-1,-1, 0,0,0, 1,1,1};
static constexpr int SDX[9] = {-1, 0, 1,-1,0,1,-1,0,1};

// ---------------------------------------------------------------- init + weight pack
// apack (ushort): idx = ((s*2+h)*64 + lane)*8 ; co=lane&31, c=(lane>>5)*8+e ;
//   val = (c<12) ? w1[co][c][s] : 0 ; h=0 hi, h=1 lo.
// ep (float): reordered to 32x32 D-register order, co=(reg&3)+8*(reg>>2)+4*kg:
//   [0,32) sc | [32,64) shift | [64,96) w2 | [96] b2
__global__ void k_init(unsigned* __restrict__ cnt,
                       const float* __restrict__ w1, const float* __restrict__ b1,
                       const float* __restrict__ gam, const float* __restrict__ bet,
                       const float* __restrict__ mean, const float* __restrict__ var,
                       const float* __restrict__ w2, const float* __restrict__ b2,
                       unsigned short* __restrict__ apack, float* __restrict__ ep) {
  int i = blockIdx.x * 256 + threadIdx.x;
  if (i < 16) cnt[i] = 0;
  if (i < 9216) {
    int e = i & 7, lane = (i >> 3) & 63, frag = i >> 9;   // frag 0..17
    int s = frag >> 1, hh = frag & 1;
    int co = lane & 31;
    int c = ((lane >> 5) << 3) + e;
    float val = (c < 12) ? w1[co * 108 + c * 9 + s] : 0.0f;
    unsigned short hb = f2bf(val);
    apack[i] = hh ? f2bf(val - bf2f(hb)) : hb;
  }
  if (i < 96) {
    int t = i >> 5, rem = i & 31, kg = rem >> 4, reg = rem & 15;
    int co = (reg & 3) + 8 * (reg >> 2) + 4 * kg;
    float sc = gam[co] * rsqrtf(var[co] + 1e-5f);
    float v = (t == 0) ? sc
            : (t == 1) ? (b1[co] - mean[co]) * sc + bet[co]
                       : w2[co];
    ep[i] = v;
  } else if (i == 96) {
    ep[96] = b2[0];
  }
}

// ---------------------------------------------------------------- border zero
// zero 32B border records of BOTH planes of each batch slot.
__global__ __launch_bounds__(256) void k_zero(unsigned short* __restrict__ freq2) {
  int i = blockIdx.x * 256 + threadIdx.x;        // [0, 8208) uint4 items
  int bi = blockIdx.y;
  if (i >= 8208) return;                          // 2 planes * 2052 recs * 2
  int q = i & 1, r = (i >> 1) % 2052, pl = (i >> 1) / 2052;
  int row, col;
  if (r < 514)        { row = 0;   col = r; }
  else if (r < 1028)  { row = 513; col = r - 514; }
  else if (r < 1540)  { row = r - 1028 + 1; col = 0; }
  else                { row = r - 1540 + 1; col = 513; }
  size_t off = ((size_t)(bi * 2 + pl) * PREC + (size_t)row * PROW + col) * 16;
  uint4* p = (uint4*)(freq2 + off) + q;
  *p = make_uint4(0u, 0u, 0u, 0u);
}

// ---------------------------------------------------------------- freq ch 0..7 (P0)
// P0 record (32B): ch0-7 hi (16B) | ch0-7 lo (16B). Er/Ed -> f32 ebuf.
__global__ __launch_bounds__(256) void k_freq(const float* __restrict__ rgb,
                                              const float* __restrict__ dep,
                                              unsigned short* __restrict__ freq2,
                                              float* __restrict__ ebuf, int b0) {
  int t = blockIdx.x * 256 + threadIdx.x;        // [0, 131072)
  int bi = blockIdx.y;
  int b = b0 + bi;
  int xp = t & 255, y = t >> 8;                  // xp: pair idx, outputs x=2xp,2xp+1
  const float* base = rgb + (size_t)b * 3 * FULLHW + (size_t)(2 * y) * 1024 + 4 * xp;
  float4 R0 = *(const float4*)(base);
  float4 R1 = *(const float4*)(base + 1024);
  float4 G0 = *(const float4*)(base + FULLHW);
  float4 G1 = *(const float4*)(base + FULLHW + 1024);
  float4 Bl0 = *(const float4*)(base + 2 * FULLHW);
  float4 Bl1 = *(const float4*)(base + 2 * FULLHW + 1024);
  const float* dbase = dep + (size_t)b * FULLHW + (size_t)(2 * y) * 1024 + 4 * xp;
  float4 D0 = *(const float4*)(dbase);
  float4 D1 = *(const float4*)(dbase + 1024);

  float gt[4], gb[4], dt[4], db_[4];
  gt[0] = (R0.x + G0.x + Bl0.x) / 3.0f; gt[1] = (R0.y + G0.y + Bl0.y) / 3.0f;
  gt[2] = (R0.z + G0.z + Bl0.z) / 3.0f; gt[3] = (R0.w + G0.w + Bl0.w) / 3.0f;
  gb[0] = (R1.x + G1.x + Bl1.x) / 3.0f; gb[1] = (R1.y + G1.y + Bl1.y) / 3.0f;
  gb[2] = (R1.z + G1.z + Bl1.z) / 3.0f; gb[3] = (R1.w + G1.w + Bl1.w) / 3.0f;
  dt[0] = D0.x; dt[1] = D0.y; dt[2] = D0.z; dt[3] = D0.w;
  db_[0] = D1.x; db_[1] = D1.y; db_[2] = D1.z; db_[3] = D1.w;

  unsigned short hs[2][8], ls[2][8];
  float er[2], ed[2];
  #pragma unroll
  for (int j = 0; j < 2; ++j) {
    float a = gt[2 * j] * 0.5f, bb = gb[2 * j] * 0.5f;
    float c = gt[2 * j + 1] * 0.5f, d = gb[2 * j + 1] * 0.5f;
    float v[8];
    v[0] = a + bb; v[1] = a - bb; v[2] = c + d; v[3] = c - d;
    float da = dt[2 * j] * 0.5f, db2 = db_[2 * j] * 0.5f;
    float dc = dt[2 * j + 1] * 0.5f, dd = db_[2 * j + 1] * 0.5f;
    v[4] = da + db2; v[5] = da - db2; v[6] = dc + dd; v[7] = dc - dd;
    er[j] = sqrtf(v[1] * v[1] + v[2] * v[2] + v[3] * v[3] + 1e-8f);
    ed[j] = sqrtf(v[5] * v[5] + v[6] * v[6] + v[7] * v[7] + 1e-8f);
    #pragma unroll
    for (int cc = 0; cc < 8; ++cc) {
      unsigned short hb = f2bf(v[cc]);
      hs[j][cc] = hb;
      ls[j][cc] = f2bf(v[cc] - bf2f(hb));
    }
  }
  unsigned short* dst = freq2 +
      ((size_t)(bi * 2) * PREC + (size_t)(y + 1) * PROW + (2 * xp + 1)) * 16;
  uint4* d4 = (uint4*)dst;
  d4[0] = ((const uint4*)hs[0])[0]; d4[1] = ((const uint4*)ls[0])[0];
  d4[2] = ((const uint4*)hs[1])[0]; d4[3] = ((const uint4*)ls[1])[0];
  float* eb = ebuf + (size_t)bi * 2 * CHW + (size_t)y * 512 + 2 * xp;
  *(float2*)(eb) = make_float2(er[0], er[1]);
  *(float2*)(eb + CHW) = make_float2(ed[0], ed[1]);
}

// ---------------------------------------------------------------- smooth -> P1
__constant__ float GW[25] = {
  0.00296901f, 0.01330621f, 0.02193824f, 0.01330621f, 0.00296901f,
  0.01330621f, 0.05963435f, 0.09832035f, 0.05963435f, 0.01330621f,
  0.02193824f, 0.09832035f, 0.16210276f, 0.09832035f, 0.02193824f,
  0.01330621f, 0.05963435f, 0.09832035f, 0.05963435f, 0.01330621f,
  0.00296901f, 0.01330621f, 0.02193824f, 0.01330621f, 0.00296901f};

// P1 record (32B): [Er,Ed,Ers,Eds,0,0,0,0] hi | same lo. Full-line streaming.
__global__ __launch_bounds__(256) void k_smooth(const float* __restrict__ ebuf,
                                                unsigned short* __restrict__ freq2) {
  int t = blockIdx.x * 256 + threadIdx.x;
  int bi = blockIdx.y;
  int x = t & 511, y = t >> 9;
  const float* eb = ebuf + (size_t)bi * 2 * CHW;
  float accv[2];
  #pragma unroll
  for (int ch = 0; ch < 2; ++ch) {
    const float* fin = eb + ch * CHW;
    float acc = 0.0f;
    #pragma unroll
    for (int i = 0; i < 5; ++i) {
      int yy = y + i - 2;
      if (yy < 0 || yy > 511) continue;
      #pragma unroll
      for (int j = 0; j < 5; ++j) {
        int xx = x + j - 2;
        if (xx < 0 || xx > 511) continue;
        acc += GW[i * 5 + j] * fin[yy * 512 + xx];
      }
    }
    accv[ch] = acc;
  }
  float erc = eb[t], edc = eb[CHW + t];          // center (unsmoothed) ch8,9
  unsigned short rec[16];
  float v4[4] = {erc, edc, accv[0], accv[1]};
  #pragma unroll
  for (int j = 0; j < 4; ++j) {
    unsigned short hb = f2bf(v4[j]);
    rec[j] = hb;
    rec[8 + j] = f2bf(v4[j] - bf2f(hb));
  }
  #pragma unroll
  for (int j = 4; j < 8; ++j) { rec[j] = 0; rec[8 + j] = 0; }
  unsigned short* px = freq2 +
      ((size_t)(bi * 2 + 1) * PREC + (size_t)(y + 1) * PROW + (x + 1)) * 16;
  ((uint4*)px)[0] = ((const uint4*)rec)[0];
  ((uint4*)px)[1] = ((const uint4*)rec)[1];
}

// ---------------------------------------------------------------- conv fused (MFMA)
// Wave = 32 px (N) x 32 co (M), 32x32x16 bf16. K=16 = 16 padded ch (c=kg*8+e;
// kg selects plane P0/P1). Phase-split: ALL 18 B-pairs prefetched to registers
// (one latency round-trip), then 27 MFMAs. A-loads stay inline (L1-hot 18KB).
__global__ __launch_bounds__(256) void k_conv(const unsigned short* __restrict__ freq2,
    const unsigned short* __restrict__ apack, const float* __restrict__ ep,
    float* __restrict__ sal, int b0) {
  int tid = threadIdx.x;
  int l = tid & 63, wv = tid >> 6;
  int y = blockIdx.y;
  int xw = blockIdx.x * 128 + wv * 32;
  int bi = blockIdx.z;
  int n = l & 31, kg = l >> 5;

  const unsigned short* pb0 = freq2 +
      ((size_t)(bi * 2 + kg) * PREC + (size_t)(y + 1) * PROW + (xw + n + 1)) * 16;
  const unsigned short* ab = apack + l * 8;

  // phase 1: prefetch all B fragments (static indices -> registers)
  bf16x8 Bh[9], Bl[9];
  #pragma unroll
  for (int s = 0; s < 9; ++s) {
    const int doff = (SDY[s] * PROW + SDX[s]) * 16;   // compile-time
    Bh[s] = *(const bf16x8*)(pb0 + doff);
    Bl[s] = *(const bf16x8*)(pb0 + doff + 8);
  }

  // phase 2: MFMA chain
  f32x16 acc = {};
  #pragma unroll
  for (int s = 0; s < 9; ++s) {
    bf16x8 Ah = *(const bf16x8*)(ab + s * 1024);
    bf16x8 Al = *(const bf16x8*)(ab + s * 1024 + 512);
    acc = __builtin_amdgcn_mfma_f32_32x32x16_bf16(Ah, Bh[s], acc, 0, 0, 0);
    acc = __builtin_amdgcn_mfma_f32_32x32x16_bf16(Al, Bh[s], acc, 0, 0, 0);
    acc = __builtin_amdgcn_mfma_f32_32x32x16_bf16(Ah, Bl[s], acc, 0, 0, 0);
  }

  // epilogue: BN + gelu + w2-dot over 16 regs (co=(reg&3)+8*(reg>>2)+4*kg),
  // pair-lane reduce (l ^ 32), sigmoid, store px n by lanes 0..31.
  const float* e0 = ep + kg * 16;
  const float* e1 = ep + 32 + kg * 16;
  const float* e2 = ep + 64 + kg * 16;
  float s2 = 0.0f;
  #pragma unroll
  for (int r = 0; r < 16; ++r) {
    float t = acc[r] * e0[r] + e1[r];
    float z = t * (1.5957691216057308f + 0.07135481283247183f * (t * t));
    s2 += (t / (1.0f + __expf(-z))) * e2[r];   // == gelu(t)
  }
  s2 += __shfl_xor(s2, 32);
  s2 += ep[96];
  float res = 1.0f / (1.0f + __expf(-s2));
  if (l < 32)
    sal[(size_t)(b0 + bi) * CHW + (size_t)y * 512 + xw + n] = res;
}

// ---------------------------------------------------------------- resize + box partials
__global__ __launch_bounds__(256) void k_resize(const float* __restrict__ sal,
                                                float* __restrict__ masks,
                                                int* __restrict__ part) {
  int b = blockIdx.y;
  int blk = blockIdx.x;
  int t = threadIdx.x;
  const float* sp = sal + (size_t)b * CHW;
  float* mp = masks + (size_t)b * FULLHW;
  int mnX = 0x7FFFFFFF, mxX = -1, mnY = 0x7FFFFFFF, mxY = -1;
  int c0 = 4 * t;
  #pragma unroll
  for (int r = 0; r < 4; ++r) {
    int Y = blk * 4 + r;
    int y0 = (Y - 1) >> 1;
    float wy = (Y & 1) ? 0.25f : 0.75f;
    int y0c = y0 < 0 ? 0 : y0, y1c = (y0 + 1 > 511) ? 511 : y0 + 1;
    const float* r0 = sp + y0c * 512;
    const float* r1 = sp + y1c * 512;
    float o[4];
    #pragma unroll
    for (int j = 0; j < 4; ++j) {
      int X = c0 + j;
      int x0 = (X - 1) >> 1;
      float wx = (X & 1) ? 0.25f : 0.75f;
      int x0c = x0 < 0 ? 0 : x0, x1c = (x0 + 1 > 511) ? 511 : x0 + 1;
      float v00 = r0[x0c], v01 = r0[x1c], v10 = r1[x0c], v11 = r1[x1c];
      o[j] = (1.0f - wy) * ((1.0f - wx) * v00 + wx * v01)
           + wy * ((1.0f - wx) * v10 + wx * v11);
      if (o[j] > 0.5f) {
        mnX = min(mnX, X); mxX = max(mxX, X);
        mnY = min(mnY, Y); mxY = max(mxY, Y);
      }
    }
    *(float4*)(mp + (size_t)Y * 1024 + c0) = make_float4(o[0], o[1], o[2], o[3]);
  }
  __shared__ int s0[256], s1[256], s2[256], s3[256];
  s0[t] = mnX; s1[t] = mxX; s2[t] = mnY; s3[t] = mxY;
  __syncthreads();
  for (int off = 128; off > 0; off >>= 1) {
    if (t < off) {
      s0[t] = min(s0[t], s0[t + off]); s1[t] = max(s1[t], s1[t + off]);
      s2[t] = min(s2[t], s2[t + off]); s3[t] = max(s3[t], s3[t + off]);
    }
    __syncthreads();
  }
  if (t == 0) {
    int* pp = part + (b * 256 + blk) * 4;
    pp[0] = s0[0]; pp[1] = s1[0]; pp[2] = s2[0]; pp[3] = s3[0];
  }
}

// ---------------------------------------------------------------- box reduce -> out
__global__ __launch_bounds__(256) void k_boxreduce(const int* __restrict__ part,
                                                   float* __restrict__ out) {
  int b = blockIdx.x, t = threadIdx.x;
  const int* pp = part + (b * 256 + t) * 4;
  __shared__ int s0[256], s1[256], s2[256], s3[256];
  s0[t] = pp[0]; s1[t] = pp[1]; s2[t] = pp[2]; s3[t] = pp[3];
  __syncthreads();
  for (int off = 128; off > 0; off >>= 1) {
    if (t < off) {
      s0[t] = min(s0[t], s0[t + off]); s1[t] = max(s1[t], s1[t + off]);
      s2[t] = min(s2[t], s2[t + off]); s3[t] = max(s3[t], s3[t + off]);
    }
    __syncthreads();
  }
  if (t == 0) {
    float x0, y0, x1, y1;
    if (s3[0] < 0) { x0 = 0.0f; y0 = 0.0f; x1 = 1023.0f; y1 = 1023.0f; }
    else { x0 = (float)s0[0]; y0 = (float)s2[0]; x1 = (float)s1[0]; y1 = (float)s3[0]; }
    out[240 + b * 4 + 0] = x0;
    out[240 + b * 4 + 1] = y0;
    out[240 + b * 4 + 2] = x1;
    out[240 + b * 4 + 3] = y1;
  }
}

// ---------------------------------------------------------------- level-1 hist (+peak mask)
__global__ __launch_bounds__(256) void k_hist1(const float* __restrict__ sal,
                                               unsigned* __restrict__ h1p,
                                               unsigned char* __restrict__ pkm) {
  __shared__ unsigned sH[4096];                   // [class][2048]
  int b = blockIdx.y, tid = threadIdx.x;
  for (int i = tid; i < 4096; i += 256) sH[i] = 0;
  __syncthreads();
  const float* sp = sal + (size_t)b * CHW;
  int base = blockIdx.x * 4096;
  for (int it = 0; it < 4; ++it) {
    int p = base + it * 1024 + tid * 4;
    int x0 = p & 511, y = p >> 9;
    int ym = (y > 0) ? y - 1 : 0, yp = (y < 511) ? y + 1 : 511;
    const float* r0 = sp + ym * 512;
    const float* r1 = sp + y * 512;
    const float* r2 = sp + yp * 512;
    float4 m0 = *(const float4*)(r0 + x0);
    float4 m1 = *(const float4*)(r1 + x0);
    float4 m2 = *(const float4*)(r2 + x0);
    float l0 = x0 ? r0[x0 - 1] : m0.x;
    float l1 = x0 ? r1[x0 - 1] : m1.x;
    float l2 = x0 ? r2[x0 - 1] : m2.x;
    float q0 = (x0 < 508) ? r0[x0 + 4] : m0.w;
    float q1 = (x0 < 508) ? r1[x0 + 4] : m1.w;
    float q2 = (x0 < 508) ? r2[x0 + 4] : m2.w;
    float a0[6] = {l0, m0.x, m0.y, m0.z, m0.w, q0};
    float a1[6] = {l1, m1.x, m1.y, m1.z, m1.w, q1};
    float a2[6] = {l2, m2.x, m2.y, m2.z, m2.w, q2};
    unsigned pw = 0;
    #pragma unroll
    for (int j = 0; j < 4; ++j) {
      float r0m = fmaxf(fmaxf(a0[j], a0[j + 1]), a0[j + 2]);
      float r1m = fmaxf(fmaxf(a1[j], a1[j + 1]), a1[j + 2]);
      float r2m = fmaxf(fmaxf(a2[j], a2[j + 1]), a2[j + 2]);
      float cmax = fmaxf(fmaxf(r0m, r1m), r2m);
      float sv = a1[j + 1];
      bool pk = (sv > 0.0f) && (sv >= cmax);      // no neighbor strictly greater
      pw |= (pk ? 1u : 0u) << (8 * j);
      unsigned bin = (__float_as_uint(sv) >> 21) & 2047;
      atomicAdd(&sH[(pk ? 0 : 2048) + bin], 1u);
    }
    *(unsigned*)(pkm + (size_t)b * CHW + p) = pw;
  }
  __syncthreads();
  unsigned* dst = h1p + ((size_t)b * NB1 + blockIdx.x) * 4096;
  for (int i = tid; i < 4096; i += 256) dst[i] = sH[i];
}

// ---------------------------------------------------------------- radix scan (sums partials)
__global__ __launch_bounds__(256) void k_scan(const unsigned* __restrict__ hp,
                                              int* __restrict__ thr, int level,
                                              int np) {
  int c = blockIdx.x, b = blockIdx.y, t = threadIdx.x;
  __shared__ unsigned sBins[2048];
  __shared__ unsigned sS[256];
  __shared__ int sT;
  unsigned bv[8] = {0, 0, 0, 0, 0, 0, 0, 0};
  for (int p = 0; p < np; ++p) {
    const unsigned* q = hp + ((size_t)(b * np + p)) * 4096 + c * 2048 + t * 8;
    uint4 a = *(const uint4*)(q);
    uint4 d = *(const uint4*)(q + 4);
    bv[0] += a.x; bv[1] += a.y; bv[2] += a.z; bv[3] += a.w;
    bv[4] += d.x; bv[5] += d.y; bv[6] += d.z; bv[7] += d.w;
  }
  unsigned part = 0;
  #pragma unroll
  for (int r = 0; r < 8; ++r) {
    sBins[t * 8 + r] = bv[r];
    part += bv[r];
  }
  sS[t] = part;
  __syncthreads();
  for (int off = 1; off < 256; off <<= 1) {
    unsigned add = (t + off < 256) ? sS[t + off] : 0;
    __syncthreads();
    sS[t] += add;
    __syncthreads();
  }
  int K = (c == 0) ? 512 : 10;
  int* tb = thr + (c * 8 + b) * 4;
  if (level == 1) { K -= tb[1]; if (K < 1) K = 1; }
  if (t == 0) sT = -1;
  __syncthreads();
  if (sS[t] >= (unsigned)K && (t == 255 || sS[t + 1] < (unsigned)K)) sT = t;
  __syncthreads();
  if (t == 0) {
    int T = 0;
    unsigned run = 0;
    if (sT >= 0) {
      int ts = sT;
      run = (ts < 255) ? sS[ts + 1] : 0;
      for (int r = 7; r >= 0; --r) {
        unsigned v = sBins[ts * 8 + r];
        run += v;
        if (run >= (unsigned)K) { T = ts * 8 + r; run -= v; break; }
      }
    } else {
      T = 0;
      run = sS[0] - sBins[0];                     // suffix(1); take everything
    }
    if (level == 0) { tb[0] = T; tb[1] = (int)run; }
    else           { tb[2] = (tb[0] << 11) | T; }
  }
}

// ---------------------------------------------------------------- level-2 hist
__global__ __launch_bounds__(256) void k_hist2(const float* __restrict__ sal,
                                               const unsigned char* __restrict__ pkm,
                                               const int* __restrict__ thr,
                                               unsigned* __restrict__ h2p) {
  __shared__ unsigned sH[4096];
  int b = blockIdx.y, tid = threadIdx.x;
  for (int i = tid; i < 4096; i += 256) sH[i] = 0;
  __syncthreads();
  int t0 = thr[(0 * 8 + b) * 4];
  int t1 = thr[(1 * 8 + b) * 4];
  const float* sp = sal + (size_t)b * CHW;
  const unsigned char* pp = pkm + (size_t)b * CHW;
  int base = blockIdx.x * 8192;
  for (int it = 0; it < 8; ++it) {
    int p = base + it * 1024 + tid * 4;
    float4 s4 = *(const float4*)(sp + p);
    unsigned pk4 = *(const unsigned*)(pp + p);
    float sv[4] = {s4.x, s4.y, s4.z, s4.w};
    #pragma unroll
    for (int j = 0; j < 4; ++j) {
      bool pk = ((pk4 >> (8 * j)) & 255u) != 0;
      unsigned bits = __float_as_uint(sv[j]);
      int tt = pk ? t0 : t1;
      if ((int)(bits >> 21) == tt)
        atomicAdd(&sH[(pk ? 0 : 2048) + ((bits >> 10) & 2047)], 1u);
    }
  }
  __syncthreads();
  unsigned* dst = h2p + ((size_t)b * NB2 + blockIdx.x) * 4096;
  for (int i = tid; i < 4096; i += 256) dst[i] = sH[i];
}

// ---------------------------------------------------------------- compact
__global__ __launch_bounds__(256) void k_compact(const float* __restrict__ sal,
                                                 const unsigned char* __restrict__ pkm,
                                                 const int* __restrict__ thr,
                                                 unsigned* __restrict__ cnt,
                                                 unsigned long long* __restrict__ cand) {
  int b = blockIdx.y;
  int p = (blockIdx.x * 256 + threadIdx.x) * 4;
  const float* sp = sal + (size_t)b * CHW;
  float4 s4 = *(const float4*)(sp + p);
  unsigned pk4 = *(const unsigned*)(pkm + (size_t)b * CHW + p);
  unsigned q0 = (unsigned)thr[(0 * 8 + b) * 4 + 2];
  unsigned q1 = (unsigned)thr[(1 * 8 + b) * 4 + 2];
  float sv[4] = {s4.x, s4.y, s4.z, s4.w};
  #pragma unroll
  for (int j = 0; j < 4; ++j) {
    bool pk = ((pk4 >> (8 * j)) & 255u) != 0;
    unsigned bits = __float_as_uint(sv[j]);
    unsigned q = pk ? q0 : q1;
    int c = pk ? 0 : 1;
    if ((bits >> 10) >= q) {
      unsigned pos = atomicAdd(&cnt[c * 8 + b], 1u);
      if (pos < 1024)
        cand[((size_t)(c * 8 + b) << 10) + pos] =
            ((unsigned long long)bits << 32) | (unsigned)(~(p + j));
    }
  }
}

// ---------------------------------------------------------------- sort + NMS
__device__ inline void bitonic1024_desc(unsigned long long* sKey) {
  int t = threadIdx.x;
  for (unsigned k = 2; k <= 1024; k <<= 1) {
    for (unsigned j = k >> 1; j > 0; j >>= 1) {
      __syncthreads();
      #pragma unroll
      for (int e = 0; e < 2; ++e) {
        unsigned i = (unsigned)t + (unsigned)e * 512u;
        unsigned l = i ^ j;
        if (l > i) {
          unsigned long long a = sKey[i], bb = sKey[l];
          if (((i & k) == 0) ? (a < bb) : (a > bb)) { sKey[i] = bb; sKey[l] = a; }
        }
      }
    }
  }
  __syncthreads();
}

__global__ __launch_bounds__(512) void k_nms(const unsigned long long* __restrict__ cand,
                                             const unsigned* __restrict__ cnt,
                                             float* __restrict__ out) {
  __shared__ unsigned long long sKey[1024];
  __shared__ unsigned sIdx[512];
  __shared__ int sAvail[512];
  __shared__ int sSel[16];
  int b = blockIdx.x, t = threadIdx.x;
  if (t < 10) out[160 + b * 10 + t] = 1.0f;       // labels
  int Cp = (int)cnt[b]; if (Cp > 1024) Cp = 1024;
  const unsigned long long* cp = cand + ((size_t)b << 10);
  sKey[t] = (t < Cp) ? cp[t] : 0ULL;
  sKey[t + 512] = (t + 512 < Cp) ? cp[t + 512] : 0ULL;
  bitonic1024_desc(sKey);
  sIdx[t] = (unsigned)(~sKey[t]);
  int ncand = (Cp < 512) ? Cp : 512;              // K_PEAKS cap
  sAvail[t] = (t < ncand) ? 1 : 0;
  __syncthreads();
  int nsel = 0;
  for (int i = 0; i < 512 && nsel < 10; ++i) {
    if (sAvail[i] != 0) {                         // uniform branch
      unsigned pi = sIdx[i];
      int xi = (int)(pi & 511), yi = (int)(pi >> 9);
      if (t > i && sAvail[t]) {
        int dx = (int)(sIdx[t] & 511) - xi;
        int dy = (int)(sIdx[t] >> 9) - yi;
        if (dx * dx + dy * dy < 625) sAvail[t] = 0;   // dist < 25
      }
      if (t == 0) sSel[nsel] = (int)pi;
      ++nsel;
      __syncthreads();
    }
  }
  __syncthreads();
  // fallback: top-10 non-peak pixels
  int Cf = (int)cnt[8 + b]; if (Cf > 1024) Cf = 1024;
  const unsigned long long* cf = cand + ((size_t)(8 + b) << 10);
  sKey[t] = (t < Cf) ? cf[t] : 0ULL;
  sKey[t + 512] = (t + 512 < Cf) ? cf[t + 512] : 0ULL;
  bitonic1024_desc(sKey);
  if (t < 10) {
    int fi;
    if (t < nsel) fi = sSel[t];
    else { int r = t - nsel; if (r > 9) r = 9; fi = (int)((unsigned)(~sKey[r])); }
    out[((size_t)b * 10 + t) * 2 + 0] = (float)(fi & 511) * (1.0f / 512.0f);
    out[((size_t)b * 10 + t) * 2 + 1] = (float)(fi >> 9) * (1.0f / 512.0f);
  }
}

// ---------------------------------------------------------------------------
extern "C" void kernel_launch(void* const* d_in, const int* in_sizes, int n_in,
                              void* d_out, int out_size, void* d_ws, size_t ws_size,
                              hipStream_t stream) {
  const float* rgb  = (const float*)d_in[0];
  const float* dep  = (const float*)d_in[1];
  const float* w1   = (const float*)d_in[2];
  const float* b1   = (const float*)d_in[3];
  const float* gam  = (const float*)d_in[4];
  const float* bet  = (const float*)d_in[5];
  const float* bmn  = (const float*)d_in[6];
  const float* bvr  = (const float*)d_in[7];
  const float* w2   = (const float*)d_in[8];
  const float* b2   = (const float*)d_in[9];
  float* out = (float*)d_out;
  char* ws = (char*)d_ws;

  float* sal = (float*)(ws + OFF_SAL);
  int* thr = (int*)(ws + OFF_THR);
  unsigned* cnt = (unsigned*)(ws + OFF_CNT);
  unsigned long long* cand = (unsigned long long*)(ws + OFF_CAND);
  int* part = (int*)(ws + OFF_PART);
  unsigned short* apack = (unsigned short*)(ws + OFF_APACK);
  float* ep = (float*)(ws + OFF_EP);
  unsigned char* pkm = (unsigned char*)(ws + OFF_PKM);

  // dynamic region, phase 1 (conv): ebuf (nb*2MB) then 2-plane freq2
  size_t perE = (size_t)2 * CHW * 4;             // 2 MB / batch
  size_t perF = (size_t)PREC * 64;               // 2 planes * 32B, ~16.9 MB
  long long avail = (long long)ws_size - (long long)OFF_DYN;
  int nb = 1;
  if (avail >= (long long)(perE + perF)) {
    long long m = avail / (long long)(perE + perF);
    nb = (m > 8) ? 8 : (int)m;
  }
  float* ebuf = (float*)(ws + OFF_DYN);
  unsigned short* freq2 = (unsigned short*)(ws + OFF_DYN + perE * (size_t)nb);
  // dynamic region, phase 2 (hist): partials overlap the dead conv buffers
  unsigned* h1p = (unsigned*)(ws + OFF_DYN);                       // 8 MB
  unsigned* h2p = (unsigned*)(ws + OFF_DYN + (size_t)8 * NB1 * 4096 * 4);  // 4 MB

  k_init<<<40, 256, 0, stream>>>(cnt, w1, b1, gam, bet, bmn, bvr, w2, b2,
                                 apack, ep);
  k_zero<<<dim3(33, nb), 256, 0, stream>>>(freq2);

  for (int b0 = 0; b0 < 8; b0 += nb) {
    int nbc = (8 - b0 < nb) ? (8 - b0) : nb;
    k_freq<<<dim3(512, nbc), 256, 0, stream>>>(rgb, dep, freq2, ebuf, b0);
    k_smooth<<<dim3(1024, nbc), 256, 0, stream>>>(ebuf, freq2);
    k_conv<<<dim3(4, 512, nbc), 256, 0, stream>>>(freq2, apack, ep, sal, b0);
  }

  k_resize<<<dim3(256, 8), 256, 0, stream>>>(sal, out + 272, part);
  k_boxreduce<<<8, 256, 0, stream>>>(part, out);
  k_hist1<<<dim3(NB1, 8), 256, 0, stream>>>(sal, h1p, pkm);
  k_scan<<<dim3(2, 8), 256, 0, stream>>>(h1p, thr, 0, NB1);
  k_hist2<<<dim3(NB2, 8), 256, 0, stream>>>(sal, pkm, thr, h2p);
  k_scan<<<dim3(2, 8), 256, 0, stream>>>(h2p, thr, 1, NB2);
  k_compact<<<dim3(256, 8), 256, 0, stream>>>(sal, pkm, thr, cnt, cand);
  k_nms<<<8, 512, 0, stream>>>(cand, cnt, out);
}

// Round 6
// 520.339 us; speedup vs baseline: 1.8692x; 1.0073x over previous
//
#include <hip/hip_runtime.h>
#include <math.h>

// ---------------------------------------------------------------------------
// PromptGenerate: DWT->E->smooth->conv1+BN+GELU->conv2->sigmoid (sal, 512x512)
//  -> bilinear 2x upsample (masks), boxes from mask>0.5, greedy-NMS peak coords
// R6: k_conv on bf16 MFMA hi/lo 3-term. R8: hist -> LDS + non-atomic partials.
// R9: padded freq2, 32x32x16 MFMA (27/wave): latency-bound at 141us.
// R10: phase-split prefetch + 2-plane freq2 (killed k_smooth 64B-line RMW).
//      Result 119us but VGPR=36 -> compiler RE-SANK the B-loads next to their
//      MFMA uses (unroll+scheduler defeats source-level phasing): still ~9
//      serialized latency round-trips.
// R11: enforce the split with __builtin_amdgcn_sched_barrier(0) between the
//      18 B-loads and the MFMA chain (loads can't sink, MFMAs can't hoist).
//      Expect VGPR ~110-130 (verification signature), one latency round-trip.
//      Only k_conv changed this round (clean attribution).
// ---------------------------------------------------------------------------

#define CHW 262144          // 512*512
#define FULLHW 1048576      // 1024*1024
#define NB1 64              // k_hist1 blocks per batch (4096 px each)
#define NB2 32              // k_hist2 blocks per batch (8192 px each)
#define PROW 514            // padded row stride (records)
#define PREC (514*514)      // padded records per plane per batch

typedef __attribute__((ext_vector_type(8))) short bf16x8;
typedef __attribute__((ext_vector_type(16))) float f32x16;

static __device__ __forceinline__ unsigned short f2bf(float x) {
  unsigned u = __float_as_uint(x);
  u += 0x7FFFu + ((u >> 16) & 1u);
  return (unsigned short)(u >> 16);
}
static __device__ __forceinline__ float bf2f(unsigned short h) {
  return __uint_as_float(((unsigned)h) << 16);
}

static constexpr size_t OFF_SAL   = 0;                       // 8*CHW*4
static constexpr size_t OFF_THR   = 8388608;                 // 256
static constexpr size_t OFF_CNT   = OFF_THR + 256;           // 256
static constexpr size_t OFF_CAND  = OFF_CNT + 256;           // 131072
static constexpr size_t OFF_PART  = OFF_CAND + 131072;       // 32768
static constexpr size_t OFF_APACK = OFF_PART + 32768;        // 18432 used
static constexpr size_t OFF_EP    = OFF_APACK + 20480;       // 512 (epilogue)
static constexpr size_t OFF_PKM   = OFF_EP + 512;            // 8*CHW u8
static constexpr size_t OFF_DYN   = OFF_PKM + 2097152;
// dynamic region (temporally disjoint uses):
//   conv phase : ebuf (nb*2MB) + freq2 (nb * 2 planes * PREC*32B ~= 16.9MB)
//   hist phase : h1p (8MB) + h2p (4MB)

// shift s = ky*3+kx (0..8)
static constexpr int SDY[9] = {-1,-1,-1, 0,0,0, 1,1,1};
static constexpr int SDX[9] = {-1, 0, 1,-1,0,1,-1,0,1};

// ---------------------------------------------------------------- init + weight pack
// apack (ushort): idx = ((s*2+h)*64 + lane)*8 ; co=lane&31, c=(lane>>5)*8+e ;
//   val = (c<12) ? w1[co][c][s] : 0 ; h=0 hi, h=1 lo.
// ep (float): reordered to 32x32 D-register order, co=(reg&3)+8*(reg>>2)+4*kg:
//   [0,32) sc | [32,64) shift | [64,96) w2 | [96] b2
__global__ void k_init(unsigned* __restrict__ cnt,
                       const float* __restrict__ w1, const float* __restrict__ b1,
                       const float* __restrict__ gam, const float* __restrict__ bet,
                       const float* __restrict__ mean, const float* __restrict__ var,
                       const float* __restrict__ w2, const float* __restrict__ b2,
                       unsigned short* __restrict__ apack, float* __restrict__ ep) {
  int i = blockIdx.x * 256 + threadIdx.x;
  if (i < 16) cnt[i] = 0;
  if (i < 9216) {
    int e = i & 7, lane = (i >> 3) & 63, frag = i >> 9;   // frag 0..17
    int s = frag >> 1, hh = frag & 1;
    int co = lane & 31;
    int c = ((lane >> 5) << 3) + e;
    float val = (c < 12) ? w1[co * 108 + c * 9 + s] : 0.0f;
    unsigned short hb = f2bf(val);
    apack[i] = hh ? f2bf(val - bf2f(hb)) : hb;
  }
  if (i < 96) {
    int t = i >> 5, rem = i & 31, kg = rem >> 4, reg = rem & 15;
    int co = (reg & 3) + 8 * (reg >> 2) + 4 * kg;
    float sc = gam[co] * rsqrtf(var[co] + 1e-5f);
    float v = (t == 0) ? sc
            : (t == 1) ? (b1[co] - mean[co]) * sc + bet[co]
                       : w2[co];
    ep[i] = v;
  } else if (i == 96) {
    ep[96] = b2[0];
  }
}

// ---------------------------------------------------------------- border zero
// zero 32B border records of BOTH planes of each batch slot.
__global__ __launch_bounds__(256) void k_zero(unsigned short* __restrict__ freq2) {
  int i = blockIdx.x * 256 + threadIdx.x;        // [0, 8208) uint4 items
  int bi = blockIdx.y;
  if (i >= 8208) return;                          // 2 planes * 2052 recs * 2
  int q = i & 1, r = (i >> 1) % 2052, pl = (i >> 1) / 2052;
  int row, col;
  if (r < 514)        { row = 0;   col = r; }
  else if (r < 1028)  { row = 513; col = r - 514; }
  else if (r < 1540)  { row = r - 1028 + 1; col = 0; }
  else                { row = r - 1540 + 1; col = 513; }
  size_t off = ((size_t)(bi * 2 + pl) * PREC + (size_t)row * PROW + col) * 16;
  uint4* p = (uint4*)(freq2 + off) + q;
  *p = make_uint4(0u, 0u, 0u, 0u);
}

// ---------------------------------------------------------------- freq ch 0..7 (P0)
// P0 record (32B): ch0-7 hi (16B) | ch0-7 lo (16B). Er/Ed -> f32 ebuf.
__global__ __launch_bounds__(256) void k_freq(const float* __restrict__ rgb,
                                              const float* __restrict__ dep,
                                              unsigned short* __restrict__ freq2,
                                              float* __restrict__ ebuf, int b0) {
  int t = blockIdx.x * 256 + threadIdx.x;        // [0, 131072)
  int bi = blockIdx.y;
  int b = b0 + bi;
  int xp = t & 255, y = t >> 8;                  // xp: pair idx, outputs x=2xp,2xp+1
  const float* base = rgb + (size_t)b * 3 * FULLHW + (size_t)(2 * y) * 1024 + 4 * xp;
  float4 R0 = *(const float4*)(base);
  float4 R1 = *(const float4*)(base + 1024);
  float4 G0 = *(const float4*)(base + FULLHW);
  float4 G1 = *(const float4*)(base + FULLHW + 1024);
  float4 Bl0 = *(const float4*)(base + 2 * FULLHW);
  float4 Bl1 = *(const float4*)(base + 2 * FULLHW + 1024);
  const float* dbase = dep + (size_t)b * FULLHW + (size_t)(2 * y) * 1024 + 4 * xp;
  float4 D0 = *(const float4*)(dbase);
  float4 D1 = *(const float4*)(dbase + 1024);

  float gt[4], gb[4], dt[4], db_[4];
  gt[0] = (R0.x + G0.x + Bl0.x) / 3.0f; gt[1] = (R0.y + G0.y + Bl0.y) / 3.0f;
  gt[2] = (R0.z + G0.z + Bl0.z) / 3.0f; gt[3] = (R0.w + G0.w + Bl0.w) / 3.0f;
  gb[0] = (R1.x + G1.x + Bl1.x) / 3.0f; gb[1] = (R1.y + G1.y + Bl1.y) / 3.0f;
  gb[2] = (R1.z + G1.z + Bl1.z) / 3.0f; gb[3] = (R1.w + G1.w + Bl1.w) / 3.0f;
  dt[0] = D0.x; dt[1] = D0.y; dt[2] = D0.z; dt[3] = D0.w;
  db_[0] = D1.x; db_[1] = D1.y; db_[2] = D1.z; db_[3] = D1.w;

  unsigned short hs[2][8], ls[2][8];
  float er[2], ed[2];
  #pragma unroll
  for (int j = 0; j < 2; ++j) {
    float a = gt[2 * j] * 0.5f, bb = gb[2 * j] * 0.5f;
    float c = gt[2 * j + 1] * 0.5f, d = gb[2 * j + 1] * 0.5f;
    float v[8];
    v[0] = a + bb; v[1] = a - bb; v[2] = c + d; v[3] = c - d;
    float da = dt[2 * j] * 0.5f, db2 = db_[2 * j] * 0.5f;
    float dc = dt[2 * j + 1] * 0.5f, dd = db_[2 * j + 1] * 0.5f;
    v[4] = da + db2; v[5] = da - db2; v[6] = dc + dd; v[7] = dc - dd;
    er[j] = sqrtf(v[1] * v[1] + v[2] * v[2] + v[3] * v[3] + 1e-8f);
    ed[j] = sqrtf(v[5] * v[5] + v[6] * v[6] + v[7] * v[7] + 1e-8f);
    #pragma unroll
    for (int cc = 0; cc < 8; ++cc) {
      unsigned short hb = f2bf(v[cc]);
      hs[j][cc] = hb;
      ls[j][cc] = f2bf(v[cc] - bf2f(hb));
    }
  }
  unsigned short* dst = freq2 +
      ((size_t)(bi * 2) * PREC + (size_t)(y + 1) * PROW + (2 * xp + 1)) * 16;
  uint4* d4 = (uint4*)dst;
  d4[0] = ((const uint4*)hs[0])[0]; d4[1] = ((const uint4*)ls[0])[0];
  d4[2] = ((const uint4*)hs[1])[0]; d4[3] = ((const uint4*)ls[1])[0];
  float* eb = ebuf + (size_t)bi * 2 * CHW + (size_t)y * 512 + 2 * xp;
  *(float2*)(eb) = make_float2(er[0], er[1]);
  *(float2*)(eb + CHW) = make_float2(ed[0], ed[1]);
}

// ---------------------------------------------------------------- smooth -> P1
__constant__ float GW[25] = {
  0.00296901f, 0.01330621f, 0.02193824f, 0.01330621f, 0.00296901f,
  0.01330621f, 0.05963435f, 0.09832035f, 0.05963435f, 0.01330621f,
  0.02193824f, 0.09832035f, 0.16210276f, 0.09832035f, 0.02193824f,
  0.01330621f, 0.05963435f, 0.09832035f, 0.05963435f, 0.01330621f,
  0.00296901f, 0.01330621f, 0.02193824f, 0.01330621f, 0.00296901f};

// P1 record (32B): [Er,Ed,Ers,Eds,0,0,0,0] hi | same lo. Full-line streaming.
__global__ __launch_bounds__(256) void k_smooth(const float* __restrict__ ebuf,
                                                unsigned short* __restrict__ freq2) {
  int t = blockIdx.x * 256 + threadIdx.x;
  int bi = blockIdx.y;
  int x = t & 511, y = t >> 9;
  const float* eb = ebuf + (size_t)bi * 2 * CHW;
  float accv[2];
  #pragma unroll
  for (int ch = 0; ch < 2; ++ch) {
    const float* fin = eb + ch * CHW;
    float acc = 0.0f;
    #pragma unroll
    for (int i = 0; i < 5; ++i) {
      int yy = y + i - 2;
      if (yy < 0 || yy > 511) continue;
      #pragma unroll
      for (int j = 0; j < 5; ++j) {
        int xx = x + j - 2;
        if (xx < 0 || xx > 511) continue;
        acc += GW[i * 5 + j] * fin[yy * 512 + xx];
      }
    }
    accv[ch] = acc;
  }
  float erc = eb[t], edc = eb[CHW + t];          // center (unsmoothed) ch8,9
  unsigned short rec[16];
  float v4[4] = {erc, edc, accv[0], accv[1]};
  #pragma unroll
  for (int j = 0; j < 4; ++j) {
    unsigned short hb = f2bf(v4[j]);
    rec[j] = hb;
    rec[8 + j] = f2bf(v4[j] - bf2f(hb));
  }
  #pragma unroll
  for (int j = 4; j < 8; ++j) { rec[j] = 0; rec[8 + j] = 0; }
  unsigned short* px = freq2 +
      ((size_t)(bi * 2 + 1) * PREC + (size_t)(y + 1) * PROW + (x + 1)) * 16;
  ((uint4*)px)[0] = ((const uint4*)rec)[0];
  ((uint4*)px)[1] = ((const uint4*)rec)[1];
}

// ---------------------------------------------------------------- conv fused (MFMA)
// Wave = 32 px (N) x 32 co (M), 32x32x16 bf16. K=16 = 16 padded ch (c=kg*8+e;
// kg selects plane P0/P1). Phase-split: ALL 18 B-pairs prefetched to registers,
// then sched_barrier(0) pins the boundary (R10's source-level split was
// re-sunk by the scheduler: VGPR=36). Then 27 MFMAs + epilogue.
__global__ __launch_bounds__(256) void k_conv(const unsigned short* __restrict__ freq2,
    const unsigned short* __restrict__ apack, const float* __restrict__ ep,
    float* __restrict__ sal, int b0) {
  int tid = threadIdx.x;
  int l = tid & 63, wv = tid >> 6;
  int y = blockIdx.y;
  int xw = blockIdx.x * 128 + wv * 32;
  int bi = blockIdx.z;
  int n = l & 31, kg = l >> 5;

  const unsigned short* pb0 = freq2 +
      ((size_t)(bi * 2 + kg) * PREC + (size_t)(y + 1) * PROW + (xw + n + 1)) * 16;
  const unsigned short* ab = apack + l * 8;

  // phase 1: prefetch all B fragments (static indices -> registers)
  bf16x8 Bh[9], Bl[9];
  #pragma unroll
  for (int s = 0; s < 9; ++s) {
    const int doff = (SDY[s] * PROW + SDX[s]) * 16;   // compile-time
    Bh[s] = *(const bf16x8*)(pb0 + doff);
    Bl[s] = *(const bf16x8*)(pb0 + doff + 8);
  }
  __builtin_amdgcn_sched_barrier(0);   // pin: loads stay above, MFMAs below

  // phase 2: MFMA chain
  f32x16 acc = {};
  #pragma unroll
  for (int s = 0; s < 9; ++s) {
    bf16x8 Ah = *(const bf16x8*)(ab + s * 1024);
    bf16x8 Al = *(const bf16x8*)(ab + s * 1024 + 512);
    acc = __builtin_amdgcn_mfma_f32_32x32x16_bf16(Ah, Bh[s], acc, 0, 0, 0);
    acc = __builtin_amdgcn_mfma_f32_32x32x16_bf16(Al, Bh[s], acc, 0, 0, 0);
    acc = __builtin_amdgcn_mfma_f32_32x32x16_bf16(Ah, Bl[s], acc, 0, 0, 0);
  }

  // epilogue: BN + gelu + w2-dot over 16 regs (co=(reg&3)+8*(reg>>2)+4*kg),
  // pair-lane reduce (l ^ 32), sigmoid, store px n by lanes 0..31.
  const float* e0 = ep + kg * 16;
  const float* e1 = ep + 32 + kg * 16;
  const float* e2 = ep + 64 + kg * 16;
  float s2 = 0.0f;
  #pragma unroll
  for (int r = 0; r < 16; ++r) {
    float t = acc[r] * e0[r] + e1[r];
    float z = t * (1.5957691216057308f + 0.07135481283247183f * (t * t));
    s2 += (t / (1.0f + __expf(-z))) * e2[r];   // == gelu(t)
  }
  s2 += __shfl_xor(s2, 32);
  s2 += ep[96];
  float res = 1.0f / (1.0f + __expf(-s2));
  if (l < 32)
    sal[(size_t)(b0 + bi) * CHW + (size_t)y * 512 + xw + n] = res;
}

// ---------------------------------------------------------------- resize + box partials
__global__ __launch_bounds__(256) void k_resize(const float* __restrict__ sal,
                                                float* __restrict__ masks,
                                                int* __restrict__ part) {
  int b = blockIdx.y;
  int blk = blockIdx.x;
  int t = threadIdx.x;
  const float* sp = sal + (size_t)b * CHW;
  float* mp = masks + (size_t)b * FULLHW;
  int mnX = 0x7FFFFFFF, mxX = -1, mnY = 0x7FFFFFFF, mxY = -1;
  int c0 = 4 * t;
  #pragma unroll
  for (int r = 0; r < 4; ++r) {
    int Y = blk * 4 + r;
    int y0 = (Y - 1) >> 1;
    float wy = (Y & 1) ? 0.25f : 0.75f;
    int y0c = y0 < 0 ? 0 : y0, y1c = (y0 + 1 > 511) ? 511 : y0 + 1;
    const float* r0 = sp + y0c * 512;
    const float* r1 = sp + y1c * 512;
    float o[4];
    #pragma unroll
    for (int j = 0; j < 4; ++j) {
      int X = c0 + j;
      int x0 = (X - 1) >> 1;
      float wx = (X & 1) ? 0.25f : 0.75f;
      int x0c = x0 < 0 ? 0 : x0, x1c = (x0 + 1 > 511) ? 511 : x0 + 1;
      float v00 = r0[x0c], v01 = r0[x1c], v10 = r1[x0c], v11 = r1[x1c];
      o[j] = (1.0f - wy) * ((1.0f - wx) * v00 + wx * v01)
           + wy * ((1.0f - wx) * v10 + wx * v11);
      if (o[j] > 0.5f) {
        mnX = min(mnX, X); mxX = max(mxX, X);
        mnY = min(mnY, Y); mxY = max(mxY, Y);
      }
    }
    *(float4*)(mp + (size_t)Y * 1024 + c0) = make_float4(o[0], o[1], o[2], o[3]);
  }
  __shared__ int s0[256], s1[256], s2[256], s3[256];
  s0[t] = mnX; s1[t] = mxX; s2[t] = mnY; s3[t] = mxY;
  __syncthreads();
  for (int off = 128; off > 0; off >>= 1) {
    if (t < off) {
      s0[t] = min(s0[t], s0[t + off]); s1[t] = max(s1[t], s1[t + off]);
      s2[t] = min(s2[t], s2[t + off]); s3[t] = max(s3[t], s3[t + off]);
    }
    __syncthreads();
  }
  if (t == 0) {
    int* pp = part + (b * 256 + blk) * 4;
    pp[0] = s0[0]; pp[1] = s1[0]; pp[2] = s2[0]; pp[3] = s3[0];
  }
}

// ---------------------------------------------------------------- box reduce -> out
__global__ __launch_bounds__(256) void k_boxreduce(const int* __restrict__ part,
                                                   float* __restrict__ out) {
  int b = blockIdx.x, t = threadIdx.x;
  const int* pp = part + (b * 256 + t) * 4;
  __shared__ int s0[256], s1[256], s2[256], s3[256];
  s0[t] = pp[0]; s1[t] = pp[1]; s2[t] = pp[2]; s3[t] = pp[3];
  __syncthreads();
  for (int off = 128; off > 0; off >>= 1) {
    if (t < off) {
      s0[t] = min(s0[t], s0[t + off]); s1[t] = max(s1[t], s1[t + off]);
      s2[t] = min(s2[t], s2[t + off]); s3[t] = max(s3[t], s3[t + off]);
    }
    __syncthreads();
  }
  if (t == 0) {
    float x0, y0, x1, y1;
    if (s3[0] < 0) { x0 = 0.0f; y0 = 0.0f; x1 = 1023.0f; y1 = 1023.0f; }
    else { x0 = (float)s0[0]; y0 = (float)s2[0]; x1 = (float)s1[0]; y1 = (float)s3[0]; }
    out[240 + b * 4 + 0] = x0;
    out[240 + b * 4 + 1] = y0;
    out[240 + b * 4 + 2] = x1;
    out[240 + b * 4 + 3] = y1;
  }
}

// ---------------------------------------------------------------- level-1 hist (+peak mask)
__global__ __launch_bounds__(256) void k_hist1(const float* __restrict__ sal,
                                               unsigned* __restrict__ h1p,
                                               unsigned char* __restrict__ pkm) {
  __shared__ unsigned sH[4096];                   // [class][2048]
  int b = blockIdx.y, tid = threadIdx.x;
  for (int i = tid; i < 4096; i += 256) sH[i] = 0;
  __syncthreads();
  const float* sp = sal + (size_t)b * CHW;
  int base = blockIdx.x * 4096;
  for (int it = 0; it < 4; ++it) {
    int p = base + it * 1024 + tid * 4;
    int x0 = p & 511, y = p >> 9;
    int ym = (y > 0) ? y - 1 : 0, yp = (y < 511) ? y + 1 : 511;
    const float* r0 = sp + ym * 512;
    const float* r1 = sp + y * 512;
    const float* r2 = sp + yp * 512;
    float4 m0 = *(const float4*)(r0 + x0);
    float4 m1 = *(const float4*)(r1 + x0);
    float4 m2 = *(const float4*)(r2 + x0);
    float l0 = x0 ? r0[x0 - 1] : m0.x;
    float l1 = x0 ? r1[x0 - 1] : m1.x;
    float l2 = x0 ? r2[x0 - 1] : m2.x;
    float q0 = (x0 < 508) ? r0[x0 + 4] : m0.w;
    float q1 = (x0 < 508) ? r1[x0 + 4] : m1.w;
    float q2 = (x0 < 508) ? r2[x0 + 4] : m2.w;
    float a0[6] = {l0, m0.x, m0.y, m0.z, m0.w, q0};
    float a1[6] = {l1, m1.x, m1.y, m1.z, m1.w, q1};
    float a2[6] = {l2, m2.x, m2.y, m2.z, m2.w, q2};
    unsigned pw = 0;
    #pragma unroll
    for (int j = 0; j < 4; ++j) {
      float r0m = fmaxf(fmaxf(a0[j], a0[j + 1]), a0[j + 2]);
      float r1m = fmaxf(fmaxf(a1[j], a1[j + 1]), a1[j + 2]);
      float r2m = fmaxf(fmaxf(a2[j], a2[j + 1]), a2[j + 2]);
      float cmax = fmaxf(fmaxf(r0m, r1m), r2m);
      float sv = a1[j + 1];
      bool pk = (sv > 0.0f) && (sv >= cmax);      // no neighbor strictly greater
      pw |= (pk ? 1u : 0u) << (8 * j);
      unsigned bin = (__float_as_uint(sv) >> 21) & 2047;
      atomicAdd(&sH[(pk ? 0 : 2048) + bin], 1u);
    }
    *(unsigned*)(pkm + (size_t)b * CHW + p) = pw;
  }
  __syncthreads();
  unsigned* dst = h1p + ((size_t)b * NB1 + blockIdx.x) * 4096;
  for (int i = tid; i < 4096; i += 256) dst[i] = sH[i];
}

// ---------------------------------------------------------------- radix scan (sums partials)
__global__ __launch_bounds__(256) void k_scan(const unsigned* __restrict__ hp,
                                              int* __restrict__ thr, int level,
                                              int np) {
  int c = blockIdx.x, b = blockIdx.y, t = threadIdx.x;
  __shared__ unsigned sBins[2048];
  __shared__ unsigned sS[256];
  __shared__ int sT;
  unsigned bv[8] = {0, 0, 0, 0, 0, 0, 0, 0};
  for (int p = 0; p < np; ++p) {
    const unsigned* q = hp + ((size_t)(b * np + p)) * 4096 + c * 2048 + t * 8;
    uint4 a = *(const uint4*)(q);
    uint4 d = *(const uint4*)(q + 4);
    bv[0] += a.x; bv[1] += a.y; bv[2] += a.z; bv[3] += a.w;
    bv[4] += d.x; bv[5] += d.y; bv[6] += d.z; bv[7] += d.w;
  }
  unsigned part = 0;
  #pragma unroll
  for (int r = 0; r < 8; ++r) {
    sBins[t * 8 + r] = bv[r];
    part += bv[r];
  }
  sS[t] = part;
  __syncthreads();
  for (int off = 1; off < 256; off <<= 1) {
    unsigned add = (t + off < 256) ? sS[t + off] : 0;
    __syncthreads();
    sS[t] += add;
    __syncthreads();
  }
  int K = (c == 0) ? 512 : 10;
  int* tb = thr + (c * 8 + b) * 4;
  if (level == 1) { K -= tb[1]; if (K < 1) K = 1; }
  if (t == 0) sT = -1;
  __syncthreads();
  if (sS[t] >= (unsigned)K && (t == 255 || sS[t + 1] < (unsigned)K)) sT = t;
  __syncthreads();
  if (t == 0) {
    int T = 0;
    unsigned run = 0;
    if (sT >= 0) {
      int ts = sT;
      run = (ts < 255) ? sS[ts + 1] : 0;
      for (int r = 7; r >= 0; --r) {
        unsigned v = sBins[ts * 8 + r];
        run += v;
        if (run >= (unsigned)K) { T = ts * 8 + r; run -= v; break; }
      }
    } else {
      T = 0;
      run = sS[0] - sBins[0];                     // suffix(1); take everything
    }
    if (level == 0) { tb[0] = T; tb[1] = (int)run; }
    else           { tb[2] = (tb[0] << 11) | T; }
  }
}

// ---------------------------------------------------------------- level-2 hist
__global__ __launch_bounds__(256) void k_hist2(const float* __restrict__ sal,
                                               const unsigned char* __restrict__ pkm,
                                               const int* __restrict__ thr,
                                               unsigned* __restrict__ h2p) {
  __shared__ unsigned sH[4096];
  int b = blockIdx.y, tid = threadIdx.x;
  for (int i = tid; i < 4096; i += 256) sH[i] = 0;
  __syncthreads();
  int t0 = thr[(0 * 8 + b) * 4];
  int t1 = thr[(1 * 8 + b) * 4];
  const float* sp = sal + (size_t)b * CHW;
  const unsigned char* pp = pkm + (size_t)b * CHW;
  int base = blockIdx.x * 8192;
  for (int it = 0; it < 8; ++it) {
    int p = base + it * 1024 + tid * 4;
    float4 s4 = *(const float4*)(sp + p);
    unsigned pk4 = *(const unsigned*)(pp + p);
    float sv[4] = {s4.x, s4.y, s4.z, s4.w};
    #pragma unroll
    for (int j = 0; j < 4; ++j) {
      bool pk = ((pk4 >> (8 * j)) & 255u) != 0;
      unsigned bits = __float_as_uint(sv[j]);
      int tt = pk ? t0 : t1;
      if ((int)(bits >> 21) == tt)
        atomicAdd(&sH[(pk ? 0 : 2048) + ((bits >> 10) & 2047)], 1u);
    }
  }
  __syncthreads();
  unsigned* dst = h2p + ((size_t)b * NB2 + blockIdx.x) * 4096;
  for (int i = tid; i < 4096; i += 256) dst[i] = sH[i];
}

// ---------------------------------------------------------------- compact
__global__ __launch_bounds__(256) void k_compact(const float* __restrict__ sal,
                                                 const unsigned char* __restrict__ pkm,
                                                 const int* __restrict__ thr,
                                                 unsigned* __restrict__ cnt,
                                                 unsigned long long* __restrict__ cand) {
  int b = blockIdx.y;
  int p = (blockIdx.x * 256 + threadIdx.x) * 4;
  const float* sp = sal + (size_t)b * CHW;
  float4 s4 = *(const float4*)(sp + p);
  unsigned pk4 = *(const unsigned*)(pkm + (size_t)b * CHW + p);
  unsigned q0 = (unsigned)thr[(0 * 8 + b) * 4 + 2];
  unsigned q1 = (unsigned)thr[(1 * 8 + b) * 4 + 2];
  float sv[4] = {s4.x, s4.y, s4.z, s4.w};
  #pragma unroll
  for (int j = 0; j < 4; ++j) {
    bool pk = ((pk4 >> (8 * j)) & 255u) != 0;
    unsigned bits = __float_as_uint(sv[j]);
    unsigned q = pk ? q0 : q1;
    int c = pk ? 0 : 1;
    if ((bits >> 10) >= q) {
      unsigned pos = atomicAdd(&cnt[c * 8 + b], 1u);
      if (pos < 1024)
        cand[((size_t)(c * 8 + b) << 10) + pos] =
            ((unsigned long long)bits << 32) | (unsigned)(~(p + j));
    }
  }
}

// ---------------------------------------------------------------- sort + NMS
__device__ inline void bitonic1024_desc(unsigned long long* sKey) {
  int t = threadIdx.x;
  for (unsigned k = 2; k <= 1024; k <<= 1) {
    for (unsigned j = k >> 1; j > 0; j >>= 1) {
      __syncthreads();
      #pragma unroll
      for (int e = 0; e < 2; ++e) {
        unsigned i = (unsigned)t + (unsigned)e * 512u;
        unsigned l = i ^ j;
        if (l > i) {
          unsigned long long a = sKey[i], bb = sKey[l];
          if (((i & k) == 0) ? (a < bb) : (a > bb)) { sKey[i] = bb; sKey[l] = a; }
        }
      }
    }
  }
  __syncthreads();
}

__global__ __launch_bounds__(512) void k_nms(const unsigned long long* __restrict__ cand,
                                             const unsigned* __restrict__ cnt,
                                             float* __restrict__ out) {
  __shared__ unsigned long long sKey[1024];
  __shared__ unsigned sIdx[512];
  __shared__ int sAvail[512];
  __shared__ int sSel[16];
  int b = blockIdx.x, t = threadIdx.x;
  if (t < 10) out[160 + b * 10 + t] = 1.0f;       // labels
  int Cp = (int)cnt[b]; if (Cp > 1024) Cp = 1024;
  const unsigned long long* cp = cand + ((size_t)b << 10);
  sKey[t] = (t < Cp) ? cp[t] : 0ULL;
  sKey[t + 512] = (t + 512 < Cp) ? cp[t + 512] : 0ULL;
  bitonic1024_desc(sKey);
  sIdx[t] = (unsigned)(~sKey[t]);
  int ncand = (Cp < 512) ? Cp : 512;              // K_PEAKS cap
  sAvail[t] = (t < ncand) ? 1 : 0;
  __syncthreads();
  int nsel = 0;
  for (int i = 0; i < 512 && nsel < 10; ++i) {
    if (sAvail[i] != 0) {                         // uniform branch
      unsigned pi = sIdx[i];
      int xi = (int)(pi & 511), yi = (int)(pi >> 9);
      if (t > i && sAvail[t]) {
        int dx = (int)(sIdx[t] & 511) - xi;
        int dy = (int)(sIdx[t] >> 9) - yi;
        if (dx * dx + dy * dy < 625) sAvail[t] = 0;   // dist < 25
      }
      if (t == 0) sSel[nsel] = (int)pi;
      ++nsel;
      __syncthreads();
    }
  }
  __syncthreads();
  // fallback: top-10 non-peak pixels
  int Cf = (int)cnt[8 + b]; if (Cf > 1024) Cf = 1024;
  const unsigned long long* cf = cand + ((size_t)(8 + b) << 10);
  sKey[t] = (t < Cf) ? cf[t] : 0ULL;
  sKey[t + 512] = (t + 512 < Cf) ? cf[t + 512] : 0ULL;
  bitonic1024_desc(sKey);
  if (t < 10) {
    int fi;
    if (t < nsel) fi = sSel[t];
    else { int r = t - nsel; if (r > 9) r = 9; fi = (int)((unsigned)(~sKey[r])); }
    out[((size_t)b * 10 + t) * 2 + 0] = (float)(fi & 511) * (1.0f / 512.0f);
    out[((size_t)b * 10 + t) * 2 + 1] = (float)(fi >> 9) * (1.0f / 512.0f);
  }
}

// ---------------------------------------------------------------------------
extern "C" void kernel_launch(void* const* d_in, const int* in_sizes, int n_in,
                              void* d_out, int out_size, void* d_ws, size_t ws_size,
                              hipStream_t stream) {
  const float* rgb  = (const float*)d_in[0];
  const float* dep  = (const float*)d_in[1];
  const float* w1   = (const float*)d_in[2];
  const float* b1   = (const float*)d_in[3];
  const float* gam  = (const float*)d_in[4];
  const float* bet  = (const float*)d_in[5];
  const float* bmn  = (const float*)d_in[6];
  const float* bvr  = (const float*)d_in[7];
  const float* w2   = (const float*)d_in[8];
  const float* b2   = (const float*)d_in[9];
  float* out = (float*)d_out;
  char* ws = (char*)d_ws;

  float* sal = (float*)(ws + OFF_SAL);
  int* thr = (int*)(ws + OFF_THR);
  unsigned* cnt = (unsigned*)(ws + OFF_CNT);
  unsigned long long* cand = (unsigned long long*)(ws + OFF_CAND);
  int* part = (int*)(ws + OFF_PART);
  unsigned short* apack = (unsigned short*)(ws + OFF_APACK);
  float* ep = (float*)(ws + OFF_EP);
  unsigned char* pkm = (unsigned char*)(ws + OFF_PKM);

  // dynamic region, phase 1 (conv): ebuf (nb*2MB) then 2-plane freq2
  size_t perE = (size_t)2 * CHW * 4;             // 2 MB / batch
  size_t perF = (size_t)PREC * 64;               // 2 planes * 32B, ~16.9 MB
  long long avail = (long long)ws_size - (long long)OFF_DYN;
  int nb = 1;
  if (avail >= (long long)(perE + perF)) {
    long long m = avail / (long long)(perE + perF);
    nb = (m > 8) ? 8 : (int)m;
  }
  float* ebuf = (float*)(ws + OFF_DYN);
  unsigned short* freq2 = (unsigned short*)(ws + OFF_DYN + perE * (size_t)nb);
  // dynamic region, phase 2 (hist): partials overlap the dead conv buffers
  unsigned* h1p = (unsigned*)(ws + OFF_DYN);                       // 8 MB
  unsigned* h2p = (unsigned*)(ws + OFF_DYN + (size_t)8 * NB1 * 4096 * 4);  // 4 MB

  k_init<<<40, 256, 0, stream>>>(cnt, w1, b1, gam, bet, bmn, bvr, w2, b2,
                                 apack, ep);
  k_zero<<<dim3(33, nb), 256, 0, stream>>>(freq2);

  for (int b0 = 0; b0 < 8; b0 += nb) {
    int nbc = (8 - b0 < nb) ? (8 - b0) : nb;
    k_freq<<<dim3(512, nbc), 256, 0, stream>>>(rgb, dep, freq2, ebuf, b0);
    k_smooth<<<dim3(1024, nbc), 256, 0, stream>>>(ebuf, freq2);
    k_conv<<<dim3(4, 512, nbc), 256, 0, stream>>>(freq2, apack, ep, sal, b0);
  }

  k_resize<<<dim3(256, 8), 256, 0, stream>>>(sal, out + 272, part);
  k_boxreduce<<<8, 256, 0, stream>>>(part, out);
  k_hist1<<<dim3(NB1, 8), 256, 0, stream>>>(sal, h1p, pkm);
  k_scan<<<dim3(2, 8), 256, 0, stream>>>(h1p, thr, 0, NB1);
  k_hist2<<<dim3(NB2, 8), 256, 0, stream>>>(sal, pkm, thr, h2p);
  k_scan<<<dim3(2, 8), 256, 0, stream>>>(h2p, thr, 1, NB2);
  k_compact<<<dim3(256, 8), 256, 0, stream>>>(sal, pkm, thr, cnt, cand);
  k_nms<<<8, 512, 0, stream>>>(cand, cnt, out);
}

// Round 7
// 509.844 us; speedup vs baseline: 1.9077x; 1.0206x over previous
//
#include <hip/hip_runtime.h>
#include <math.h>

// ---------------------------------------------------------------------------
// PromptGenerate: DWT->E->smooth->conv1+BN+GELU->conv2->sigmoid (sal, 512x512)
//  -> bilinear 2x upsample (masks), boxes from mask>0.5, greedy-NMS peak coords
// R6: k_conv on bf16 MFMA hi/lo 3-term. R8: hist -> LDS + non-atomic partials.
// R9: padded freq2, 32x32x16 MFMA. R10: 2-plane split (k_smooth RMW fix).
// R11: sched_barrier prefetch: VGPR 36->60, only 119->114us. Compiler keeps
//      splitting the 18-pair register prefetch -> still latency-bound
//      (MfmaUtil 21%, VALU 44%, HBM 16%, occ 40%: nothing saturated).
// R12: stop fighting the scheduler -> LDS-stage the B tile (canonical GEMM
//      pattern). freq2 now 4 planes of 16B/px (P0h,P0l,P1h,P1l) so LDS reads
//      are consecutive-16B-per-lane ds_read_b128 (conflict-free). Block
//      stages 3 rows x 4 planes x 130 recs (24.96KB) via reg-staging, one
//      syncthreads, then 9-shift MFMA loop reads B from LDS (~12cyc/read).
//      Epilogue divisions -> v_rcp (rel err ~1e-7 << 2^-8 tolerance).
// ---------------------------------------------------------------------------

#define CHW 262144          // 512*512
#define FULLHW 1048576      // 1024*1024
#define NB1 64              // k_hist1 blocks per batch (4096 px each)
#define NB2 32              // k_hist2 blocks per batch (8192 px each)
#define PROW 514            // padded row stride (records)
#define PREC (514*514)      // padded records per plane per batch (16B records)
#define LREC 130            // LDS records per (row,plane)

typedef __attribute__((ext_vector_type(8))) short bf16x8;
typedef __attribute__((ext_vector_type(16))) float f32x16;

static __device__ __forceinline__ unsigned short f2bf(float x) {
  unsigned u = __float_as_uint(x);
  u += 0x7FFFu + ((u >> 16) & 1u);
  return (unsigned short)(u >> 16);
}
static __device__ __forceinline__ float bf2f(unsigned short h) {
  return __uint_as_float(((unsigned)h) << 16);
}

static constexpr size_t OFF_SAL   = 0;                       // 8*CHW*4
static constexpr size_t OFF_THR   = 8388608;                 // 256
static constexpr size_t OFF_CNT   = OFF_THR + 256;           // 256
static constexpr size_t OFF_CAND  = OFF_CNT + 256;           // 131072
static constexpr size_t OFF_PART  = OFF_CAND + 131072;       // 32768
static constexpr size_t OFF_APACK = OFF_PART + 32768;        // 18432 used
static constexpr size_t OFF_EP    = OFF_APACK + 20480;       // 512 (epilogue)
static constexpr size_t OFF_PKM   = OFF_EP + 512;            // 8*CHW u8
static constexpr size_t OFF_DYN   = OFF_PKM + 2097152;
// dynamic region (temporally disjoint uses):
//   conv phase : ebuf (nb*2MB) + freq2 (nb * 4 planes * PREC*16B ~= 16.9MB)
//   hist phase : h1p (8MB) + h2p (4MB)

// shift s = ky*3+kx (0..8)
static constexpr int SDY[9] = {-1,-1,-1, 0,0,0, 1,1,1};
static constexpr int SDX[9] = {-1, 0, 1,-1,0,1,-1,0,1};

// ---------------------------------------------------------------- init + weight pack
// apack (ushort): idx = ((s*2+h)*64 + lane)*8 ; co=lane&31, c=(lane>>5)*8+e ;
//   val = (c<12) ? w1[co][c][s] : 0 ; h=0 hi, h=1 lo.
// ep (float): reordered to 32x32 D-register order, co=(reg&3)+8*(reg>>2)+4*kg:
//   [0,32) sc | [32,64) shift | [64,96) w2 | [96] b2
__global__ void k_init(unsigned* __restrict__ cnt,
                       const float* __restrict__ w1, const float* __restrict__ b1,
                       const float* __restrict__ gam, const float* __restrict__ bet,
                       const float* __restrict__ mean, const float* __restrict__ var,
                       const float* __restrict__ w2, const float* __restrict__ b2,
                       unsigned short* __restrict__ apack, float* __restrict__ ep) {
  int i = blockIdx.x * 256 + threadIdx.x;
  if (i < 16) cnt[i] = 0;
  if (i < 9216) {
    int e = i & 7, lane = (i >> 3) & 63, frag = i >> 9;   // frag 0..17
    int s = frag >> 1, hh = frag & 1;
    int co = lane & 31;
    int c = ((lane >> 5) << 3) + e;
    float val = (c < 12) ? w1[co * 108 + c * 9 + s] : 0.0f;
    unsigned short hb = f2bf(val);
    apack[i] = hh ? f2bf(val - bf2f(hb)) : hb;
  }
  if (i < 96) {
    int t = i >> 5, rem = i & 31, kg = rem >> 4, reg = rem & 15;
    int co = (reg & 3) + 8 * (reg >> 2) + 4 * kg;
    float sc = gam[co] * rsqrtf(var[co] + 1e-5f);
    float v = (t == 0) ? sc
            : (t == 1) ? (b1[co] - mean[co]) * sc + bet[co]
                       : w2[co];
    ep[i] = v;
  } else if (i == 96) {
    ep[96] = b2[0];
  }
}

// ---------------------------------------------------------------- border zero
// zero 16B border records of all 4 planes of each batch slot.
__global__ __launch_bounds__(256) void k_zero(unsigned short* __restrict__ freq2) {
  int i = blockIdx.x * 256 + threadIdx.x;        // [0, 8208) 16B items
  int bi = blockIdx.y;
  if (i >= 8208) return;                          // 4 planes * 2052 records
  int pl = i / 2052, r = i % 2052;
  int row, col;
  if (r < 514)        { row = 0;   col = r; }
  else if (r < 1028)  { row = 513; col = r - 514; }
  else if (r < 1540)  { row = r - 1028 + 1; col = 0; }
  else                { row = r - 1540 + 1; col = 513; }
  uint4* p = (uint4*)(freq2 + ((size_t)(bi * 4 + pl) * PREC + (size_t)row * PROW + col) * 8);
  *p = make_uint4(0u, 0u, 0u, 0u);
}

// ---------------------------------------------------------------- freq ch 0..7 (P0h/P0l)
// plane0 = ch0-7 hi (16B/px), plane1 = ch0-7 lo. Er/Ed -> f32 ebuf.
__global__ __launch_bounds__(256) void k_freq(const float* __restrict__ rgb,
                                              const float* __restrict__ dep,
                                              unsigned short* __restrict__ freq2,
                                              float* __restrict__ ebuf, int b0) {
  int t = blockIdx.x * 256 + threadIdx.x;        // [0, 131072)
  int bi = blockIdx.y;
  int b = b0 + bi;
  int xp = t & 255, y = t >> 8;                  // xp: pair idx, outputs x=2xp,2xp+1
  const float* base = rgb + (size_t)b * 3 * FULLHW + (size_t)(2 * y) * 1024 + 4 * xp;
  float4 R0 = *(const float4*)(base);
  float4 R1 = *(const float4*)(base + 1024);
  float4 G0 = *(const float4*)(base + FULLHW);
  float4 G1 = *(const float4*)(base + FULLHW + 1024);
  float4 Bl0 = *(const float4*)(base + 2 * FULLHW);
  float4 Bl1 = *(const float4*)(base + 2 * FULLHW + 1024);
  const float* dbase = dep + (size_t)b * FULLHW + (size_t)(2 * y) * 1024 + 4 * xp;
  float4 D0 = *(const float4*)(dbase);
  float4 D1 = *(const float4*)(dbase + 1024);

  float gt[4], gb[4], dt[4], db_[4];
  gt[0] = (R0.x + G0.x + Bl0.x) / 3.0f; gt[1] = (R0.y + G0.y + Bl0.y) / 3.0f;
  gt[2] = (R0.z + G0.z + Bl0.z) / 3.0f; gt[3] = (R0.w + G0.w + Bl0.w) / 3.0f;
  gb[0] = (R1.x + G1.x + Bl1.x) / 3.0f; gb[1] = (R1.y + G1.y + Bl1.y) / 3.0f;
  gb[2] = (R1.z + G1.z + Bl1.z) / 3.0f; gb[3] = (R1.w + G1.w + Bl1.w) / 3.0f;
  dt[0] = D0.x; dt[1] = D0.y; dt[2] = D0.z; dt[3] = D0.w;
  db_[0] = D1.x; db_[1] = D1.y; db_[2] = D1.z; db_[3] = D1.w;

  unsigned short hs[2][8], ls[2][8];
  float er[2], ed[2];
  #pragma unroll
  for (int j = 0; j < 2; ++j) {
    float a = gt[2 * j] * 0.5f, bb = gb[2 * j] * 0.5f;
    float c = gt[2 * j + 1] * 0.5f, d = gb[2 * j + 1] * 0.5f;
    float v[8];
    v[0] = a + bb; v[1] = a - bb; v[2] = c + d; v[3] = c - d;
    float da = dt[2 * j] * 0.5f, db2 = db_[2 * j] * 0.5f;
    float dc = dt[2 * j + 1] * 0.5f, dd = db_[2 * j + 1] * 0.5f;
    v[4] = da + db2; v[5] = da - db2; v[6] = dc + dd; v[7] = dc - dd;
    er[j] = sqrtf(v[1] * v[1] + v[2] * v[2] + v[3] * v[3] + 1e-8f);
    ed[j] = sqrtf(v[5] * v[5] + v[6] * v[6] + v[7] * v[7] + 1e-8f);
    #pragma unroll
    for (int cc = 0; cc < 8; ++cc) {
      unsigned short hb = f2bf(v[cc]);
      hs[j][cc] = hb;
      ls[j][cc] = f2bf(v[cc] - bf2f(hb));
    }
  }
  size_t rbase = (size_t)(y + 1) * PROW + (2 * xp + 1);
  unsigned short* d0 = freq2 + ((size_t)(bi * 4 + 0) * PREC + rbase) * 8;
  unsigned short* d1 = freq2 + ((size_t)(bi * 4 + 1) * PREC + rbase) * 8;
  ((uint4*)d0)[0] = ((const uint4*)hs[0])[0];
  ((uint4*)d0)[1] = ((const uint4*)hs[1])[0];
  ((uint4*)d1)[0] = ((const uint4*)ls[0])[0];
  ((uint4*)d1)[1] = ((const uint4*)ls[1])[0];
  float* eb = ebuf + (size_t)bi * 2 * CHW + (size_t)y * 512 + 2 * xp;
  *(float2*)(eb) = make_float2(er[0], er[1]);
  *(float2*)(eb + CHW) = make_float2(ed[0], ed[1]);
}

// ---------------------------------------------------------------- smooth -> P1h/P1l
__constant__ float GW[25] = {
  0.00296901f, 0.01330621f, 0.02193824f, 0.01330621f, 0.00296901f,
  0.01330621f, 0.05963435f, 0.09832035f, 0.05963435f, 0.01330621f,
  0.02193824f, 0.09832035f, 0.16210276f, 0.09832035f, 0.02193824f,
  0.01330621f, 0.05963435f, 0.09832035f, 0.05963435f, 0.01330621f,
  0.00296901f, 0.01330621f, 0.02193824f, 0.01330621f, 0.00296901f};

// plane2 = [Er,Ed,Ers,Eds,0,0,0,0] hi (16B/px), plane3 = lo.
__global__ __launch_bounds__(256) void k_smooth(const float* __restrict__ ebuf,
                                                unsigned short* __restrict__ freq2) {
  int t = blockIdx.x * 256 + threadIdx.x;
  int bi = blockIdx.y;
  int x = t & 511, y = t >> 9;
  const float* eb = ebuf + (size_t)bi * 2 * CHW;
  float accv[2];
  #pragma unroll
  for (int ch = 0; ch < 2; ++ch) {
    const float* fin = eb + ch * CHW;
    float acc = 0.0f;
    #pragma unroll
    for (int i = 0; i < 5; ++i) {
      int yy = y + i - 2;
      if (yy < 0 || yy > 511) continue;
      #pragma unroll
      for (int j = 0; j < 5; ++j) {
        int xx = x + j - 2;
        if (xx < 0 || xx > 511) continue;
        acc += GW[i * 5 + j] * fin[yy * 512 + xx];
      }
    }
    accv[ch] = acc;
  }
  float erc = eb[t], edc = eb[CHW + t];          // center (unsmoothed) ch8,9
  unsigned short rh[8], rl[8];
  float v4[4] = {erc, edc, accv[0], accv[1]};
  #pragma unroll
  for (int j = 0; j < 4; ++j) {
    unsigned short hb = f2bf(v4[j]);
    rh[j] = hb;
    rl[j] = f2bf(v4[j] - bf2f(hb));
  }
  #pragma unroll
  for (int j = 4; j < 8; ++j) { rh[j] = 0; rl[j] = 0; }
  size_t rbase = (size_t)(y + 1) * PROW + (x + 1);
  unsigned short* p2 = freq2 + ((size_t)(bi * 4 + 2) * PREC + rbase) * 8;
  unsigned short* p3 = freq2 + ((size_t)(bi * 4 + 3) * PREC + rbase) * 8;
  *(uint4*)p2 = *(const uint4*)rh;
  *(uint4*)p3 = *(const uint4*)rl;
}

// ---------------------------------------------------------------- conv fused (MFMA)
// Wave = 32 px (N) x 32 co (M), 32x32x16 bf16, K=16ch (c=kg*8+e; plane pair by
// kg). Block = 128 px strip at row y. B tile staged in LDS: 3 rows x 4 planes
// x 130 recs x 16B = 24.96KB; ds_read_b128 consecutive-16B-per-lane
// (conflict-free). 27 MFMAs/wave; epilogue uses v_rcp.
__global__ __launch_bounds__(256) void k_conv(const unsigned short* __restrict__ freq2,
    const unsigned short* __restrict__ apack, const float* __restrict__ ep,
    float* __restrict__ sal, int b0) {
  __shared__ __align__(16) char smem[24960];     // ((row*4+plane)*130+rec)*16
  int tid = threadIdx.x;
  int l = tid & 63, wv = tid >> 6;
  int y = blockIdx.y;
  int xwb = blockIdx.x * 128;
  int bi = blockIdx.z;
  int n = l & 31, kg = l >> 5;

  // stage: 1560 records of 16B, cooperative (reg-staged)
  #pragma unroll
  for (int it = 0; it < 7; ++it) {
    int j = it * 256 + tid;
    if (j < 1560) {
      int row = j / 520, rem = j % 520;
      int plane = rem / 130, rec = rem % 130;
      const unsigned short* g = freq2 +
          ((size_t)(bi * 4 + plane) * PREC + (size_t)(y + row) * PROW + (xwb + rec)) * 8;
      *(uint4*)(smem + j * 16) = *(const uint4*)g;
    }
  }
  __syncthreads();

  const unsigned short* ab = apack + l * 8;
  f32x16 acc = {};
  #pragma unroll
  for (int s = 0; s < 9; ++s) {
    int row = 1 + SDY[s];
    int rec = wv * 32 + n + 1 + SDX[s];
    const char* bh = smem + (((row * 4 + kg * 2 + 0) * LREC) + rec) * 16;
    const char* bl = smem + (((row * 4 + kg * 2 + 1) * LREC) + rec) * 16;
    bf16x8 Bh = *(const bf16x8*)bh;
    bf16x8 Bl = *(const bf16x8*)bl;
    bf16x8 Ah = *(const bf16x8*)(ab + s * 1024);
    bf16x8 Al = *(const bf16x8*)(ab + s * 1024 + 512);
    acc = __builtin_amdgcn_mfma_f32_32x32x16_bf16(Ah, Bh, acc, 0, 0, 0);
    acc = __builtin_amdgcn_mfma_f32_32x32x16_bf16(Al, Bh, acc, 0, 0, 0);
    acc = __builtin_amdgcn_mfma_f32_32x32x16_bf16(Ah, Bl, acc, 0, 0, 0);
  }

  // epilogue: BN + gelu + w2-dot over 16 regs (co=(reg&3)+8*(reg>>2)+4*kg),
  // pair-lane reduce (l ^ 32), sigmoid, store px n by lanes 0..31.
  const float* e0 = ep + kg * 16;
  const float* e1 = ep + 32 + kg * 16;
  const float* e2 = ep + 64 + kg * 16;
  float s2 = 0.0f;
  #pragma unroll
  for (int r = 0; r < 16; ++r) {
    float t = acc[r] * e0[r] + e1[r];
    float z = t * (1.5957691216057308f + 0.07135481283247183f * (t * t));
    float g = t * __builtin_amdgcn_rcpf(1.0f + __expf(-z));   // == gelu(t)
    s2 += g * e2[r];
  }
  s2 += __shfl_xor(s2, 32);
  s2 += ep[96];
  float res = __builtin_amdgcn_rcpf(1.0f + __expf(-s2));
  if (l < 32)
    sal[(size_t)(b0 + bi) * CHW + (size_t)y * 512 + xwb + wv * 32 + n] = res;
}

// ---------------------------------------------------------------- resize + box partials
__global__ __launch_bounds__(256) void k_resize(const float* __restrict__ sal,
                                                float* __restrict__ masks,
                                                int* __restrict__ part) {
  int b = blockIdx.y;
  int blk = blockIdx.x;
  int t = threadIdx.x;
  const float* sp = sal + (size_t)b * CHW;
  float* mp = masks + (size_t)b * FULLHW;
  int mnX = 0x7FFFFFFF, mxX = -1, mnY = 0x7FFFFFFF, mxY = -1;
  int c0 = 4 * t;
  #pragma unroll
  for (int r = 0; r < 4; ++r) {
    int Y = blk * 4 + r;
    int y0 = (Y - 1) >> 1;
    float wy = (Y & 1) ? 0.25f : 0.75f;
    int y0c = y0 < 0 ? 0 : y0, y1c = (y0 + 1 > 511) ? 511 : y0 + 1;
    const float* r0 = sp + y0c * 512;
    const float* r1 = sp + y1c * 512;
    float o[4];
    #pragma unroll
    for (int j = 0; j < 4; ++j) {
      int X = c0 + j;
      int x0 = (X - 1) >> 1;
      float wx = (X & 1) ? 0.25f : 0.75f;
      int x0c = x0 < 0 ? 0 : x0, x1c = (x0 + 1 > 511) ? 511 : x0 + 1;
      float v00 = r0[x0c], v01 = r0[x1c], v10 = r1[x0c], v11 = r1[x1c];
      o[j] = (1.0f - wy) * ((1.0f - wx) * v00 + wx * v01)
           + wy * ((1.0f - wx) * v10 + wx * v11);
      if (o[j] > 0.5f) {
        mnX = min(mnX, X); mxX = max(mxX, X);
        mnY = min(mnY, Y); mxY = max(mxY, Y);
      }
    }
    *(float4*)(mp + (size_t)Y * 1024 + c0) = make_float4(o[0], o[1], o[2], o[3]);
  }
  __shared__ int s0[256], s1[256], s2[256], s3[256];
  s0[t] = mnX; s1[t] = mxX; s2[t] = mnY; s3[t] = mxY;
  __syncthreads();
  for (int off = 128; off > 0; off >>= 1) {
    if (t < off) {
      s0[t] = min(s0[t], s0[t + off]); s1[t] = max(s1[t], s1[t + off]);
      s2[t] = min(s2[t], s2[t + off]); s3[t] = max(s3[t], s3[t + off]);
    }
    __syncthreads();
  }
  if (t == 0) {
    int* pp = part + (b * 256 + blk) * 4;
    pp[0] = s0[0]; pp[1] = s1[0]; pp[2] = s2[0]; pp[3] = s3[0];
  }
}

// ---------------------------------------------------------------- box reduce -> out
__global__ __launch_bounds__(256) void k_boxreduce(const int* __restrict__ part,
                                                   float* __restrict__ out) {
  int b = blockIdx.x, t = threadIdx.x;
  const int* pp = part + (b * 256 + t) * 4;
  __shared__ int s0[256], s1[256], s2[256], s3[256];
  s0[t] = pp[0]; s1[t] = pp[1]; s2[t] = pp[2]; s3[t] = pp[3];
  __syncthreads();
  for (int off = 128; off > 0; off >>= 1) {
    if (t < off) {
      s0[t] = min(s0[t], s0[t + off]); s1[t] = max(s1[t], s1[t + off]);
      s2[t] = min(s2[t], s2[t + off]); s3[t] = max(s3[t], s3[t + off]);
    }
    __syncthreads();
  }
  if (t == 0) {
    float x0, y0, x1, y1;
    if (s3[0] < 0) { x0 = 0.0f; y0 = 0.0f; x1 = 1023.0f; y1 = 1023.0f; }
    else { x0 = (float)s0[0]; y0 = (float)s2[0]; x1 = (float)s1[0]; y1 = (float)s3[0]; }
    out[240 + b * 4 + 0] = x0;
    out[240 + b * 4 + 1] = y0;
    out[240 + b * 4 + 2] = x1;
    out[240 + b * 4 + 3] = y1;
  }
}

// ---------------------------------------------------------------- level-1 hist (+peak mask)
__global__ __launch_bounds__(256) void k_hist1(const float* __restrict__ sal,
                                               unsigned* __restrict__ h1p,
                                               unsigned char* __restrict__ pkm) {
  __shared__ unsigned sH[4096];                   // [class][2048]
  int b = blockIdx.y, tid = threadIdx.x;
  for (int i = tid; i < 4096; i += 256) sH[i] = 0;
  __syncthreads();
  const float* sp = sal + (size_t)b * CHW;
  int base = blockIdx.x * 4096;
  for (int it = 0; it < 4; ++it) {
    int p = base + it * 1024 + tid * 4;
    int x0 = p & 511, y = p >> 9;
    int ym = (y > 0) ? y - 1 : 0, yp = (y < 511) ? y + 1 : 511;
    const float* r0 = sp + ym * 512;
    const float* r1 = sp + y * 512;
    const float* r2 = sp + yp * 512;
    float4 m0 = *(const float4*)(r0 + x0);
    float4 m1 = *(const float4*)(r1 + x0);
    float4 m2 = *(const float4*)(r2 + x0);
    float l0 = x0 ? r0[x0 - 1] : m0.x;
    float l1 = x0 ? r1[x0 - 1] : m1.x;
    float l2 = x0 ? r2[x0 - 1] : m2.x;
    float q0 = (x0 < 508) ? r0[x0 + 4] : m0.w;
    float q1 = (x0 < 508) ? r1[x0 + 4] : m1.w;
    float q2 = (x0 < 508) ? r2[x0 + 4] : m2.w;
    float a0[6] = {l0, m0.x, m0.y, m0.z, m0.w, q0};
    float a1[6] = {l1, m1.x, m1.y, m1.z, m1.w, q1};
    float a2[6] = {l2, m2.x, m2.y, m2.z, m2.w, q2};
    unsigned pw = 0;
    #pragma unroll
    for (int j = 0; j < 4; ++j) {
      float r0m = fmaxf(fmaxf(a0[j], a0[j + 1]), a0[j + 2]);
      float r1m = fmaxf(fmaxf(a1[j], a1[j + 1]), a1[j + 2]);
      float r2m = fmaxf(fmaxf(a2[j], a2[j + 1]), a2[j + 2]);
      float cmax = fmaxf(fmaxf(r0m, r1m), r2m);
      float sv = a1[j + 1];
      bool pk = (sv > 0.0f) && (sv >= cmax);      // no neighbor strictly greater
      pw |= (pk ? 1u : 0u) << (8 * j);
      unsigned bin = (__float_as_uint(sv) >> 21) & 2047;
      atomicAdd(&sH[(pk ? 0 : 2048) + bin], 1u);
    }
    *(unsigned*)(pkm + (size_t)b * CHW + p) = pw;
  }
  __syncthreads();
  unsigned* dst = h1p + ((size_t)b * NB1 + blockIdx.x) * 4096;
  for (int i = tid; i < 4096; i += 256) dst[i] = sH[i];
}

// ---------------------------------------------------------------- radix scan (sums partials)
__global__ __launch_bounds__(256) void k_scan(const unsigned* __restrict__ hp,
                                              int* __restrict__ thr, int level,
                                              int np) {
  int c = blockIdx.x, b = blockIdx.y, t = threadIdx.x;
  __shared__ unsigned sBins[2048];
  __shared__ unsigned sS[256];
  __shared__ int sT;
  unsigned bv[8] = {0, 0, 0, 0, 0, 0, 0, 0};
  for (int p = 0; p < np; ++p) {
    const unsigned* q = hp + ((size_t)(b * np + p)) * 4096 + c * 2048 + t * 8;
    uint4 a = *(const uint4*)(q);
    uint4 d = *(const uint4*)(q + 4);
    bv[0] += a.x; bv[1] += a.y; bv[2] += a.z; bv[3] += a.w;
    bv[4] += d.x; bv[5] += d.y; bv[6] += d.z; bv[7] += d.w;
  }
  unsigned part = 0;
  #pragma unroll
  for (int r = 0; r < 8; ++r) {
    sBins[t * 8 + r] = bv[r];
    part += bv[r];
  }
  sS[t] = part;
  __syncthreads();
  for (int off = 1; off < 256; off <<= 1) {
    unsigned add = (t + off < 256) ? sS[t + off] : 0;
    __syncthreads();
    sS[t] += add;
    __syncthreads();
  }
  int K = (c == 0) ? 512 : 10;
  int* tb = thr + (c * 8 + b) * 4;
  if (level == 1) { K -= tb[1]; if (K < 1) K = 1; }
  if (t == 0) sT = -1;
  __syncthreads();
  if (sS[t] >= (unsigned)K && (t == 255 || sS[t + 1] < (unsigned)K)) sT = t;
  __syncthreads();
  if (t == 0) {
    int T = 0;
    unsigned run = 0;
    if (sT >= 0) {
      int ts = sT;
      run = (ts < 255) ? sS[ts + 1] : 0;
      for (int r = 7; r >= 0; --r) {
        unsigned v = sBins[ts * 8 + r];
        run += v;
        if (run >= (unsigned)K) { T = ts * 8 + r; run -= v; break; }
      }
    } else {
      T = 0;
      run = sS[0] - sBins[0];                     // suffix(1); take everything
    }
    if (level == 0) { tb[0] = T; tb[1] = (int)run; }
    else           { tb[2] = (tb[0] << 11) | T; }
  }
}

// ---------------------------------------------------------------- level-2 hist
__global__ __launch_bounds__(256) void k_hist2(const float* __restrict__ sal,
                                               const unsigned char* __restrict__ pkm,
                                               const int* __restrict__ thr,
                                               unsigned* __restrict__ h2p) {
  __shared__ unsigned sH[4096];
  int b = blockIdx.y, tid = threadIdx.x;
  for (int i = tid; i < 4096; i += 256) sH[i] = 0;
  __syncthreads();
  int t0 = thr[(0 * 8 + b) * 4];
  int t1 = thr[(1 * 8 + b) * 4];
  const float* sp = sal + (size_t)b * CHW;
  const unsigned char* pp = pkm + (size_t)b * CHW;
  int base = blockIdx.x * 8192;
  for (int it = 0; it < 8; ++it) {
    int p = base + it * 1024 + tid * 4;
    float4 s4 = *(const float4*)(sp + p);
    unsigned pk4 = *(const unsigned*)(pp + p);
    float sv[4] = {s4.x, s4.y, s4.z, s4.w};
    #pragma unroll
    for (int j = 0; j < 4; ++j) {
      bool pk = ((pk4 >> (8 * j)) & 255u) != 0;
      unsigned bits = __float_as_uint(sv[j]);
      int tt = pk ? t0 : t1;
      if ((int)(bits >> 21) == tt)
        atomicAdd(&sH[(pk ? 0 : 2048) + ((bits >> 10) & 2047)], 1u);
    }
  }
  __syncthreads();
  unsigned* dst = h2p + ((size_t)b * NB2 + blockIdx.x) * 4096;
  for (int i = tid; i < 4096; i += 256) dst[i] = sH[i];
}

// ---------------------------------------------------------------- compact
__global__ __launch_bounds__(256) void k_compact(const float* __restrict__ sal,
                                                 const unsigned char* __restrict__ pkm,
                                                 const int* __restrict__ thr,
                                                 unsigned* __restrict__ cnt,
                                                 unsigned long long* __restrict__ cand) {
  int b = blockIdx.y;
  int p = (blockIdx.x * 256 + threadIdx.x) * 4;
  const float* sp = sal + (size_t)b * CHW;
  float4 s4 = *(const float4*)(sp + p);
  unsigned pk4 = *(const unsigned*)(pkm + (size_t)b * CHW + p);
  unsigned q0 = (unsigned)thr[(0 * 8 + b) * 4 + 2];
  unsigned q1 = (unsigned)thr[(1 * 8 + b) * 4 + 2];
  float sv[4] = {s4.x, s4.y, s4.z, s4.w};
  #pragma unroll
  for (int j = 0; j < 4; ++j) {
    bool pk = ((pk4 >> (8 * j)) & 255u) != 0;
    unsigned bits = __float_as_uint(sv[j]);
    unsigned q = pk ? q0 : q1;
    int c = pk ? 0 : 1;
    if ((bits >> 10) >= q) {
      unsigned pos = atomicAdd(&cnt[c * 8 + b], 1u);
      if (pos < 1024)
        cand[((size_t)(c * 8 + b) << 10) + pos] =
            ((unsigned long long)bits << 32) | (unsigned)(~(p + j));
    }
  }
}

// ---------------------------------------------------------------- sort + NMS
__device__ inline void bitonic1024_desc(unsigned long long* sKey) {
  int t = threadIdx.x;
  for (unsigned k = 2; k <= 1024; k <<= 1) {
    for (unsigned j = k >> 1; j > 0; j >>= 1) {
      __syncthreads();
      #pragma unroll
      for (int e = 0; e < 2; ++e) {
        unsigned i = (unsigned)t + (unsigned)e * 512u;
        unsigned l = i ^ j;
        if (l > i) {
          unsigned long long a = sKey[i], bb = sKey[l];
          if (((i & k) == 0) ? (a < bb) : (a > bb)) { sKey[i] = bb; sKey[l] = a; }
        }
      }
    }
  }
  __syncthreads();
}

__global__ __launch_bounds__(512) void k_nms(const unsigned long long* __restrict__ cand,
                                             const unsigned* __restrict__ cnt,
                                             float* __restrict__ out) {
  __shared__ unsigned long long sKey[1024];
  __shared__ unsigned sIdx[512];
  __shared__ int sAvail[512];
  __shared__ int sSel[16];
  int b = blockIdx.x, t = threadIdx.x;
  if (t < 10) out[160 + b * 10 + t] = 1.0f;       // labels
  int Cp = (int)cnt[b]; if (Cp > 1024) Cp = 1024;
  const unsigned long long* cp = cand + ((size_t)b << 10);
  sKey[t] = (t < Cp) ? cp[t] : 0ULL;
  sKey[t + 512] = (t + 512 < Cp) ? cp[t + 512] : 0ULL;
  bitonic1024_desc(sKey);
  sIdx[t] = (unsigned)(~sKey[t]);
  int ncand = (Cp < 512) ? Cp : 512;              // K_PEAKS cap
  sAvail[t] = (t < ncand) ? 1 : 0;
  __syncthreads();
  int nsel = 0;
  for (int i = 0; i < 512 && nsel < 10; ++i) {
    if (sAvail[i] != 0) {                         // uniform branch
      unsigned pi = sIdx[i];
      int xi = (int)(pi & 511), yi = (int)(pi >> 9);
      if (t > i && sAvail[t]) {
        int dx = (int)(sIdx[t] & 511) - xi;
        int dy = (int)(sIdx[t] >> 9) - yi;
        if (dx * dx + dy * dy < 625) sAvail[t] = 0;   // dist < 25
      }
      if (t == 0) sSel[nsel] = (int)pi;
      ++nsel;
      __syncthreads();
    }
  }
  __syncthreads();
  // fallback: top-10 non-peak pixels
  int Cf = (int)cnt[8 + b]; if (Cf > 1024) Cf = 1024;
  const unsigned long long* cf = cand + ((size_t)(8 + b) << 10);
  sKey[t] = (t < Cf) ? cf[t] : 0ULL;
  sKey[t + 512] = (t + 512 < Cf) ? cf[t + 512] : 0ULL;
  bitonic1024_desc(sKey);
  if (t < 10) {
    int fi;
    if (t < nsel) fi = sSel[t];
    else { int r = t - nsel; if (r > 9) r = 9; fi = (int)((unsigned)(~sKey[r])); }
    out[((size_t)b * 10 + t) * 2 + 0] = (float)(fi & 511) * (1.0f / 512.0f);
    out[((size_t)b * 10 + t) * 2 + 1] = (float)(fi >> 9) * (1.0f / 512.0f);
  }
}

// ---------------------------------------------------------------------------
extern "C" void kernel_launch(void* const* d_in, const int* in_sizes, int n_in,
                              void* d_out, int out_size, void* d_ws, size_t ws_size,
                              hipStream_t stream) {
  const float* rgb  = (const float*)d_in[0];
  const float* dep  = (const float*)d_in[1];
  const float* w1   = (const float*)d_in[2];
  const float* b1   = (const float*)d_in[3];
  const float* gam  = (const float*)d_in[4];
  const float* bet  = (const float*)d_in[5];
  const float* bmn  = (const float*)d_in[6];
  const float* bvr  = (const float*)d_in[7];
  const float* w2   = (const float*)d_in[8];
  const float* b2   = (const float*)d_in[9];
  float* out = (float*)d_out;
  char* ws = (char*)d_ws;

  float* sal = (float*)(ws + OFF_SAL);
  int* thr = (int*)(ws + OFF_THR);
  unsigned* cnt = (unsigned*)(ws + OFF_CNT);
  unsigned long long* cand = (unsigned long long*)(ws + OFF_CAND);
  int* part = (int*)(ws + OFF_PART);
  unsigned short* apack = (unsigned short*)(ws + OFF_APACK);
  float* ep = (float*)(ws + OFF_EP);
  unsigned char* pkm = (unsigned char*)(ws + OFF_PKM);

  // dynamic region, phase 1 (conv): ebuf (nb*2MB) then 4-plane freq2
  size_t perE = (size_t)2 * CHW * 4;             // 2 MB / batch
  size_t perF = (size_t)PREC * 64;               // 4 planes * 16B, ~16.9 MB
  long long avail = (long long)ws_size - (long long)OFF_DYN;
  int nb = 1;
  if (avail >= (long long)(perE + perF)) {
    long long m = avail / (long long)(perE + perF);
    nb = (m > 8) ? 8 : (int)m;
  }
  float* ebuf = (float*)(ws + OFF_DYN);
  unsigned short* freq2 = (unsigned short*)(ws + OFF_DYN + perE * (size_t)nb);
  // dynamic region, phase 2 (hist): partials overlap the dead conv buffers
  unsigned* h1p = (unsigned*)(ws + OFF_DYN);                       // 8 MB
  unsigned* h2p = (unsigned*)(ws + OFF_DYN + (size_t)8 * NB1 * 4096 * 4);  // 4 MB

  k_init<<<40, 256, 0, stream>>>(cnt, w1, b1, gam, bet, bmn, bvr, w2, b2,
                                 apack, ep);
  k_zero<<<dim3(33, nb), 256, 0, stream>>>(freq2);

  for (int b0 = 0; b0 < 8; b0 += nb) {
    int nbc = (8 - b0 < nb) ? (8 - b0) : nb;
    k_freq<<<dim3(512, nbc), 256, 0, stream>>>(rgb, dep, freq2, ebuf, b0);
    k_smooth<<<dim3(1024, nbc), 256, 0, stream>>>(ebuf, freq2);
    k_conv<<<dim3(4, 512, nbc), 256, 0, stream>>>(freq2, apack, ep, sal, b0);
  }

  k_resize<<<dim3(256, 8), 256, 0, stream>>>(sal, out + 272, part);
  k_boxreduce<<<8, 256, 0, stream>>>(part, out);
  k_hist1<<<dim3(NB1, 8), 256, 0, stream>>>(sal, h1p, pkm);
  k_scan<<<dim3(2, 8), 256, 0, stream>>>(h1p, thr, 0, NB1);
  k_hist2<<<dim3(NB2, 8), 256, 0, stream>>>(sal, pkm, thr, h2p);
  k_scan<<<dim3(2, 8), 256, 0, stream>>>(h2p, thr, 1, NB2);
  k_compact<<<dim3(256, 8), 256, 0, stream>>>(sal, pkm, thr, cnt, cand);
  k_nms<<<8, 512, 0, stream>>>(cand, cnt, out);
}

// Round 8
// 505.091 us; speedup vs baseline: 1.9256x; 1.0094x over previous
//
#include <hip/hip_runtime.h>
#include <math.h>

// ---------------------------------------------------------------------------
// PromptGenerate: DWT->E->smooth->conv1+BN+GELU->conv2->sigmoid (sal, 512x512)
//  -> bilinear 2x upsample (masks), boxes from mask>0.5, greedy-NMS peak coords
// R6: k_conv on bf16 MFMA hi/lo 3-term. R8: hist -> LDS + non-atomic partials.
// R9: padded freq2, 32x32x16 MFMA. R10: 2-plane split. R11: sched_barrier.
// R12: LDS-staged B tile, 4x16B planes, conflict-free ds_read_b128: 105us.
//      Bookkeeping: MFMA pipe 23us (floor for this scheme), VALU 44us, LDS
//      ~23us. Waste: each block staged 3 rows for 1 output row (3x re-stage),
//      A-frags reloaded per block.
// R13: 4 output rows per block. Stage 6 rows x 4 planes x 130 recs = 49.9KB
//      once; A-frags resident in regs (72 VGPR) reused over 4 rows; per row
//      18 ds_read + 27 MFMA + epilogue. Stage traffic/row x0.5, A-loads x0.25,
//      sync x0.25, 13 independent stage loads (full MLP). Grid y: 512->128.
// ---------------------------------------------------------------------------

#define CHW 262144          // 512*512
#define FULLHW 1048576      // 1024*1024
#define NB1 64              // k_hist1 blocks per batch (4096 px each)
#define NB2 32              // k_hist2 blocks per batch (8192 px each)
#define PROW 514            // padded row stride (records)
#define PREC (514*514)      // padded records per plane per batch (16B records)
#define LREC 130            // LDS records per (row,plane)

typedef __attribute__((ext_vector_type(8))) short bf16x8;
typedef __attribute__((ext_vector_type(16))) float f32x16;

static __device__ __forceinline__ unsigned short f2bf(float x) {
  unsigned u = __float_as_uint(x);
  u += 0x7FFFu + ((u >> 16) & 1u);
  return (unsigned short)(u >> 16);
}
static __device__ __forceinline__ float bf2f(unsigned short h) {
  return __uint_as_float(((unsigned)h) << 16);
}

static constexpr size_t OFF_SAL   = 0;                       // 8*CHW*4
static constexpr size_t OFF_THR   = 8388608;                 // 256
static constexpr size_t OFF_CNT   = OFF_THR + 256;           // 256
static constexpr size_t OFF_CAND  = OFF_CNT + 256;           // 131072
static constexpr size_t OFF_PART  = OFF_CAND + 131072;       // 32768
static constexpr size_t OFF_APACK = OFF_PART + 32768;        // 18432 used
static constexpr size_t OFF_EP    = OFF_APACK + 20480;       // 512 (epilogue)
static constexpr size_t OFF_PKM   = OFF_EP + 512;            // 8*CHW u8
static constexpr size_t OFF_DYN   = OFF_PKM + 2097152;
// dynamic region (temporally disjoint uses):
//   conv phase : ebuf (nb*2MB) + freq2 (nb * 4 planes * PREC*16B ~= 16.9MB)
//   hist phase : h1p (8MB) + h2p (4MB)

// shift s = ky*3+kx (0..8)
static constexpr int SDY[9] = {-1,-1,-1, 0,0,0, 1,1,1};
static constexpr int SDX[9] = {-1, 0, 1,-1,0,1,-1,0,1};

// ---------------------------------------------------------------- init + weight pack
// apack (ushort): idx = ((s*2+h)*64 + lane)*8 ; co=lane&31, c=(lane>>5)*8+e ;
//   val = (c<12) ? w1[co][c][s] : 0 ; h=0 hi, h=1 lo.
// ep (float): reordered to 32x32 D-register order, co=(reg&3)+8*(reg>>2)+4*kg:
//   [0,32) sc | [32,64) shift | [64,96) w2 | [96] b2
__global__ void k_init(unsigned* __restrict__ cnt,
                       const float* __restrict__ w1, const float* __restrict__ b1,
                       const float* __restrict__ gam, const float* __restrict__ bet,
                       const float* __restrict__ mean, const float* __restrict__ var,
                       const float* __restrict__ w2, const float* __restrict__ b2,
                       unsigned short* __restrict__ apack, float* __restrict__ ep) {
  int i = blockIdx.x * 256 + threadIdx.x;
  if (i < 16) cnt[i] = 0;
  if (i < 9216) {
    int e = i & 7, lane = (i >> 3) & 63, frag = i >> 9;   // frag 0..17
    int s = frag >> 1, hh = frag & 1;
    int co = lane & 31;
    int c = ((lane >> 5) << 3) + e;
    float val = (c < 12) ? w1[co * 108 + c * 9 + s] : 0.0f;
    unsigned short hb = f2bf(val);
    apack[i] = hh ? f2bf(val - bf2f(hb)) : hb;
  }
  if (i < 96) {
    int t = i >> 5, rem = i & 31, kg = rem >> 4, reg = rem & 15;
    int co = (reg & 3) + 8 * (reg >> 2) + 4 * kg;
    float sc = gam[co] * rsqrtf(var[co] + 1e-5f);
    float v = (t == 0) ? sc
            : (t == 1) ? (b1[co] - mean[co]) * sc + bet[co]
                       : w2[co];
    ep[i] = v;
  } else if (i == 96) {
    ep[96] = b2[0];
  }
}

// ---------------------------------------------------------------- border zero
// zero 16B border records of all 4 planes of each batch slot.
__global__ __launch_bounds__(256) void k_zero(unsigned short* __restrict__ freq2) {
  int i = blockIdx.x * 256 + threadIdx.x;        // [0, 8208) 16B items
  int bi = blockIdx.y;
  if (i >= 8208) return;                          // 4 planes * 2052 records
  int pl = i / 2052, r = i % 2052;
  int row, col;
  if (r < 514)        { row = 0;   col = r; }
  else if (r < 1028)  { row = 513; col = r - 514; }
  else if (r < 1540)  { row = r - 1028 + 1; col = 0; }
  else                { row = r - 1540 + 1; col = 513; }
  uint4* p = (uint4*)(freq2 + ((size_t)(bi * 4 + pl) * PREC + (size_t)row * PROW + col) * 8);
  *p = make_uint4(0u, 0u, 0u, 0u);
}

// ---------------------------------------------------------------- freq ch 0..7 (P0h/P0l)
// plane0 = ch0-7 hi (16B/px), plane1 = ch0-7 lo. Er/Ed -> f32 ebuf.
__global__ __launch_bounds__(256) void k_freq(const float* __restrict__ rgb,
                                              const float* __restrict__ dep,
                                              unsigned short* __restrict__ freq2,
                                              float* __restrict__ ebuf, int b0) {
  int t = blockIdx.x * 256 + threadIdx.x;        // [0, 131072)
  int bi = blockIdx.y;
  int b = b0 + bi;
  int xp = t & 255, y = t >> 8;                  // xp: pair idx, outputs x=2xp,2xp+1
  const float* base = rgb + (size_t)b * 3 * FULLHW + (size_t)(2 * y) * 1024 + 4 * xp;
  float4 R0 = *(const float4*)(base);
  float4 R1 = *(const float4*)(base + 1024);
  float4 G0 = *(const float4*)(base + FULLHW);
  float4 G1 = *(const float4*)(base + FULLHW + 1024);
  float4 Bl0 = *(const float4*)(base + 2 * FULLHW);
  float4 Bl1 = *(const float4*)(base + 2 * FULLHW + 1024);
  const float* dbase = dep + (size_t)b * FULLHW + (size_t)(2 * y) * 1024 + 4 * xp;
  float4 D0 = *(const float4*)(dbase);
  float4 D1 = *(const float4*)(dbase + 1024);

  float gt[4], gb[4], dt[4], db_[4];
  gt[0] = (R0.x + G0.x + Bl0.x) / 3.0f; gt[1] = (R0.y + G0.y + Bl0.y) / 3.0f;
  gt[2] = (R0.z + G0.z + Bl0.z) / 3.0f; gt[3] = (R0.w + G0.w + Bl0.w) / 3.0f;
  gb[0] = (R1.x + G1.x + Bl1.x) / 3.0f; gb[1] = (R1.y + G1.y + Bl1.y) / 3.0f;
  gb[2] = (R1.z + G1.z + Bl1.z) / 3.0f; gb[3] = (R1.w + G1.w + Bl1.w) / 3.0f;
  dt[0] = D0.x; dt[1] = D0.y; dt[2] = D0.z; dt[3] = D0.w;
  db_[0] = D1.x; db_[1] = D1.y; db_[2] = D1.z; db_[3] = D1.w;

  unsigned short hs[2][8], ls[2][8];
  float er[2], ed[2];
  #pragma unroll
  for (int j = 0; j < 2; ++j) {
    float a = gt[2 * j] * 0.5f, bb = gb[2 * j] * 0.5f;
    float c = gt[2 * j + 1] * 0.5f, d = gb[2 * j + 1] * 0.5f;
    float v[8];
    v[0] = a + bb; v[1] = a - bb; v[2] = c + d; v[3] = c - d;
    float da = dt[2 * j] * 0.5f, db2 = db_[2 * j] * 0.5f;
    float dc = dt[2 * j + 1] * 0.5f, dd = db_[2 * j + 1] * 0.5f;
    v[4] = da + db2; v[5] = da - db2; v[6] = dc + dd; v[7] = dc - dd;
    er[j] = sqrtf(v[1] * v[1] + v[2] * v[2] + v[3] * v[3] + 1e-8f);
    ed[j] = sqrtf(v[5] * v[5] + v[6] * v[6] + v[7] * v[7] + 1e-8f);
    #pragma unroll
    for (int cc = 0; cc < 8; ++cc) {
      unsigned short hb = f2bf(v[cc]);
      hs[j][cc] = hb;
      ls[j][cc] = f2bf(v[cc] - bf2f(hb));
    }
  }
  size_t rbase = (size_t)(y + 1) * PROW + (2 * xp + 1);
  unsigned short* d0 = freq2 + ((size_t)(bi * 4 + 0) * PREC + rbase) * 8;
  unsigned short* d1 = freq2 + ((size_t)(bi * 4 + 1) * PREC + rbase) * 8;
  ((uint4*)d0)[0] = ((const uint4*)hs[0])[0];
  ((uint4*)d0)[1] = ((const uint4*)hs[1])[0];
  ((uint4*)d1)[0] = ((const uint4*)ls[0])[0];
  ((uint4*)d1)[1] = ((const uint4*)ls[1])[0];
  float* eb = ebuf + (size_t)bi * 2 * CHW + (size_t)y * 512 + 2 * xp;
  *(float2*)(eb) = make_float2(er[0], er[1]);
  *(float2*)(eb + CHW) = make_float2(ed[0], ed[1]);
}

// ---------------------------------------------------------------- smooth -> P1h/P1l
__constant__ float GW[25] = {
  0.00296901f, 0.01330621f, 0.02193824f, 0.01330621f, 0.00296901f,
  0.01330621f, 0.05963435f, 0.09832035f, 0.05963435f, 0.01330621f,
  0.02193824f, 0.09832035f, 0.16210276f, 0.09832035f, 0.02193824f,
  0.01330621f, 0.05963435f, 0.09832035f, 0.05963435f, 0.01330621f,
  0.00296901f, 0.01330621f, 0.02193824f, 0.01330621f, 0.00296901f};

// plane2 = [Er,Ed,Ers,Eds,0,0,0,0] hi (16B/px), plane3 = lo.
__global__ __launch_bounds__(256) void k_smooth(const float* __restrict__ ebuf,
                                                unsigned short* __restrict__ freq2) {
  int t = blockIdx.x * 256 + threadIdx.x;
  int bi = blockIdx.y;
  int x = t & 511, y = t >> 9;
  const float* eb = ebuf + (size_t)bi * 2 * CHW;
  float accv[2];
  #pragma unroll
  for (int ch = 0; ch < 2; ++ch) {
    const float* fin = eb + ch * CHW;
    float acc = 0.0f;
    #pragma unroll
    for (int i = 0; i < 5; ++i) {
      int yy = y + i - 2;
      if (yy < 0 || yy > 511) continue;
      #pragma unroll
      for (int j = 0; j < 5; ++j) {
        int xx = x + j - 2;
        if (xx < 0 || xx > 511) continue;
        acc += GW[i * 5 + j] * fin[yy * 512 + xx];
      }
    }
    accv[ch] = acc;
  }
  float erc = eb[t], edc = eb[CHW + t];          // center (unsmoothed) ch8,9
  unsigned short rh[8], rl[8];
  float v4[4] = {erc, edc, accv[0], accv[1]};
  #pragma unroll
  for (int j = 0; j < 4; ++j) {
    unsigned short hb = f2bf(v4[j]);
    rh[j] = hb;
    rl[j] = f2bf(v4[j] - bf2f(hb));
  }
  #pragma unroll
  for (int j = 4; j < 8; ++j) { rh[j] = 0; rl[j] = 0; }
  size_t rbase = (size_t)(y + 1) * PROW + (x + 1);
  unsigned short* p2 = freq2 + ((size_t)(bi * 4 + 2) * PREC + rbase) * 8;
  unsigned short* p3 = freq2 + ((size_t)(bi * 4 + 3) * PREC + rbase) * 8;
  *(uint4*)p2 = *(const uint4*)rh;
  *(uint4*)p3 = *(const uint4*)rl;
}

// ---------------------------------------------------------------- conv fused (MFMA)
// Block = 128 px strip x 4 OUTPUT ROWS, 4 waves (each 32 px x 32 co x 4 rows).
// Stage 6 padded rows x 4 planes x 130 recs = 49.9KB LDS once. A-frags
// resident in regs across rows. Per row: 18 ds_read_b128 + 27 MFMA + epilogue.
__global__ __launch_bounds__(256) void k_conv(const unsigned short* __restrict__ freq2,
    const unsigned short* __restrict__ apack, const float* __restrict__ ep,
    float* __restrict__ sal, int b0) {
  __shared__ __align__(16) char smem[49920];     // ((row*4+plane)*130+rec)*16, row 0..5
  int tid = threadIdx.x;
  int l = tid & 63, wv = tid >> 6;
  int yb = blockIdx.y * 4;                       // output rows yb..yb+3
  int xwb = blockIdx.x * 128;
  int bi = blockIdx.z;
  int n = l & 31, kg = l >> 5;

  // stage: 3120 records of 16B (padded rows yb..yb+5), all loads independent
  #pragma unroll
  for (int it = 0; it < 13; ++it) {
    int j = it * 256 + tid;
    if (j < 3120) {
      int row = j / 520, rem = j - row * 520;
      int plane = rem / 130, rec = rem - plane * 130;
      const unsigned short* g = freq2 +
          ((size_t)(bi * 4 + plane) * PREC + (size_t)(yb + row) * PROW + (xwb + rec)) * 8;
      *(uint4*)(smem + j * 16) = *(const uint4*)g;
    }
  }

  // A fragments resident across all 4 rows (load during staging, pre-sync)
  const unsigned short* ab = apack + l * 8;
  bf16x8 Ah[9], Al[9];
  #pragma unroll
  for (int s = 0; s < 9; ++s) {
    Ah[s] = *(const bf16x8*)(ab + s * 1024);
    Al[s] = *(const bf16x8*)(ab + s * 1024 + 512);
  }

  // epilogue tables (uniform)
  const float* e0 = ep + kg * 16;
  const float* e1 = ep + 32 + kg * 16;
  const float* e2 = ep + 64 + kg * 16;
  float b2v = ep[96];

  __syncthreads();

  #pragma unroll
  for (int ry = 0; ry < 4; ++ry) {
    f32x16 acc = {};
    #pragma unroll
    for (int s = 0; s < 9; ++s) {
      int row = ry + 1 + SDY[s];
      int rec = wv * 32 + n + 1 + SDX[s];
      const char* bh = smem + (((row * 4 + kg * 2 + 0) * LREC) + rec) * 16;
      const char* bl = smem + (((row * 4 + kg * 2 + 1) * LREC) + rec) * 16;
      bf16x8 Bh = *(const bf16x8*)bh;
      bf16x8 Bl = *(const bf16x8*)bl;
      acc = __builtin_amdgcn_mfma_f32_32x32x16_bf16(Ah[s], Bh, acc, 0, 0, 0);
      acc = __builtin_amdgcn_mfma_f32_32x32x16_bf16(Al[s], Bh, acc, 0, 0, 0);
      acc = __builtin_amdgcn_mfma_f32_32x32x16_bf16(Ah[s], Bl, acc, 0, 0, 0);
    }

    // BN + gelu + w2-dot over 16 regs (co=(reg&3)+8*(reg>>2)+4*kg),
    // pair-lane reduce (l ^ 32), sigmoid, store px n by lanes 0..31.
    float s2 = 0.0f;
    #pragma unroll
    for (int r = 0; r < 16; ++r) {
      float t = acc[r] * e0[r] + e1[r];
      float z = t * (1.5957691216057308f + 0.07135481283247183f * (t * t));
      float g = t * __builtin_amdgcn_rcpf(1.0f + __expf(-z));   // == gelu(t)
      s2 += g * e2[r];
    }
    s2 += __shfl_xor(s2, 32);
    s2 += b2v;
    float res = __builtin_amdgcn_rcpf(1.0f + __expf(-s2));
    if (l < 32)
      sal[(size_t)(b0 + bi) * CHW + (size_t)(yb + ry) * 512 + xwb + wv * 32 + n] = res;
  }
}

// ---------------------------------------------------------------- resize + box partials
__global__ __launch_bounds__(256) void k_resize(const float* __restrict__ sal,
                                                float* __restrict__ masks,
                                                int* __restrict__ part) {
  int b = blockIdx.y;
  int blk = blockIdx.x;
  int t = threadIdx.x;
  const float* sp = sal + (size_t)b * CHW;
  float* mp = masks + (size_t)b * FULLHW;
  int mnX = 0x7FFFFFFF, mxX = -1, mnY = 0x7FFFFFFF, mxY = -1;
  int c0 = 4 * t;
  #pragma unroll
  for (int r = 0; r < 4; ++r) {
    int Y = blk * 4 + r;
    int y0 = (Y - 1) >> 1;
    float wy = (Y & 1) ? 0.25f : 0.75f;
    int y0c = y0 < 0 ? 0 : y0, y1c = (y0 + 1 > 511) ? 511 : y0 + 1;
    const float* r0 = sp + y0c * 512;
    const float* r1 = sp + y1c * 512;
    float o[4];
    #pragma unroll
    for (int j = 0; j < 4; ++j) {
      int X = c0 + j;
      int x0 = (X - 1) >> 1;
      float wx = (X & 1) ? 0.25f : 0.75f;
      int x0c = x0 < 0 ? 0 : x0, x1c = (x0 + 1 > 511) ? 511 : x0 + 1;
      float v00 = r0[x0c], v01 = r0[x1c], v10 = r1[x0c], v11 = r1[x1c];
      o[j] = (1.0f - wy) * ((1.0f - wx) * v00 + wx * v01)
           + wy * ((1.0f - wx) * v10 + wx * v11);
      if (o[j] > 0.5f) {
        mnX = min(mnX, X); mxX = max(mxX, X);
        mnY = min(mnY, Y); mxY = max(mxY, Y);
      }
    }
    *(float4*)(mp + (size_t)Y * 1024 + c0) = make_float4(o[0], o[1], o[2], o[3]);
  }
  __shared__ int s0[256], s1[256], s2[256], s3[256];
  s0[t] = mnX; s1[t] = mxX; s2[t] = mnY; s3[t] = mxY;
  __syncthreads();
  for (int off = 128; off > 0; off >>= 1) {
    if (t < off) {
      s0[t] = min(s0[t], s0[t + off]); s1[t] = max(s1[t], s1[t + off]);
      s2[t] = min(s2[t], s2[t + off]); s3[t] = max(s3[t], s3[t + off]);
    }
    __syncthreads();
  }
  if (t == 0) {
    int* pp = part + (b * 256 + blk) * 4;
    pp[0] = s0[0]; pp[1] = s1[0]; pp[2] = s2[0]; pp[3] = s3[0];
  }
}

// ---------------------------------------------------------------- box reduce -> out
__global__ __launch_bounds__(256) void k_boxreduce(const int* __restrict__ part,
                                                   float* __restrict__ out) {
  int b = blockIdx.x, t = threadIdx.x;
  const int* pp = part + (b * 256 + t) * 4;
  __shared__ int s0[256], s1[256], s2[256], s3[256];
  s0[t] = pp[0]; s1[t] = pp[1]; s2[t] = pp[2]; s3[t] = pp[3];
  __syncthreads();
  for (int off = 128; off > 0; off >>= 1) {
    if (t < off) {
      s0[t] = min(s0[t], s0[t + off]); s1[t] = max(s1[t], s1[t + off]);
      s2[t] = min(s2[t], s2[t + off]); s3[t] = max(s3[t], s3[t + off]);
    }
    __syncthreads();
  }
  if (t == 0) {
    float x0, y0, x1, y1;
    if (s3[0] < 0) { x0 = 0.0f; y0 = 0.0f; x1 = 1023.0f; y1 = 1023.0f; }
    else { x0 = (float)s0[0]; y0 = (float)s2[0]; x1 = (float)s1[0]; y1 = (float)s3[0]; }
    out[240 + b * 4 + 0] = x0;
    out[240 + b * 4 + 1] = y0;
    out[240 + b * 4 + 2] = x1;
    out[240 + b * 4 + 3] = y1;
  }
}

// ---------------------------------------------------------------- level-1 hist (+peak mask)
__global__ __launch_bounds__(256) void k_hist1(const float* __restrict__ sal,
                                               unsigned* __restrict__ h1p,
                                               unsigned char* __restrict__ pkm) {
  __shared__ unsigned sH[4096];                   // [class][2048]
  int b = blockIdx.y, tid = threadIdx.x;
  for (int i = tid; i < 4096; i += 256) sH[i] = 0;
  __syncthreads();
  const float* sp = sal + (size_t)b * CHW;
  int base = blockIdx.x * 4096;
  for (int it = 0; it < 4; ++it) {
    int p = base + it * 1024 + tid * 4;
    int x0 = p & 511, y = p >> 9;
    int ym = (y > 0) ? y - 1 : 0, yp = (y < 511) ? y + 1 : 511;
    const float* r0 = sp + ym * 512;
    const float* r1 = sp + y * 512;
    const float* r2 = sp + yp * 512;
    float4 m0 = *(const float4*)(r0 + x0);
    float4 m1 = *(const float4*)(r1 + x0);
    float4 m2 = *(const float4*)(r2 + x0);
    float l0 = x0 ? r0[x0 - 1] : m0.x;
    float l1 = x0 ? r1[x0 - 1] : m1.x;
    float l2 = x0 ? r2[x0 - 1] : m2.x;
    float q0 = (x0 < 508) ? r0[x0 + 4] : m0.w;
    float q1 = (x0 < 508) ? r1[x0 + 4] : m1.w;
    float q2 = (x0 < 508) ? r2[x0 + 4] : m2.w;
    float a0[6] = {l0, m0.x, m0.y, m0.z, m0.w, q0};
    float a1[6] = {l1, m1.x, m1.y, m1.z, m1.w, q1};
    float a2[6] = {l2, m2.x, m2.y, m2.z, m2.w, q2};
    unsigned pw = 0;
    #pragma unroll
    for (int j = 0; j < 4; ++j) {
      float r0m = fmaxf(fmaxf(a0[j], a0[j + 1]), a0[j + 2]);
      float r1m = fmaxf(fmaxf(a1[j], a1[j + 1]), a1[j + 2]);
      float r2m = fmaxf(fmaxf(a2[j], a2[j + 1]), a2[j + 2]);
      float cmax = fmaxf(fmaxf(r0m, r1m), r2m);
      float sv = a1[j + 1];
      bool pk = (sv > 0.0f) && (sv >= cmax);      // no neighbor strictly greater
      pw |= (pk ? 1u : 0u) << (8 * j);
      unsigned bin = (__float_as_uint(sv) >> 21) & 2047;
      atomicAdd(&sH[(pk ? 0 : 2048) + bin], 1u);
    }
    *(unsigned*)(pkm + (size_t)b * CHW + p) = pw;
  }
  __syncthreads();
  unsigned* dst = h1p + ((size_t)b * NB1 + blockIdx.x) * 4096;
  for (int i = tid; i < 4096; i += 256) dst[i] = sH[i];
}

// ---------------------------------------------------------------- radix scan (sums partials)
__global__ __launch_bounds__(256) void k_scan(const unsigned* __restrict__ hp,
                                              int* __restrict__ thr, int level,
                                              int np) {
  int c = blockIdx.x, b = blockIdx.y, t = threadIdx.x;
  __shared__ unsigned sBins[2048];
  __shared__ unsigned sS[256];
  __shared__ int sT;
  unsigned bv[8] = {0, 0, 0, 0, 0, 0, 0, 0};
  for (int p = 0; p < np; ++p) {
    const unsigned* q = hp + ((size_t)(b * np + p)) * 4096 + c * 2048 + t * 8;
    uint4 a = *(const uint4*)(q);
    uint4 d = *(const uint4*)(q + 4);
    bv[0] += a.x; bv[1] += a.y; bv[2] += a.z; bv[3] += a.w;
    bv[4] += d.x; bv[5] += d.y; bv[6] += d.z; bv[7] += d.w;
  }
  unsigned part = 0;
  #pragma unroll
  for (int r = 0; r < 8; ++r) {
    sBins[t * 8 + r] = bv[r];
    part += bv[r];
  }
  sS[t] = part;
  __syncthreads();
  for (int off = 1; off < 256; off <<= 1) {
    unsigned add = (t + off < 256) ? sS[t + off] : 0;
    __syncthreads();
    sS[t] += add;
    __syncthreads();
  }
  int K = (c == 0) ? 512 : 10;
  int* tb = thr + (c * 8 + b) * 4;
  if (level == 1) { K -= tb[1]; if (K < 1) K = 1; }
  if (t == 0) sT = -1;
  __syncthreads();
  if (sS[t] >= (unsigned)K && (t == 255 || sS[t + 1] < (unsigned)K)) sT = t;
  __syncthreads();
  if (t == 0) {
    int T = 0;
    unsigned run = 0;
    if (sT >= 0) {
      int ts = sT;
      run = (ts < 255) ? sS[ts + 1] : 0;
      for (int r = 7; r >= 0; --r) {
        unsigned v = sBins[ts * 8 + r];
        run += v;
        if (run >= (unsigned)K) { T = ts * 8 + r; run -= v; break; }
      }
    } else {
      T = 0;
      run = sS[0] - sBins[0];                     // suffix(1); take everything
    }
    if (level == 0) { tb[0] = T; tb[1] = (int)run; }
    else           { tb[2] = (tb[0] << 11) | T; }
  }
}

// ---------------------------------------------------------------- level-2 hist
__global__ __launch_bounds__(256) void k_hist2(const float* __restrict__ sal,
                                               const unsigned char* __restrict__ pkm,
                                               const int* __restrict__ thr,
                                               unsigned* __restrict__ h2p) {
  __shared__ unsigned sH[4096];
  int b = blockIdx.y, tid = threadIdx.x;
  for (int i = tid; i < 4096; i += 256) sH[i] = 0;
  __syncthreads();
  int t0 = thr[(0 * 8 + b) * 4];
  int t1 = thr[(1 * 8 + b) * 4];
  const float* sp = sal + (size_t)b * CHW;
  const unsigned char* pp = pkm + (size_t)b * CHW;
  int base = blockIdx.x * 8192;
  for (int it = 0; it < 8; ++it) {
    int p = base + it * 1024 + tid * 4;
    float4 s4 = *(const float4*)(sp + p);
    unsigned pk4 = *(const unsigned*)(pp + p);
    float sv[4] = {s4.x, s4.y, s4.z, s4.w};
    #pragma unroll
    for (int j = 0; j < 4; ++j) {
      bool pk = ((pk4 >> (8 * j)) & 255u) != 0;
      unsigned bits = __float_as_uint(sv[j]);
      int tt = pk ? t0 : t1;
      if ((int)(bits >> 21) == tt)
        atomicAdd(&sH[(pk ? 0 : 2048) + ((bits >> 10) & 2047)], 1u);
    }
  }
  __syncthreads();
  unsigned* dst = h2p + ((size_t)b * NB2 + blockIdx.x) * 4096;
  for (int i = tid; i < 4096; i += 256) dst[i] = sH[i];
}

// ---------------------------------------------------------------- compact
__global__ __launch_bounds__(256) void k_compact(const float* __restrict__ sal,
                                                 const unsigned char* __restrict__ pkm,
                                                 const int* __restrict__ thr,
                                                 unsigned* __restrict__ cnt,
                                                 unsigned long long* __restrict__ cand) {
  int b = blockIdx.y;
  int p = (blockIdx.x * 256 + threadIdx.x) * 4;
  const float* sp = sal + (size_t)b * CHW;
  float4 s4 = *(const float4*)(sp + p);
  unsigned pk4 = *(const unsigned*)(pkm + (size_t)b * CHW + p);
  unsigned q0 = (unsigned)thr[(0 * 8 + b) * 4 + 2];
  unsigned q1 = (unsigned)thr[(1 * 8 + b) * 4 + 2];
  float sv[4] = {s4.x, s4.y, s4.z, s4.w};
  #pragma unroll
  for (int j = 0; j < 4; ++j) {
    bool pk = ((pk4 >> (8 * j)) & 255u) != 0;
    unsigned bits = __float_as_uint(sv[j]);
    unsigned q = pk ? q0 : q1;
    int c = pk ? 0 : 1;
    if ((bits >> 10) >= q) {
      unsigned pos = atomicAdd(&cnt[c * 8 + b], 1u);
      if (pos < 1024)
        cand[((size_t)(c * 8 + b) << 10) + pos] =
            ((unsigned long long)bits << 32) | (unsigned)(~(p + j));
    }
  }
}

// ---------------------------------------------------------------- sort + NMS
__device__ inline void bitonic1024_desc(unsigned long long* sKey) {
  int t = threadIdx.x;
  for (unsigned k = 2; k <= 1024; k <<= 1) {
    for (unsigned j = k >> 1; j > 0; j >>= 1) {
      __syncthreads();
      #pragma unroll
      for (int e = 0; e < 2; ++e) {
        unsigned i = (unsigned)t + (unsigned)e * 512u;
        unsigned l = i ^ j;
        if (l > i) {
          unsigned long long a = sKey[i], bb = sKey[l];
          if (((i & k) == 0) ? (a < bb) : (a > bb)) { sKey[i] = bb; sKey[l] = a; }
        }
      }
    }
  }
  __syncthreads();
}

__global__ __launch_bounds__(512) void k_nms(const unsigned long long* __restrict__ cand,
                                             const unsigned* __restrict__ cnt,
                                             float* __restrict__ out) {
  __shared__ unsigned long long sKey[1024];
  __shared__ unsigned sIdx[512];
  __shared__ int sAvail[512];
  __shared__ int sSel[16];
  int b = blockIdx.x, t = threadIdx.x;
  if (t < 10) out[160 + b * 10 + t] = 1.0f;       // labels
  int Cp = (int)cnt[b]; if (Cp > 1024) Cp = 1024;
  const unsigned long long* cp = cand + ((size_t)b << 10);
  sKey[t] = (t < Cp) ? cp[t] : 0ULL;
  sKey[t + 512] = (t + 512 < Cp) ? cp[t + 512] : 0ULL;
  bitonic1024_desc(sKey);
  sIdx[t] = (unsigned)(~sKey[t]);
  int ncand = (Cp < 512) ? Cp : 512;              // K_PEAKS cap
  sAvail[t] = (t < ncand) ? 1 : 0;
  __syncthreads();
  int nsel = 0;
  for (int i = 0; i < 512 && nsel < 10; ++i) {
    if (sAvail[i] != 0) {                         // uniform branch
      unsigned pi = sIdx[i];
      int xi = (int)(pi & 511), yi = (int)(pi >> 9);
      if (t > i && sAvail[t]) {
        int dx = (int)(sIdx[t] & 511) - xi;
        int dy = (int)(sIdx[t] >> 9) - yi;
        if (dx * dx + dy * dy < 625) sAvail[t] = 0;   // dist < 25
      }
      if (t == 0) sSel[nsel] = (int)pi;
      ++nsel;
      __syncthreads();
    }
  }
  __syncthreads();
  // fallback: top-10 non-peak pixels
  int Cf = (int)cnt[8 + b]; if (Cf > 1024) Cf = 1024;
  const unsigned long long* cf = cand + ((size_t)(8 + b) << 10);
  sKey[t] = (t < Cf) ? cf[t] : 0ULL;
  sKey[t + 512] = (t + 512 < Cf) ? cf[t + 512] : 0ULL;
  bitonic1024_desc(sKey);
  if (t < 10) {
    int fi;
    if (t < nsel) fi = sSel[t];
    else { int r = t - nsel; if (r > 9) r = 9; fi = (int)((unsigned)(~sKey[r])); }
    out[((size_t)b * 10 + t) * 2 + 0] = (float)(fi & 511) * (1.0f / 512.0f);
    out[((size_t)b * 10 + t) * 2 + 1] = (float)(fi >> 9) * (1.0f / 512.0f);
  }
}

// ---------------------------------------------------------------------------
extern "C" void kernel_launch(void* const* d_in, const int* in_sizes, int n_in,
                              void* d_out, int out_size, void* d_ws, size_t ws_size,
                              hipStream_t stream) {
  const float* rgb  = (const float*)d_in[0];
  const float* dep  = (const float*)d_in[1];
  const float* w1   = (const float*)d_in[2];
  const float* b1   = (const float*)d_in[3];
  const float* gam  = (const float*)d_in[4];
  const float* bet  = (const float*)d_in[5];
  const float* bmn  = (const float*)d_in[6];
  const float* bvr  = (const float*)d_in[7];
  const float* w2   = (const float*)d_in[8];
  const float* b2   = (const float*)d_in[9];
  float* out = (float*)d_out;
  char* ws = (char*)d_ws;

  float* sal = (float*)(ws + OFF_SAL);
  int* thr = (int*)(ws + OFF_THR);
  unsigned* cnt = (unsigned*)(ws + OFF_CNT);
  unsigned long long* cand = (unsigned long long*)(ws + OFF_CAND);
  int* part = (int*)(ws + OFF_PART);
  unsigned short* apack = (unsigned short*)(ws + OFF_APACK);
  float* ep = (float*)(ws + OFF_EP);
  unsigned char* pkm = (unsigned char*)(ws + OFF_PKM);

  // dynamic region, phase 1 (conv): ebuf (nb*2MB) then 4-plane freq2
  size_t perE = (size_t)2 * CHW * 4;             // 2 MB / batch
  size_t perF = (size_t)PREC * 64;               // 4 planes * 16B, ~16.9 MB
  long long avail = (long long)ws_size - (long long)OFF_DYN;
  int nb = 1;
  if (avail >= (long long)(perE + perF)) {
    long long m = avail / (long long)(perE + perF);
    nb = (m > 8) ? 8 : (int)m;
  }
  float* ebuf = (float*)(ws + OFF_DYN);
  unsigned short* freq2 = (unsigned short*)(ws + OFF_DYN + perE * (size_t)nb);
  // dynamic region, phase 2 (hist): partials overlap the dead conv buffers
  unsigned* h1p = (unsigned*)(ws + OFF_DYN);                       // 8 MB
  unsigned* h2p = (unsigned*)(ws + OFF_DYN + (size_t)8 * NB1 * 4096 * 4);  // 4 MB

  k_init<<<40, 256, 0, stream>>>(cnt, w1, b1, gam, bet, bmn, bvr, w2, b2,
                                 apack, ep);
  k_zero<<<dim3(33, nb), 256, 0, stream>>>(freq2);

  for (int b0 = 0; b0 < 8; b0 += nb) {
    int nbc = (8 - b0 < nb) ? (8 - b0) : nb;
    k_freq<<<dim3(512, nbc), 256, 0, stream>>>(rgb, dep, freq2, ebuf, b0);
    k_smooth<<<dim3(1024, nbc), 256, 0, stream>>>(ebuf, freq2);
    k_conv<<<dim3(4, 128, nbc), 256, 0, stream>>>(freq2, apack, ep, sal, b0);
  }

  k_resize<<<dim3(256, 8), 256, 0, stream>>>(sal, out + 272, part);
  k_boxreduce<<<8, 256, 0, stream>>>(part, out);
  k_hist1<<<dim3(NB1, 8), 256, 0, stream>>>(sal, h1p, pkm);
  k_scan<<<dim3(2, 8), 256, 0, stream>>>(h1p, thr, 0, NB1);
  k_hist2<<<dim3(NB2, 8), 256, 0, stream>>>(sal, pkm, thr, h2p);
  k_scan<<<dim3(2, 8), 256, 0, stream>>>(h2p, thr, 1, NB2);
  k_compact<<<dim3(256, 8), 256, 0, stream>>>(sal, pkm, thr, cnt, cand);
  k_nms<<<8, 512, 0, stream>>>(cand, cnt, out);
}